// Round 1
// baseline (3693.085 us; speedup 1.0000x reference)
//
#include <hip/hip_runtime.h>
#include <math.h>

// ---------------------------------------------------------------------------
// TimeMix (RWKV-6 vision block) — round 0: correct fp32 implementation.
// B=8, T=1024 (32x32), C=768, H=12 heads of 64.
// Pipeline:
//   1. qshift -> xx, xxx
//   2. t5 = tanh(xxx @ maa_w1)            [M,160]
//   3. mix5: xw..xg = x + xx*(maa_* + t5f @ maa_w2[f])
//   4. r,k,v = x? @ W_?^T ; g = relu(xg @ W_g^T)
//      t6 = tanh(xw @ dec_w1); w = time_decay + t6 @ dec_w2
//   5. wkv6 recurrence (fp32, 1 wave per (b,h))
//   6. groupnorm(y) * g
//   7. out = z @ W_o^T
// ---------------------------------------------------------------------------

#define EPI_NONE 0
#define EPI_TANH 1
#define EPI_RELU 2
#define EPI_BIAS 3

// ---------------------------------------------------------------- qshift ---
__global__ __launch_bounds__(256) void k_qshift(
    const float* __restrict__ x, const float* __restrict__ maa_x,
    float* __restrict__ xx, float* __restrict__ xxx,
    int B, int T, int C, int ph, int pw) {
  long idx = (long)blockIdx.x * blockDim.x + threadIdx.x;
  long total = (long)B * T * C;
  if (idx >= total) return;
  int c = (int)(idx % C);
  long bt = idx / C;
  int t = (int)(bt % T);
  int hc = c & 63;
  int quarter = hc >> 4;
  int hh = t / pw;
  int ww = t - hh * pw;
  long rowbase = (bt - t) * C;  // (b*T)*C
  float sval = 0.f;
  int st = -1;
  if (quarter == 0)      { if (ww >= 1)      st = t - 1;  }   // shift right in W
  else if (quarter == 1) { if (ww < pw - 1)  st = t + 1;  }   // shift left in W
  else if (quarter == 2) { if (hh >= 1)      st = t - pw; }   // shift down in H
  else                   { if (hh < ph - 1)  st = t + pw; }   // shift up in H
  if (st >= 0) sval = x[rowbase + (long)st * C + c];
  float xval = x[idx];
  float d = sval - xval;
  xx[idx] = d;
  xxx[idx] = xval + d * maa_x[c];
}

// ------------------------------------------------------------------ mix5 ---
// 4 rows per block; t5 row chunks staged in LDS; maa_w2 reused across rows.
__global__ __launch_bounds__(256) void k_mix5(
    const float* __restrict__ x, const float* __restrict__ xx,
    const float* __restrict__ t5, const float* __restrict__ maa_w2,
    const float* __restrict__ maa_w, const float* __restrict__ maa_k,
    const float* __restrict__ maa_v, const float* __restrict__ maa_r,
    const float* __restrict__ maa_g,
    float* __restrict__ xw, float* __restrict__ xk, float* __restrict__ xvb,
    float* __restrict__ xr, float* __restrict__ xg, int C) {
  const int ROWS = 4;
  int row0 = blockIdx.x * ROWS;
  __shared__ float st[ROWS][160];
  int tid = threadIdx.x;
  for (int i = tid; i < ROWS * 160; i += 256) {
    int q = i / 160, rr = i - q * 160;
    st[q][rr] = t5[(long)(row0 + q) * 160 + rr];
  }
  __syncthreads();
  for (int c = tid; c < C; c += 256) {
    float acc[ROWS][5];
#pragma unroll
    for (int q = 0; q < ROWS; q++)
#pragma unroll
      for (int f = 0; f < 5; f++) acc[q][f] = 0.f;
#pragma unroll
    for (int f = 0; f < 5; f++) {
#pragma unroll
      for (int rr = 0; rr < 32; rr++) {
        float wv = maa_w2[(long)(f * 32 + rr) * C + c];
#pragma unroll
        for (int q = 0; q < ROWS; q++)
          acc[q][f] = fmaf(st[q][f * 32 + rr], wv, acc[q][f]);
      }
    }
#pragma unroll
    for (int q = 0; q < ROWS; q++) {
      long off = (long)(row0 + q) * C + c;
      float xval = x[off];
      float d = xx[off];
      xw[off]  = xval + d * (maa_w[c] + acc[q][0]);
      xk[off]  = xval + d * (maa_k[c] + acc[q][1]);
      xvb[off] = xval + d * (maa_v[c] + acc[q][2]);
      xr[off]  = xval + d * (maa_r[c] + acc[q][3]);
      xg[off]  = xval + d * (maa_g[c] + acc[q][4]);
    }
  }
}

// ------------------------------------------------------------------ gemm ---
// C[m,n] = act( sum_k A[m,k] * B(k,n) [+ bias[n]] )
// BT=true : B stored [N,K] row-major (i.e. A @ B^T)
// BT=false: B stored [K,N] row-major (i.e. A @ B)
template <int EPI, bool BT>
__global__ __launch_bounds__(256) void k_gemm(
    const float* __restrict__ A, const float* __restrict__ Bm,
    const float* __restrict__ bias, float* __restrict__ Cm,
    int M, int N, int K) {
  const int BMt = 64, BNt = 64, BKt = 16;
  __shared__ float As[BKt][BMt];
  __shared__ float Bs[BKt][BNt];
  int tid = (int)threadIdx.x;
  int m0 = blockIdx.y * BMt, n0 = blockIdx.x * BNt;
  int tx = tid & 15, ty = tid >> 4;
  float acc[4][4];
#pragma unroll
  for (int i = 0; i < 4; i++)
#pragma unroll
    for (int j = 0; j < 4; j++) acc[i][j] = 0.f;

  for (int k0 = 0; k0 < K; k0 += BKt) {
#pragma unroll
    for (int i = 0; i < 4; i++) {
      int idx = tid + i * 256;
      int am = idx >> 4, ak = idx & 15;
      int gm = m0 + am, gk = k0 + ak;
      float va = 0.f;
      if (gm < M && gk < K) va = A[(size_t)gm * K + gk];
      As[ak][am] = va;
    }
#pragma unroll
    for (int i = 0; i < 4; i++) {
      int idx = tid + i * 256;
      float vb = 0.f;
      if (BT) {
        int bn = idx >> 4, bk = idx & 15;
        int gn = n0 + bn, gk = k0 + bk;
        if (gn < N && gk < K) vb = Bm[(size_t)gn * K + gk];
        Bs[bk][bn] = vb;
      } else {
        int bk = idx >> 6, bn = idx & 63;
        int gk = k0 + bk, gn = n0 + bn;
        if (gk < K && gn < N) vb = Bm[(size_t)gk * N + gn];
        Bs[bk][bn] = vb;
      }
    }
    __syncthreads();
#pragma unroll
    for (int kk = 0; kk < BKt; kk++) {
      float a[4], b[4];
#pragma unroll
      for (int i = 0; i < 4; i++) a[i] = As[kk][ty * 4 + i];
#pragma unroll
      for (int j = 0; j < 4; j++) b[j] = Bs[kk][tx * 4 + j];
#pragma unroll
      for (int i = 0; i < 4; i++)
#pragma unroll
        for (int j = 0; j < 4; j++) acc[i][j] = fmaf(a[i], b[j], acc[i][j]);
    }
    __syncthreads();
  }
#pragma unroll
  for (int i = 0; i < 4; i++) {
    int gm = m0 + ty * 4 + i;
    if (gm >= M) continue;
#pragma unroll
    for (int j = 0; j < 4; j++) {
      int gn = n0 + tx * 4 + j;
      if (gn >= N) continue;
      float c = acc[i][j];
      if (EPI == EPI_BIAS) c += bias[gn];
      if (EPI == EPI_TANH) c = tanhf(c);
      if (EPI == EPI_RELU) c = fmaxf(c, 0.f);
      Cm[(size_t)gm * N + gn] = c;
    }
  }
}

// ------------------------------------------------------------------ wkv6 ---
// One wave per (b,h). Lane = value index i. S[j] = state row j, column i.
// y_i = sum_j r_j*(S[j,i] + u_j*k_j*v_i);  S[j,i] = w_j*S[j,i] + k_j*v_i.
__global__ __launch_bounds__(64) void k_wkv(
    const float* __restrict__ r, const float* __restrict__ k,
    const float* __restrict__ v, const float* __restrict__ w,
    const float* __restrict__ u, float* __restrict__ y,
    int B, int T, int C, int H) {
  int bh = blockIdx.x;
  int b = bh / H, h = bh - bh / H * H;
  int lane = threadIdx.x;
  const int hs = 64;
  float S[64];
#pragma unroll
  for (int j = 0; j < 64; j++) S[j] = 0.f;
  __shared__ __attribute__((aligned(16))) float sr[64];
  __shared__ __attribute__((aligned(16))) float sk[64];
  __shared__ __attribute__((aligned(16))) float sw[64];
  __shared__ __attribute__((aligned(16))) float su[64];
  su[lane] = u[h * hs + lane];
  __syncthreads();
  long base = (long)b * T * C + h * hs;
  for (int t = 0; t < T; t++) {
    long off = base + (long)t * C;
    float rv = r[off + lane];
    float kv = k[off + lane];
    float wv = expf(-expf(w[off + lane]));
    sr[lane] = rv; sk[lane] = kv; sw[lane] = wv;
    __syncthreads();
    float vi = v[off + lane];
    float acc = 0.f;
#define WKV_STEP(RR, KK, WW, UU, JJ)                      \
    {                                                     \
      float kvp = (KK) * vi;                              \
      float tmp = fmaf((UU), kvp, S[JJ]);                 \
      acc = fmaf((RR), tmp, acc);                         \
      S[JJ] = fmaf((WW), S[JJ], kvp);                     \
    }
#pragma unroll
    for (int j0 = 0; j0 < 64; j0 += 4) {
      float4 r4 = *(const float4*)(sr + j0);
      float4 k4 = *(const float4*)(sk + j0);
      float4 w4 = *(const float4*)(sw + j0);
      float4 u4 = *(const float4*)(su + j0);
      WKV_STEP(r4.x, k4.x, w4.x, u4.x, j0 + 0)
      WKV_STEP(r4.y, k4.y, w4.y, u4.y, j0 + 1)
      WKV_STEP(r4.z, k4.z, w4.z, u4.z, j0 + 2)
      WKV_STEP(r4.w, k4.w, w4.w, u4.w, j0 + 3)
    }
#undef WKV_STEP
    y[off + lane] = acc;
    __syncthreads();
  }
}

// ----------------------------------------------------- groupnorm * gate ---
// block = 768 threads (one per channel); each 64-lane wave == one group.
__global__ __launch_bounds__(768) void k_gnmul(
    const float* __restrict__ y, const float* __restrict__ g,
    const float* __restrict__ ln_w, const float* __restrict__ ln_b,
    float* __restrict__ z, int C) {
  long row = blockIdx.x;
  int c = threadIdx.x;
  long off = row * C + c;
  float val = y[off];
  float s = val;
#pragma unroll
  for (int o = 32; o >= 1; o >>= 1) s += __shfl_xor(s, o, 64);
  float mu = s * (1.f / 64.f);
  float d = val - mu;
  float vs = d * d;
#pragma unroll
  for (int o = 32; o >= 1; o >>= 1) vs += __shfl_xor(vs, o, 64);
  float var = vs * (1.f / 64.f);
  float nrm = d * rsqrtf(var + 1e-5f);
  z[off] = (nrm * ln_w[c] + ln_b[c]) * g[off];
}

// ---------------------------------------------------------------- launch ---
extern "C" void kernel_launch(void* const* d_in, const int* in_sizes, int n_in,
                              void* d_out, int out_size, void* d_ws, size_t ws_size,
                              hipStream_t stream) {
  const int B = 8, T = 1024, C = 768, H = 12, ph = 32, pw = 32;
  const int M = B * T;

  const float* x        = (const float*)d_in[0];
  const float* W_r      = (const float*)d_in[1];
  const float* W_k      = (const float*)d_in[2];
  const float* W_v      = (const float*)d_in[3];
  const float* W_g      = (const float*)d_in[4];
  const float* W_o      = (const float*)d_in[5];
  const float* maa_x    = (const float*)d_in[6];
  const float* maa_w    = (const float*)d_in[7];
  const float* maa_k    = (const float*)d_in[8];
  const float* maa_v    = (const float*)d_in[9];
  const float* maa_r    = (const float*)d_in[10];
  const float* maa_g    = (const float*)d_in[11];
  const float* maa_w1   = (const float*)d_in[12];
  const float* maa_w2   = (const float*)d_in[13];
  const float* time_dec = (const float*)d_in[14];
  const float* dec_w1   = (const float*)d_in[15];
  const float* dec_w2   = (const float*)d_in[16];
  const float* faaaa    = (const float*)d_in[17];
  const float* ln_w     = (const float*)d_in[18];
  const float* ln_b     = (const float*)d_in[19];

  float* ws = (float*)d_ws;
  const size_t S = (size_t)M * C;
  float* b_xx  = ws + 0 * S;  // xx   -> r
  float* b_xxx = ws + 1 * S;  // xxx  -> k
  float* b_xw  = ws + 2 * S;  // xw   -> w
  float* b_xk  = ws + 3 * S;  // xk   -> v
  float* b_xv  = ws + 4 * S;  // xv   -> g
  float* b_xr  = ws + 5 * S;  // xr   -> y
  float* b_xg  = ws + 6 * S;  // xg   -> z
  float* t5    = ws + 7 * S;            // [M,160]
  float* t6    = t5 + (size_t)M * 160;  // [M,64]

  float* rb = b_xx;  float* kb = b_xxx; float* wb = b_xw;
  float* vb = b_xk;  float* gb = b_xv;  float* yb = b_xr; float* zb = b_xg;

  // 1. qshift
  {
    long total = (long)M * C;
    k_qshift<<<(int)((total + 255) / 256), 256, 0, stream>>>(
        x, maa_x, b_xx, b_xxx, B, T, C, ph, pw);
  }
  // 2. t5 = tanh(xxx @ maa_w1)   [M,768]@[768,160]
  {
    dim3 grid((160 + 63) / 64, (M + 63) / 64);
    k_gemm<EPI_TANH, false><<<grid, 256, 0, stream>>>(b_xxx, maa_w1, nullptr, t5, M, 160, C);
  }
  // 3. mix5
  k_mix5<<<M / 4, 256, 0, stream>>>(x, b_xx, t5, maa_w2, maa_w, maa_k, maa_v,
                                    maa_r, maa_g, b_xw, b_xk, b_xv, b_xr, b_xg, C);
  // 4. projections
  {
    dim3 grid(C / 64, M / 64);
    k_gemm<EPI_NONE, true><<<grid, 256, 0, stream>>>(b_xr, W_r, nullptr, rb, M, C, C);
    k_gemm<EPI_NONE, true><<<grid, 256, 0, stream>>>(b_xk, W_k, nullptr, kb, M, C, C);
    k_gemm<EPI_NONE, true><<<grid, 256, 0, stream>>>(b_xv, W_v, nullptr, vb, M, C, C);
    k_gemm<EPI_RELU, true><<<grid, 256, 0, stream>>>(b_xg, W_g, nullptr, gb, M, C, C);
    dim3 grid1((64 + 63) / 64, M / 64);
    k_gemm<EPI_TANH, false><<<grid1, 256, 0, stream>>>(b_xw, dec_w1, nullptr, t6, M, 64, C);
    k_gemm<EPI_BIAS, false><<<grid, 256, 0, stream>>>(t6, dec_w2, time_dec, wb, M, C, 64);
  }
  // 5. wkv6
  k_wkv<<<B * H, 64, 0, stream>>>(rb, kb, vb, wb, faaaa, yb, B, T, C, H);
  // 6. groupnorm * gate
  k_gnmul<<<M, 768, 0, stream>>>(yb, gb, ln_w, ln_b, zb, C);
  // 7. out = z @ W_o^T
  {
    dim3 grid(C / 64, M / 64);
    k_gemm<EPI_NONE, true><<<grid, 256, 0, stream>>>(zb, W_o, nullptr, (float*)d_out, M, C, C);
  }
}

// Round 2
// 2371.755 us; speedup vs baseline: 1.5571x; 1.5571x over previous
//
#include <hip/hip_runtime.h>
#include <math.h>

// ---------------------------------------------------------------------------
// TimeMix (RWKV-6 vision block) — round 2: chunked-parallel WKV (L=64).
// B=8, T=1024 (32x32), C=768, H=12 heads of 64.
// ---------------------------------------------------------------------------

#define EPI_NONE 0
#define EPI_TANH 1
#define EPI_RELU 2
#define EPI_BIAS 3

#define LPAD 68   // LDS row stride (floats) for 64-wide chunk tiles

// ---------------------------------------------------------------- qshift ---
__global__ __launch_bounds__(256) void k_qshift(
    const float* __restrict__ x, const float* __restrict__ maa_x,
    float* __restrict__ xx, float* __restrict__ xxx,
    int B, int T, int C, int ph, int pw) {
  long idx = (long)blockIdx.x * blockDim.x + threadIdx.x;
  long total = (long)B * T * C;
  if (idx >= total) return;
  int c = (int)(idx % C);
  long bt = idx / C;
  int t = (int)(bt % T);
  int hc = c & 63;
  int quarter = hc >> 4;
  int hh = t / pw;
  int ww = t - hh * pw;
  long rowbase = (bt - t) * C;
  float sval = 0.f;
  int st = -1;
  if (quarter == 0)      { if (ww >= 1)      st = t - 1;  }
  else if (quarter == 1) { if (ww < pw - 1)  st = t + 1;  }
  else if (quarter == 2) { if (hh >= 1)      st = t - pw; }
  else                   { if (hh < ph - 1)  st = t + pw; }
  if (st >= 0) sval = x[rowbase + (long)st * C + c];
  float xval = x[idx];
  float d = sval - xval;
  xx[idx] = d;
  xxx[idx] = xval + d * maa_x[c];
}

// ------------------------------------------------------------------ mix5 ---
__global__ __launch_bounds__(256) void k_mix5(
    const float* __restrict__ x, const float* __restrict__ xx,
    const float* __restrict__ t5, const float* __restrict__ maa_w2,
    const float* __restrict__ maa_w, const float* __restrict__ maa_k,
    const float* __restrict__ maa_v, const float* __restrict__ maa_r,
    const float* __restrict__ maa_g,
    float* __restrict__ xw, float* __restrict__ xk, float* __restrict__ xvb,
    float* __restrict__ xr, float* __restrict__ xg, int C) {
  const int ROWS = 4;
  int row0 = blockIdx.x * ROWS;
  __shared__ float st[ROWS][160];
  int tid = threadIdx.x;
  for (int i = tid; i < ROWS * 160; i += 256) {
    int q = i / 160, rr = i - q * 160;
    st[q][rr] = t5[(long)(row0 + q) * 160 + rr];
  }
  __syncthreads();
  for (int c = tid; c < C; c += 256) {
    float acc[ROWS][5];
#pragma unroll
    for (int q = 0; q < ROWS; q++)
#pragma unroll
      for (int f = 0; f < 5; f++) acc[q][f] = 0.f;
#pragma unroll
    for (int f = 0; f < 5; f++) {
#pragma unroll
      for (int rr = 0; rr < 32; rr++) {
        float wv = maa_w2[(long)(f * 32 + rr) * C + c];
#pragma unroll
        for (int q = 0; q < ROWS; q++)
          acc[q][f] = fmaf(st[q][f * 32 + rr], wv, acc[q][f]);
      }
    }
#pragma unroll
    for (int q = 0; q < ROWS; q++) {
      long off = (long)(row0 + q) * C + c;
      float xval = x[off];
      float d = xx[off];
      xw[off]  = xval + d * (maa_w[c] + acc[q][0]);
      xk[off]  = xval + d * (maa_k[c] + acc[q][1]);
      xvb[off] = xval + d * (maa_v[c] + acc[q][2]);
      xr[off]  = xval + d * (maa_r[c] + acc[q][3]);
      xg[off]  = xval + d * (maa_g[c] + acc[q][4]);
    }
  }
}

// ------------------------------------------------------------------ gemm ---
template <int EPI, bool BT>
__global__ __launch_bounds__(256) void k_gemm(
    const float* __restrict__ A, const float* __restrict__ Bm,
    const float* __restrict__ bias, float* __restrict__ Cm,
    int M, int N, int K) {
  const int BMt = 64, BNt = 64, BKt = 16;
  __shared__ float As[BKt][BMt];
  __shared__ float Bs[BKt][BNt];
  int tid = (int)threadIdx.x;
  int m0 = blockIdx.y * BMt, n0 = blockIdx.x * BNt;
  int tx = tid & 15, ty = tid >> 4;
  float acc[4][4];
#pragma unroll
  for (int i = 0; i < 4; i++)
#pragma unroll
    for (int j = 0; j < 4; j++) acc[i][j] = 0.f;

  for (int k0 = 0; k0 < K; k0 += BKt) {
#pragma unroll
    for (int i = 0; i < 4; i++) {
      int idx = tid + i * 256;
      int am = idx >> 4, ak = idx & 15;
      int gm = m0 + am, gk = k0 + ak;
      float va = 0.f;
      if (gm < M && gk < K) va = A[(size_t)gm * K + gk];
      As[ak][am] = va;
    }
#pragma unroll
    for (int i = 0; i < 4; i++) {
      int idx = tid + i * 256;
      float vb = 0.f;
      if (BT) {
        int bn = idx >> 4, bk = idx & 15;
        int gn = n0 + bn, gk = k0 + bk;
        if (gn < N && gk < K) vb = Bm[(size_t)gn * K + gk];
        Bs[bk][bn] = vb;
      } else {
        int bk = idx >> 6, bn = idx & 63;
        int gk = k0 + bk, gn = n0 + bn;
        if (gk < K && gn < N) vb = Bm[(size_t)gk * N + gn];
        Bs[bk][bn] = vb;
      }
    }
    __syncthreads();
#pragma unroll
    for (int kk = 0; kk < BKt; kk++) {
      float a[4], b[4];
#pragma unroll
      for (int i = 0; i < 4; i++) a[i] = As[kk][ty * 4 + i];
#pragma unroll
      for (int j = 0; j < 4; j++) b[j] = Bs[kk][tx * 4 + j];
#pragma unroll
      for (int i = 0; i < 4; i++)
#pragma unroll
        for (int j = 0; j < 4; j++) acc[i][j] = fmaf(a[i], b[j], acc[i][j]);
    }
    __syncthreads();
  }
#pragma unroll
  for (int i = 0; i < 4; i++) {
    int gm = m0 + ty * 4 + i;
    if (gm >= M) continue;
#pragma unroll
    for (int j = 0; j < 4; j++) {
      int gn = n0 + tx * 4 + j;
      if (gn >= N) continue;
      float c = acc[i][j];
      if (EPI == EPI_BIAS) c += bias[gn];
      if (EPI == EPI_TANH) c = tanhf(c);
      if (EPI == EPI_RELU) c = fmaxf(c, 0.f);
      Cm[(size_t)gm * N + gn] = c;
    }
  }
}

// ------------------------------------------------- chunked WKV: phase pre --
// grid = B*H*nchunk blocks, 64 threads (thread = j).
// Writes rt = r*exp(-cum_tau), kt = k*exp(+cum_{tau+1}) (in-place over w),
// aL[bh,c,j] = exp(-cum_L), pdiag[bh,t] = sum_j r*u*k.
__global__ __launch_bounds__(64) void k_wkv_pre(
    const float* __restrict__ r, const float* __restrict__ k,
    const float* __restrict__ w, const float* __restrict__ u,
    float* __restrict__ rt, float* __restrict__ kt,
    float* __restrict__ aL, float* __restrict__ pdiag,
    int B, int T, int C, int H, int L) {
  int nch = T / L;
  int blk = blockIdx.x;
  int bh = blk / nch, c = blk - bh * nch;
  int b = bh / H, h = bh - b * H;
  int j = threadIdx.x;
  float uj = u[h * 64 + j];
  float cum = 0.f;
  long base = ((long)b * T + (long)c * L) * C + h * 64 + j;
  for (int tau = 0; tau < L; tau++) {
    long off = base + (long)tau * C;
    float wv = w[off];   // read before kt (aliased) write
    float rv = r[off];
    float kv = k[off];
    float e = expf(wv);
    rt[off] = rv * expf(-cum);
    cum += e;
    kt[off] = kv * expf(cum);
    float pd = rv * uj * kv;
#pragma unroll
    for (int o = 32; o >= 1; o >>= 1) pd += __shfl_xor(pd, o, 64);
    if (j == 0) pdiag[(long)bh * T + c * L + tau] = pd;
  }
  aL[((long)bh * nch + c) * 64 + j] = expf(-cum);
}

// ----------------------------------------------- chunked WKV: state prop ---
// grid = B*H blocks, 256 threads (lane=i value idx, wave jg = j-group of 16).
// Sequential over chunks: y_inter = Rt @ S ; S = aL * (S + Kt^T V).
__global__ __launch_bounds__(256) void k_wkv_state(
    const float* __restrict__ rt, const float* __restrict__ kt,
    const float* __restrict__ v, const float* __restrict__ aL,
    float* __restrict__ y, int B, int T, int C, int H, int L) {
  int bh = blockIdx.x;
  int b = bh / H, h = bh - b * H;
  int nch = T / L;
  __shared__ float Rs[64 * LPAD];
  __shared__ float Ks[64 * LPAD];
  __shared__ float Vs[64 * LPAD];
  __shared__ float Yp[4][512];
  int tid = threadIdx.x;
  int lane = tid & 63;   // i
  int jg = tid >> 6;     // 0..3
  float S[16];
#pragma unroll
  for (int q = 0; q < 16; q++) S[q] = 0.f;
  long hbase = (long)b * T * C + h * 64;
  for (int c = 0; c < nch; c++) {
    long cbase = hbase + (long)c * L * C;
    // load Rt, Kt, V chunk -> LDS
#pragma unroll
    for (int q = 0; q < 4; q++) {
      int idx = tid + q * 256;
      int row = idx >> 4, col = (idx & 15) * 4;
      long g = cbase + (long)row * C + col;
      *(float4*)(Rs + row * LPAD + col) = *(const float4*)(rt + g);
      *(float4*)(Ks + row * LPAD + col) = *(const float4*)(kt + g);
      *(float4*)(Vs + row * LPAD + col) = *(const float4*)(v + g);
    }
    __syncthreads();
    // y_inter = Rt @ S, in 8-row passes with 4-way partial reduce
    for (int p = 0; p < 8; p++) {
      float acc[8];
#pragma unroll
      for (int t8 = 0; t8 < 8; t8++) {
        int tau = p * 8 + t8;
        float a0 = 0.f, a1 = 0.f, a2 = 0.f, a3 = 0.f;
#pragma unroll
        for (int q4 = 0; q4 < 4; q4++) {
          float4 rr = *(const float4*)(Rs + tau * LPAD + jg * 16 + q4 * 4);
          a0 = fmaf(rr.x, S[q4 * 4 + 0], a0);
          a1 = fmaf(rr.y, S[q4 * 4 + 1], a1);
          a2 = fmaf(rr.z, S[q4 * 4 + 2], a2);
          a3 = fmaf(rr.w, S[q4 * 4 + 3], a3);
        }
        acc[t8] = (a0 + a1) + (a2 + a3);
      }
#pragma unroll
      for (int t8 = 0; t8 < 8; t8++) Yp[jg][t8 * 64 + lane] = acc[t8];
      __syncthreads();
      {
        int ii = tid & 63;
#pragma unroll
        for (int s = 0; s < 2; s++) {
          int t8 = (tid >> 6) + s * 4;
          float sum = Yp[0][t8 * 64 + ii] + Yp[1][t8 * 64 + ii] +
                      Yp[2][t8 * 64 + ii] + Yp[3][t8 * 64 + ii];
          y[cbase + (long)(p * 8 + t8) * C + ii] = sum;
        }
      }
      __syncthreads();
    }
    // state update: S = aL * (S + Kt^T V)
    float acc2[16];
#pragma unroll
    for (int q = 0; q < 16; q++) acc2[q] = 0.f;
    for (int s = 0; s < 64; s++) {
      float vi = Vs[s * LPAD + lane];
#pragma unroll
      for (int q4 = 0; q4 < 4; q4++) {
        float4 kk = *(const float4*)(Ks + s * LPAD + jg * 16 + q4 * 4);
        acc2[q4 * 4 + 0] = fmaf(kk.x, vi, acc2[q4 * 4 + 0]);
        acc2[q4 * 4 + 1] = fmaf(kk.y, vi, acc2[q4 * 4 + 1]);
        acc2[q4 * 4 + 2] = fmaf(kk.z, vi, acc2[q4 * 4 + 2]);
        acc2[q4 * 4 + 3] = fmaf(kk.w, vi, acc2[q4 * 4 + 3]);
      }
    }
    const float* aLc = aL + ((long)bh * nch + c) * 64 + jg * 16;
#pragma unroll
    for (int q = 0; q < 16; q++) S[q] = aLc[q] * (S[q] + acc2[q]);
    __syncthreads();
  }
}

// ---------------------------------------------- chunked WKV: intra-chunk ---
// grid = B*H*nchunk blocks, 256 threads.
// P = mask(Rt @ Kt^T) + diag(pdiag);  y += P @ V.
__global__ __launch_bounds__(256) void k_wkv_intra(
    const float* __restrict__ rt, const float* __restrict__ kt,
    const float* __restrict__ v, const float* __restrict__ pdiag,
    float* __restrict__ y, int B, int T, int C, int H, int L) {
  int nch = T / L;
  int blk = blockIdx.x;
  int bh = blk / nch, c = blk - bh * nch;
  int b = bh / H, h = bh - b * H;
  __shared__ float RPs[64 * LPAD];   // Rt tile, then reused as P^T
  __shared__ float Ks[64 * LPAD];
  __shared__ float Vs[64 * LPAD];
  int tid = threadIdx.x;
  long cbase = ((long)b * T + (long)c * L) * C + h * 64;
#pragma unroll
  for (int q = 0; q < 4; q++) {
    int idx = tid + q * 256;
    int row = idx >> 4, col = (idx & 15) * 4;
    long g = cbase + (long)row * C + col;
    *(float4*)(RPs + row * LPAD + col) = *(const float4*)(rt + g);
    *(float4*)(Ks + row * LPAD + col) = *(const float4*)(kt + g);
    *(float4*)(Vs + row * LPAD + col) = *(const float4*)(v + g);
  }
  __syncthreads();
  // phase P: thread = (sg = tid>>6, tau = tid&63)
  int tau = tid & 63, sg = tid >> 6;
  float4 rreg[16];
#pragma unroll
  for (int q = 0; q < 16; q++)
    rreg[q] = *(const float4*)(RPs + tau * LPAD + q * 4);
  float pd = pdiag[(long)bh * T + c * L + tau];
  __syncthreads();   // Rt reads done; RPs becomes P^T storage
#pragma unroll 2
  for (int ss = 0; ss < 16; ss++) {
    int s = sg * 16 + ss;
    float a0 = 0.f, a1 = 0.f, a2 = 0.f, a3 = 0.f;
#pragma unroll
    for (int q = 0; q < 16; q++) {
      float4 kk = *(const float4*)(Ks + s * LPAD + q * 4);
      a0 = fmaf(rreg[q].x, kk.x, a0);
      a1 = fmaf(rreg[q].y, kk.y, a1);
      a2 = fmaf(rreg[q].z, kk.z, a2);
      a3 = fmaf(rreg[q].w, kk.w, a3);
    }
    float a = (a0 + a1) + (a2 + a3);
    float val = (s < tau) ? a : (s == tau ? pd : 0.f);
    RPs[s * LPAD + tau] = val;   // P^T[s][tau]
  }
  __syncthreads();
  // phase Y: y[tau,i] += sum_s P^T[s][tau] * V[s][i]
  int i = tid & 63, tg = tid >> 6;
  float acc[16];
#pragma unroll
  for (int q = 0; q < 16; q++) acc[q] = 0.f;
  for (int s = 0; s < 64; s++) {
    float vi = Vs[s * LPAD + i];
#pragma unroll
    for (int q4 = 0; q4 < 4; q4++) {
      float4 pp = *(const float4*)(RPs + s * LPAD + tg * 16 + q4 * 4);
      acc[q4 * 4 + 0] = fmaf(pp.x, vi, acc[q4 * 4 + 0]);
      acc[q4 * 4 + 1] = fmaf(pp.y, vi, acc[q4 * 4 + 1]);
      acc[q4 * 4 + 2] = fmaf(pp.z, vi, acc[q4 * 4 + 2]);
      acc[q4 * 4 + 3] = fmaf(pp.w, vi, acc[q4 * 4 + 3]);
    }
  }
#pragma unroll
  for (int q = 0; q < 16; q++) {
    long off = cbase + (long)(tg * 16 + q) * C + i;
    y[off] += acc[q];
  }
}

// ----------------------------------------------------- groupnorm * gate ---
__global__ __launch_bounds__(768) void k_gnmul(
    const float* __restrict__ y, const float* __restrict__ g,
    const float* __restrict__ ln_w, const float* __restrict__ ln_b,
    float* __restrict__ z, int C) {
  long row = blockIdx.x;
  int c = threadIdx.x;
  long off = row * C + c;
  float val = y[off];
  float s = val;
#pragma unroll
  for (int o = 32; o >= 1; o >>= 1) s += __shfl_xor(s, o, 64);
  float mu = s * (1.f / 64.f);
  float d = val - mu;
  float vs = d * d;
#pragma unroll
  for (int o = 32; o >= 1; o >>= 1) vs += __shfl_xor(vs, o, 64);
  float var = vs * (1.f / 64.f);
  float nrm = d * rsqrtf(var + 1e-5f);
  z[off] = (nrm * ln_w[c] + ln_b[c]) * g[off];
}

// ---------------------------------------------------------------- launch ---
extern "C" void kernel_launch(void* const* d_in, const int* in_sizes, int n_in,
                              void* d_out, int out_size, void* d_ws, size_t ws_size,
                              hipStream_t stream) {
  const int B = 8, T = 1024, C = 768, H = 12, ph = 32, pw = 32;
  const int M = B * T;
  const int L = 64, NCH = T / L;

  const float* x        = (const float*)d_in[0];
  const float* W_r      = (const float*)d_in[1];
  const float* W_k      = (const float*)d_in[2];
  const float* W_v      = (const float*)d_in[3];
  const float* W_g      = (const float*)d_in[4];
  const float* W_o      = (const float*)d_in[5];
  const float* maa_x    = (const float*)d_in[6];
  const float* maa_w    = (const float*)d_in[7];
  const float* maa_k    = (const float*)d_in[8];
  const float* maa_v    = (const float*)d_in[9];
  const float* maa_r    = (const float*)d_in[10];
  const float* maa_g    = (const float*)d_in[11];
  const float* maa_w1   = (const float*)d_in[12];
  const float* maa_w2   = (const float*)d_in[13];
  const float* time_dec = (const float*)d_in[14];
  const float* dec_w1   = (const float*)d_in[15];
  const float* dec_w2   = (const float*)d_in[16];
  const float* faaaa    = (const float*)d_in[17];
  const float* ln_w     = (const float*)d_in[18];
  const float* ln_b     = (const float*)d_in[19];

  float* ws = (float*)d_ws;
  const size_t S = (size_t)M * C;
  float* b_xx  = ws + 0 * S;  // xx   -> r
  float* b_xxx = ws + 1 * S;  // xxx  -> k
  float* b_xw  = ws + 2 * S;  // xw   -> w -> Kt (in place)
  float* b_xk  = ws + 3 * S;  // xk   -> v
  float* b_xv  = ws + 4 * S;  // xv   -> g
  float* b_xr  = ws + 5 * S;  // xr   -> y
  float* b_xg  = ws + 6 * S;  // xg   -> Rt -> z
  float* t5    = ws + 7 * S;            // [M,160]
  float* t6    = t5 + (size_t)M * 160;  // [M,64]
  float* aLb   = t6 + (size_t)M * 64;   // [B*H, NCH, 64]
  float* pdiag = aLb + (size_t)B * H * NCH * 64;  // [B*H, T]

  float* rb = b_xx;  float* kb = b_xxx; float* wb = b_xw;
  float* vb = b_xk;  float* gb = b_xv;  float* yb = b_xr; float* zb = b_xg;
  float* rtb = b_xg;  // Rt overwrites xg (after g GEMM consumed it)
  float* ktb = b_xw;  // Kt overwrites w in place

  // 1. qshift
  {
    long total = (long)M * C;
    k_qshift<<<(int)((total + 255) / 256), 256, 0, stream>>>(
        x, maa_x, b_xx, b_xxx, B, T, C, ph, pw);
  }
  // 2. t5 = tanh(xxx @ maa_w1)
  {
    dim3 grid((160 + 63) / 64, (M + 63) / 64);
    k_gemm<EPI_TANH, false><<<grid, 256, 0, stream>>>(b_xxx, maa_w1, nullptr, t5, M, 160, C);
  }
  // 3. mix5
  k_mix5<<<M / 4, 256, 0, stream>>>(x, b_xx, t5, maa_w2, maa_w, maa_k, maa_v,
                                    maa_r, maa_g, b_xw, b_xk, b_xv, b_xr, b_xg, C);
  // 4. projections
  {
    dim3 grid(C / 64, M / 64);
    k_gemm<EPI_NONE, true><<<grid, 256, 0, stream>>>(b_xr, W_r, nullptr, rb, M, C, C);
    k_gemm<EPI_NONE, true><<<grid, 256, 0, stream>>>(b_xk, W_k, nullptr, kb, M, C, C);
    k_gemm<EPI_NONE, true><<<grid, 256, 0, stream>>>(b_xv, W_v, nullptr, vb, M, C, C);
    k_gemm<EPI_RELU, true><<<grid, 256, 0, stream>>>(b_xg, W_g, nullptr, gb, M, C, C);
    dim3 grid1(1, M / 64);
    k_gemm<EPI_TANH, false><<<grid1, 256, 0, stream>>>(b_xw, dec_w1, nullptr, t6, M, 64, C);
    k_gemm<EPI_BIAS, false><<<grid, 256, 0, stream>>>(t6, dec_w2, time_dec, wb, M, C, 64);
  }
  // 5. chunked wkv6
  k_wkv_pre<<<B * H * NCH, 64, 0, stream>>>(rb, kb, wb, faaaa, rtb, ktb,
                                            aLb, pdiag, B, T, C, H, L);
  k_wkv_state<<<B * H, 256, 0, stream>>>(rtb, ktb, vb, aLb, yb, B, T, C, H, L);
  k_wkv_intra<<<B * H * NCH, 256, 0, stream>>>(rtb, ktb, vb, pdiag, yb, B, T, C, H, L);
  // 6. groupnorm * gate
  k_gnmul<<<M, 768, 0, stream>>>(yb, gb, ln_w, ln_b, zb, C);
  // 7. out = z @ W_o^T
  {
    dim3 grid(C / 64, M / 64);
    k_gemm<EPI_NONE, true><<<grid, 256, 0, stream>>>(zb, W_o, nullptr, (float*)d_out, M, C, C);
  }
}

// Round 3
// 1857.858 us; speedup vs baseline: 1.9878x; 1.2766x over previous
//
#include <hip/hip_runtime.h>
#include <math.h>

// ---------------------------------------------------------------------------
// TimeMix (RWKV-6 vision block) — round 3: mix5 as tiled GEMM + fused epilogue.
// B=8, T=1024 (32x32), C=768, H=12 heads of 64.
// ---------------------------------------------------------------------------

#define EPI_NONE 0
#define EPI_TANH 1
#define EPI_RELU 2
#define EPI_BIAS 3

#define LPAD 68   // LDS row stride (floats) for 64-wide chunk tiles

// ---------------------------------------------------------------- qshift ---
__global__ __launch_bounds__(256) void k_qshift(
    const float* __restrict__ x, const float* __restrict__ maa_x,
    float* __restrict__ xx, float* __restrict__ xxx,
    int B, int T, int C, int ph, int pw) {
  long idx = (long)blockIdx.x * blockDim.x + threadIdx.x;
  long total = (long)B * T * C;
  if (idx >= total) return;
  int c = (int)(idx % C);
  long bt = idx / C;
  int t = (int)(bt % T);
  int hc = c & 63;
  int quarter = hc >> 4;
  int hh = t / pw;
  int ww = t - hh * pw;
  long rowbase = (bt - t) * C;
  float sval = 0.f;
  int st = -1;
  if (quarter == 0)      { if (ww >= 1)      st = t - 1;  }
  else if (quarter == 1) { if (ww < pw - 1)  st = t + 1;  }
  else if (quarter == 2) { if (hh >= 1)      st = t - pw; }
  else                   { if (hh < ph - 1)  st = t + pw; }
  if (st >= 0) sval = x[rowbase + (long)st * C + c];
  float xval = x[idx];
  float d = sval - xval;
  xx[idx] = d;
  xxx[idx] = xval + d * maa_x[c];
}

// ---------------------------------------------- mix5 fused GEMM+epilogue ---
// Block = 64 rows x 64 channels. For f in 0..4: acc[f] += t5_slice @ w2_slice.
// Epilogue: x?_f = x + xx*(maa_f + acc[f]) written as float4.
__global__ __launch_bounds__(256) void k_mix5f(
    const float* __restrict__ t5, const float* __restrict__ maa_w2,
    const float* __restrict__ x, const float* __restrict__ xx,
    const float* __restrict__ maa_w, const float* __restrict__ maa_k,
    const float* __restrict__ maa_v, const float* __restrict__ maa_r,
    const float* __restrict__ maa_g,
    float* __restrict__ xw, float* __restrict__ xk, float* __restrict__ xvb,
    float* __restrict__ xr, float* __restrict__ xg, int C) {
  __shared__ float As[64][36];   // [row][k], pad 36 keeps 16B align, breaks conflicts
  __shared__ float Bs[32][64];   // [k][col]
  int tid = threadIdx.x;
  int m0 = blockIdx.y * 64, n0 = blockIdx.x * 64;
  int tx = tid & 15, ty = tid >> 4;
  float acc[5][4][4];
#pragma unroll
  for (int f = 0; f < 5; f++)
#pragma unroll
    for (int i = 0; i < 4; i++)
#pragma unroll
      for (int j = 0; j < 4; j++) acc[f][i][j] = 0.f;

#pragma unroll
  for (int f = 0; f < 5; f++) {
    {  // t5 tile: rows m0..m0+63, cols f*32..f*32+31
      int k4 = (tid & 7) * 4;
      int row = tid >> 3;  // 0..31
      const float* src = t5 + (size_t)(m0 + row) * 160 + f * 32 + k4;
      float4 v0 = *(const float4*)src;
      float4 v1 = *(const float4*)(src + 32 * 160);
      *(float4*)(&As[row][k4]) = v0;
      *(float4*)(&As[row + 32][k4]) = v1;
    }
    {  // maa_w2 slice: rows f*32..+31, cols n0..n0+63
      int col = (tid & 15) * 4, kk = tid >> 4;  // kk 0..15
      const float* src = maa_w2 + (size_t)(f * 32 + kk) * C + n0 + col;
      *(float4*)(&Bs[kk][col]) = *(const float4*)src;
      *(float4*)(&Bs[kk + 16][col]) = *(const float4*)(src + (size_t)16 * C);
    }
    __syncthreads();
#pragma unroll
    for (int kk = 0; kk < 32; kk++) {
      float4 b4 = *(const float4*)(&Bs[kk][tx * 4]);
#pragma unroll
      for (int i = 0; i < 4; i++) {
        float a = As[ty * 4 + i][kk];
        acc[f][i][0] = fmaf(a, b4.x, acc[f][i][0]);
        acc[f][i][1] = fmaf(a, b4.y, acc[f][i][1]);
        acc[f][i][2] = fmaf(a, b4.z, acc[f][i][2]);
        acc[f][i][3] = fmaf(a, b4.w, acc[f][i][3]);
      }
    }
    __syncthreads();
  }
  // epilogue
  int cb = n0 + tx * 4;
  float4 mw = *(const float4*)(maa_w + cb);
  float4 mk = *(const float4*)(maa_k + cb);
  float4 mv = *(const float4*)(maa_v + cb);
  float4 mr = *(const float4*)(maa_r + cb);
  float4 mg = *(const float4*)(maa_g + cb);
#pragma unroll
  for (int i = 0; i < 4; i++) {
    size_t off = (size_t)(m0 + ty * 4 + i) * C + cb;
    float4 xv = *(const float4*)(x + off);
    float4 dd = *(const float4*)(xx + off);
    float4 o;
    o.x = xv.x + dd.x * (mw.x + acc[0][i][0]);
    o.y = xv.y + dd.y * (mw.y + acc[0][i][1]);
    o.z = xv.z + dd.z * (mw.z + acc[0][i][2]);
    o.w = xv.w + dd.w * (mw.w + acc[0][i][3]);
    *(float4*)(xw + off) = o;
    o.x = xv.x + dd.x * (mk.x + acc[1][i][0]);
    o.y = xv.y + dd.y * (mk.y + acc[1][i][1]);
    o.z = xv.z + dd.z * (mk.z + acc[1][i][2]);
    o.w = xv.w + dd.w * (mk.w + acc[1][i][3]);
    *(float4*)(xk + off) = o;
    o.x = xv.x + dd.x * (mv.x + acc[2][i][0]);
    o.y = xv.y + dd.y * (mv.y + acc[2][i][1]);
    o.z = xv.z + dd.z * (mv.z + acc[2][i][2]);
    o.w = xv.w + dd.w * (mv.w + acc[2][i][3]);
    *(float4*)(xvb + off) = o;
    o.x = xv.x + dd.x * (mr.x + acc[3][i][0]);
    o.y = xv.y + dd.y * (mr.y + acc[3][i][1]);
    o.z = xv.z + dd.z * (mr.z + acc[3][i][2]);
    o.w = xv.w + dd.w * (mr.w + acc[3][i][3]);
    *(float4*)(xr + off) = o;
    o.x = xv.x + dd.x * (mg.x + acc[4][i][0]);
    o.y = xv.y + dd.y * (mg.y + acc[4][i][1]);
    o.z = xv.z + dd.z * (mg.z + acc[4][i][2]);
    o.w = xv.w + dd.w * (mg.w + acc[4][i][3]);
    *(float4*)(xg + off) = o;
  }
}

// ------------------------------------------------------------------ gemm ---
template <int EPI, bool BT>
__global__ __launch_bounds__(256) void k_gemm(
    const float* __restrict__ A, const float* __restrict__ Bm,
    const float* __restrict__ bias, float* __restrict__ Cm,
    int M, int N, int K) {
  const int BMt = 64, BNt = 64, BKt = 16;
  __shared__ float As[BKt][BMt];
  __shared__ float Bs[BKt][BNt];
  int tid = (int)threadIdx.x;
  int m0 = blockIdx.y * BMt, n0 = blockIdx.x * BNt;
  int tx = tid & 15, ty = tid >> 4;
  float acc[4][4];
#pragma unroll
  for (int i = 0; i < 4; i++)
#pragma unroll
    for (int j = 0; j < 4; j++) acc[i][j] = 0.f;

  for (int k0 = 0; k0 < K; k0 += BKt) {
#pragma unroll
    for (int i = 0; i < 4; i++) {
      int idx = tid + i * 256;
      int am = idx >> 4, ak = idx & 15;
      int gm = m0 + am, gk = k0 + ak;
      float va = 0.f;
      if (gm < M && gk < K) va = A[(size_t)gm * K + gk];
      As[ak][am] = va;
    }
#pragma unroll
    for (int i = 0; i < 4; i++) {
      int idx = tid + i * 256;
      float vb = 0.f;
      if (BT) {
        int bn = idx >> 4, bk = idx & 15;
        int gn = n0 + bn, gk = k0 + bk;
        if (gn < N && gk < K) vb = Bm[(size_t)gn * K + gk];
        Bs[bk][bn] = vb;
      } else {
        int bk = idx >> 6, bn = idx & 63;
        int gk = k0 + bk, gn = n0 + bn;
        if (gk < K && gn < N) vb = Bm[(size_t)gk * N + gn];
        Bs[bk][bn] = vb;
      }
    }
    __syncthreads();
#pragma unroll
    for (int kk = 0; kk < BKt; kk++) {
      float a[4], b[4];
#pragma unroll
      for (int i = 0; i < 4; i++) a[i] = As[kk][ty * 4 + i];
#pragma unroll
      for (int j = 0; j < 4; j++) b[j] = Bs[kk][tx * 4 + j];
#pragma unroll
      for (int i = 0; i < 4; i++)
#pragma unroll
        for (int j = 0; j < 4; j++) acc[i][j] = fmaf(a[i], b[j], acc[i][j]);
    }
    __syncthreads();
  }
#pragma unroll
  for (int i = 0; i < 4; i++) {
    int gm = m0 + ty * 4 + i;
    if (gm >= M) continue;
#pragma unroll
    for (int j = 0; j < 4; j++) {
      int gn = n0 + tx * 4 + j;
      if (gn >= N) continue;
      float c = acc[i][j];
      if (EPI == EPI_BIAS) c += bias[gn];
      if (EPI == EPI_TANH) c = tanhf(c);
      if (EPI == EPI_RELU) c = fmaxf(c, 0.f);
      Cm[(size_t)gm * N + gn] = c;
    }
  }
}

// ------------------------------------------------- chunked WKV: phase pre --
__global__ __launch_bounds__(64) void k_wkv_pre(
    const float* __restrict__ r, const float* __restrict__ k,
    const float* __restrict__ w, const float* __restrict__ u,
    float* __restrict__ rt, float* __restrict__ kt,
    float* __restrict__ aL, float* __restrict__ pdiag,
    int B, int T, int C, int H, int L) {
  int nch = T / L;
  int blk = blockIdx.x;
  int bh = blk / nch, c = blk - bh * nch;
  int b = bh / H, h = bh - b * H;
  int j = threadIdx.x;
  float uj = u[h * 64 + j];
  float cum = 0.f;
  long base = ((long)b * T + (long)c * L) * C + h * 64 + j;
  for (int tau = 0; tau < L; tau++) {
    long off = base + (long)tau * C;
    float wv = w[off];
    float rv = r[off];
    float kv = k[off];
    float e = expf(wv);
    rt[off] = rv * expf(-cum);
    cum += e;
    kt[off] = kv * expf(cum);
    float pd = rv * uj * kv;
#pragma unroll
    for (int o = 32; o >= 1; o >>= 1) pd += __shfl_xor(pd, o, 64);
    if (j == 0) pdiag[(long)bh * T + c * L + tau] = pd;
  }
  aL[((long)bh * nch + c) * 64 + j] = expf(-cum);
}

// ----------------------------------------------- chunked WKV: state prop ---
__global__ __launch_bounds__(256) void k_wkv_state(
    const float* __restrict__ rt, const float* __restrict__ kt,
    const float* __restrict__ v, const float* __restrict__ aL,
    float* __restrict__ y, int B, int T, int C, int H, int L) {
  int bh = blockIdx.x;
  int b = bh / H, h = bh - b * H;
  int nch = T / L;
  __shared__ float Rs[64 * LPAD];
  __shared__ float Ks[64 * LPAD];
  __shared__ float Vs[64 * LPAD];
  __shared__ float Yp[4][512];
  int tid = threadIdx.x;
  int lane = tid & 63;
  int jg = tid >> 6;
  float S[16];
#pragma unroll
  for (int q = 0; q < 16; q++) S[q] = 0.f;
  long hbase = (long)b * T * C + h * 64;
  for (int c = 0; c < nch; c++) {
    long cbase = hbase + (long)c * L * C;
#pragma unroll
    for (int q = 0; q < 4; q++) {
      int idx = tid + q * 256;
      int row = idx >> 4, col = (idx & 15) * 4;
      long g = cbase + (long)row * C + col;
      *(float4*)(Rs + row * LPAD + col) = *(const float4*)(rt + g);
      *(float4*)(Ks + row * LPAD + col) = *(const float4*)(kt + g);
      *(float4*)(Vs + row * LPAD + col) = *(const float4*)(v + g);
    }
    __syncthreads();
    for (int p = 0; p < 8; p++) {
      float acc[8];
#pragma unroll
      for (int t8 = 0; t8 < 8; t8++) {
        int tau = p * 8 + t8;
        float a0 = 0.f, a1 = 0.f, a2 = 0.f, a3 = 0.f;
#pragma unroll
        for (int q4 = 0; q4 < 4; q4++) {
          float4 rr = *(const float4*)(Rs + tau * LPAD + jg * 16 + q4 * 4);
          a0 = fmaf(rr.x, S[q4 * 4 + 0], a0);
          a1 = fmaf(rr.y, S[q4 * 4 + 1], a1);
          a2 = fmaf(rr.z, S[q4 * 4 + 2], a2);
          a3 = fmaf(rr.w, S[q4 * 4 + 3], a3);
        }
        acc[t8] = (a0 + a1) + (a2 + a3);
      }
#pragma unroll
      for (int t8 = 0; t8 < 8; t8++) Yp[jg][t8 * 64 + lane] = acc[t8];
      __syncthreads();
      {
        int ii = tid & 63;
#pragma unroll
        for (int s = 0; s < 2; s++) {
          int t8 = (tid >> 6) + s * 4;
          float sum = Yp[0][t8 * 64 + ii] + Yp[1][t8 * 64 + ii] +
                      Yp[2][t8 * 64 + ii] + Yp[3][t8 * 64 + ii];
          y[cbase + (long)(p * 8 + t8) * C + ii] = sum;
        }
      }
      __syncthreads();
    }
    float acc2[16];
#pragma unroll
    for (int q = 0; q < 16; q++) acc2[q] = 0.f;
    for (int s = 0; s < 64; s++) {
      float vi = Vs[s * LPAD + lane];
#pragma unroll
      for (int q4 = 0; q4 < 4; q4++) {
        float4 kk = *(const float4*)(Ks + s * LPAD + jg * 16 + q4 * 4);
        acc2[q4 * 4 + 0] = fmaf(kk.x, vi, acc2[q4 * 4 + 0]);
        acc2[q4 * 4 + 1] = fmaf(kk.y, vi, acc2[q4 * 4 + 1]);
        acc2[q4 * 4 + 2] = fmaf(kk.z, vi, acc2[q4 * 4 + 2]);
        acc2[q4 * 4 + 3] = fmaf(kk.w, vi, acc2[q4 * 4 + 3]);
      }
    }
    const float* aLc = aL + ((long)bh * nch + c) * 64 + jg * 16;
#pragma unroll
    for (int q = 0; q < 16; q++) S[q] = aLc[q] * (S[q] + acc2[q]);
    __syncthreads();
  }
}

// ---------------------------------------------- chunked WKV: intra-chunk ---
__global__ __launch_bounds__(256) void k_wkv_intra(
    const float* __restrict__ rt, const float* __restrict__ kt,
    const float* __restrict__ v, const float* __restrict__ pdiag,
    float* __restrict__ y, int B, int T, int C, int H, int L) {
  int nch = T / L;
  int blk = blockIdx.x;
  int bh = blk / nch, c = blk - bh * nch;
  int b = bh / H, h = bh - b * H;
  __shared__ float RPs[64 * LPAD];
  __shared__ float Ks[64 * LPAD];
  __shared__ float Vs[64 * LPAD];
  int tid = threadIdx.x;
  long cbase = ((long)b * T + (long)c * L) * C + h * 64;
#pragma unroll
  for (int q = 0; q < 4; q++) {
    int idx = tid + q * 256;
    int row = idx >> 4, col = (idx & 15) * 4;
    long g = cbase + (long)row * C + col;
    *(float4*)(RPs + row * LPAD + col) = *(const float4*)(rt + g);
    *(float4*)(Ks + row * LPAD + col) = *(const float4*)(kt + g);
    *(float4*)(Vs + row * LPAD + col) = *(const float4*)(v + g);
  }
  __syncthreads();
  int tau = tid & 63, sg = tid >> 6;
  float4 rreg[16];
#pragma unroll
  for (int q = 0; q < 16; q++)
    rreg[q] = *(const float4*)(RPs + tau * LPAD + q * 4);
  float pd = pdiag[(long)bh * T + c * L + tau];
  __syncthreads();
#pragma unroll 2
  for (int ss = 0; ss < 16; ss++) {
    int s = sg * 16 + ss;
    float a0 = 0.f, a1 = 0.f, a2 = 0.f, a3 = 0.f;
#pragma unroll
    for (int q = 0; q < 16; q++) {
      float4 kk = *(const float4*)(Ks + s * LPAD + q * 4);
      a0 = fmaf(rreg[q].x, kk.x, a0);
      a1 = fmaf(rreg[q].y, kk.y, a1);
      a2 = fmaf(rreg[q].z, kk.z, a2);
      a3 = fmaf(rreg[q].w, kk.w, a3);
    }
    float a = (a0 + a1) + (a2 + a3);
    float val = (s < tau) ? a : (s == tau ? pd : 0.f);
    RPs[s * LPAD + tau] = val;
  }
  __syncthreads();
  int i = tid & 63, tg = tid >> 6;
  float acc[16];
#pragma unroll
  for (int q = 0; q < 16; q++) acc[q] = 0.f;
  for (int s = 0; s < 64; s++) {
    float vi = Vs[s * LPAD + i];
#pragma unroll
    for (int q4 = 0; q4 < 4; q4++) {
      float4 pp = *(const float4*)(RPs + s * LPAD + tg * 16 + q4 * 4);
      acc[q4 * 4 + 0] = fmaf(pp.x, vi, acc[q4 * 4 + 0]);
      acc[q4 * 4 + 1] = fmaf(pp.y, vi, acc[q4 * 4 + 1]);
      acc[q4 * 4 + 2] = fmaf(pp.z, vi, acc[q4 * 4 + 2]);
      acc[q4 * 4 + 3] = fmaf(pp.w, vi, acc[q4 * 4 + 3]);
    }
  }
#pragma unroll
  for (int q = 0; q < 16; q++) {
    long off = cbase + (long)(tg * 16 + q) * C + i;
    y[off] += acc[q];
  }
}

// ----------------------------------------------------- groupnorm * gate ---
__global__ __launch_bounds__(768) void k_gnmul(
    const float* __restrict__ y, const float* __restrict__ g,
    const float* __restrict__ ln_w, const float* __restrict__ ln_b,
    float* __restrict__ z, int C) {
  long row = blockIdx.x;
  int c = threadIdx.x;
  long off = row * C + c;
  float val = y[off];
  float s = val;
#pragma unroll
  for (int o = 32; o >= 1; o >>= 1) s += __shfl_xor(s, o, 64);
  float mu = s * (1.f / 64.f);
  float d = val - mu;
  float vs = d * d;
#pragma unroll
  for (int o = 32; o >= 1; o >>= 1) vs += __shfl_xor(vs, o, 64);
  float var = vs * (1.f / 64.f);
  float nrm = d * rsqrtf(var + 1e-5f);
  z[off] = (nrm * ln_w[c] + ln_b[c]) * g[off];
}

// ---------------------------------------------------------------- launch ---
extern "C" void kernel_launch(void* const* d_in, const int* in_sizes, int n_in,
                              void* d_out, int out_size, void* d_ws, size_t ws_size,
                              hipStream_t stream) {
  const int B = 8, T = 1024, C = 768, H = 12, ph = 32, pw = 32;
  const int M = B * T;
  const int L = 64, NCH = T / L;

  const float* x        = (const float*)d_in[0];
  const float* W_r      = (const float*)d_in[1];
  const float* W_k      = (const float*)d_in[2];
  const float* W_v      = (const float*)d_in[3];
  const float* W_g      = (const float*)d_in[4];
  const float* W_o      = (const float*)d_in[5];
  const float* maa_x    = (const float*)d_in[6];
  const float* maa_w    = (const float*)d_in[7];
  const float* maa_k    = (const float*)d_in[8];
  const float* maa_v    = (const float*)d_in[9];
  const float* maa_r    = (const float*)d_in[10];
  const float* maa_g    = (const float*)d_in[11];
  const float* maa_w1   = (const float*)d_in[12];
  const float* maa_w2   = (const float*)d_in[13];
  const float* time_dec = (const float*)d_in[14];
  const float* dec_w1   = (const float*)d_in[15];
  const float* dec_w2   = (const float*)d_in[16];
  const float* faaaa    = (const float*)d_in[17];
  const float* ln_w     = (const float*)d_in[18];
  const float* ln_b     = (const float*)d_in[19];

  float* ws = (float*)d_ws;
  const size_t S = (size_t)M * C;
  float* b_xx  = ws + 0 * S;  // xx   -> r
  float* b_xxx = ws + 1 * S;  // xxx  -> k
  float* b_xw  = ws + 2 * S;  // xw   -> w -> Kt (in place)
  float* b_xk  = ws + 3 * S;  // xk   -> v
  float* b_xv  = ws + 4 * S;  // xv   -> g
  float* b_xr  = ws + 5 * S;  // xr   -> y
  float* b_xg  = ws + 6 * S;  // xg   -> Rt -> z
  float* t5    = ws + 7 * S;            // [M,160]
  float* t6    = t5 + (size_t)M * 160;  // [M,64]
  float* aLb   = t6 + (size_t)M * 64;   // [B*H, NCH, 64]
  float* pdiag = aLb + (size_t)B * H * NCH * 64;  // [B*H, T]

  float* rb = b_xx;  float* kb = b_xxx; float* wb = b_xw;
  float* vb = b_xk;  float* gb = b_xv;  float* yb = b_xr; float* zb = b_xg;
  float* rtb = b_xg;
  float* ktb = b_xw;

  // 1. qshift
  {
    long total = (long)M * C;
    k_qshift<<<(int)((total + 255) / 256), 256, 0, stream>>>(
        x, maa_x, b_xx, b_xxx, B, T, C, ph, pw);
  }
  // 2. t5 = tanh(xxx @ maa_w1)
  {
    dim3 grid((160 + 63) / 64, (M + 63) / 64);
    k_gemm<EPI_TANH, false><<<grid, 256, 0, stream>>>(b_xxx, maa_w1, nullptr, t5, M, 160, C);
  }
  // 3. mix5 (fused tiled GEMM + epilogue)
  {
    dim3 grid(C / 64, M / 64);
    k_mix5f<<<grid, 256, 0, stream>>>(t5, maa_w2, x, b_xx, maa_w, maa_k, maa_v,
                                      maa_r, maa_g, b_xw, b_xk, b_xv, b_xr, b_xg, C);
  }
  // 4. projections
  {
    dim3 grid(C / 64, M / 64);
    k_gemm<EPI_NONE, true><<<grid, 256, 0, stream>>>(b_xr, W_r, nullptr, rb, M, C, C);
    k_gemm<EPI_NONE, true><<<grid, 256, 0, stream>>>(b_xk, W_k, nullptr, kb, M, C, C);
    k_gemm<EPI_NONE, true><<<grid, 256, 0, stream>>>(b_xv, W_v, nullptr, vb, M, C, C);
    k_gemm<EPI_RELU, true><<<grid, 256, 0, stream>>>(b_xg, W_g, nullptr, gb, M, C, C);
    dim3 grid1(1, M / 64);
    k_gemm<EPI_TANH, false><<<grid1, 256, 0, stream>>>(b_xw, dec_w1, nullptr, t6, M, 64, C);
    k_gemm<EPI_BIAS, false><<<grid, 256, 0, stream>>>(t6, dec_w2, time_dec, wb, M, C, 64);
  }
  // 5. chunked wkv6
  k_wkv_pre<<<B * H * NCH, 64, 0, stream>>>(rb, kb, wb, faaaa, rtb, ktb,
                                            aLb, pdiag, B, T, C, H, L);
  k_wkv_state<<<B * H, 256, 0, stream>>>(rtb, ktb, vb, aLb, yb, B, T, C, H, L);
  k_wkv_intra<<<B * H * NCH, 256, 0, stream>>>(rtb, ktb, vb, pdiag, yb, B, T, C, H, L);
  // 6. groupnorm * gate
  k_gnmul<<<M, 768, 0, stream>>>(yb, gb, ln_w, ln_b, zb, C);
  // 7. out = z @ W_o^T
  {
    dim3 grid(C / 64, M / 64);
    k_gemm<EPI_NONE, true><<<grid, 256, 0, stream>>>(zb, W_o, nullptr, (float*)d_out, M, C, C);
  }
}

// Round 4
// 1000.818 us; speedup vs baseline: 3.6901x; 1.8563x over previous
//
#include <hip/hip_runtime.h>
#include <math.h>

// ---------------------------------------------------------------------------
// TimeMix (RWKV-6 vision block) — round 4: bf16 MFMA for the 5 big GEMMs.
// B=8, T=1024 (32x32), C=768, H=12 heads of 64, M=8192.
// ---------------------------------------------------------------------------

#define EPI_NONE 0
#define EPI_TANH 1
#define EPI_RELU 2
#define EPI_BIAS 3

#define LPAD 68   // LDS row stride (floats) for 64-wide chunk tiles

typedef float f32x4 __attribute__((ext_vector_type(4)));
typedef __bf16 bf16x8 __attribute__((ext_vector_type(8)));

__device__ __forceinline__ ushort f2bf(float x) {
  unsigned u = __float_as_uint(x);
  return (ushort)((u + 0x7fffu + ((u >> 16) & 1u)) >> 16);
}

#define GLDS16(gp, lp)                                                   \
  __builtin_amdgcn_global_load_lds(                                      \
      (const __attribute__((address_space(1))) void*)(gp),               \
      (__attribute__((address_space(3))) void*)(lp), 16, 0, 0)

// ---------------------------------------------------------------- qshift ---
__global__ __launch_bounds__(256) void k_qshift(
    const float* __restrict__ x, const float* __restrict__ maa_x,
    float* __restrict__ xx, float* __restrict__ xxx,
    int B, int T, int C, int ph, int pw) {
  long idx = (long)blockIdx.x * blockDim.x + threadIdx.x;
  long total = (long)B * T * C;
  if (idx >= total) return;
  int c = (int)(idx % C);
  long bt = idx / C;
  int t = (int)(bt % T);
  int quarter = (c & 63) >> 4;
  int hh = t / pw;
  int ww = t - hh * pw;
  long rowbase = (bt - t) * C;
  float sval = 0.f;
  int st = -1;
  if (quarter == 0)      { if (ww >= 1)      st = t - 1;  }
  else if (quarter == 1) { if (ww < pw - 1)  st = t + 1;  }
  else if (quarter == 2) { if (hh >= 1)      st = t - pw; }
  else                   { if (hh < ph - 1)  st = t + pw; }
  if (st >= 0) sval = x[rowbase + (long)st * C + c];
  float xval = x[idx];
  float d = sval - xval;
  xx[idx] = d;
  xxx[idx] = xval + d * maa_x[c];
}

// ---------------------------------------------- mix5 fused GEMM+epilogue ---
// xw written fp32 (decay path); xk/xv/xr/xg written bf16 (MFMA GEMM inputs).
__global__ __launch_bounds__(256) void k_mix5f(
    const float* __restrict__ t5, const float* __restrict__ maa_w2,
    const float* __restrict__ x, const float* __restrict__ xx,
    const float* __restrict__ maa_w, const float* __restrict__ maa_k,
    const float* __restrict__ maa_v, const float* __restrict__ maa_r,
    const float* __restrict__ maa_g,
    float* __restrict__ xw, ushort* __restrict__ xk, ushort* __restrict__ xvb,
    ushort* __restrict__ xr, ushort* __restrict__ xg, int C) {
  __shared__ float As[64][36];
  __shared__ float Bs[32][64];
  int tid = threadIdx.x;
  int m0 = blockIdx.y * 64, n0 = blockIdx.x * 64;
  int tx = tid & 15, ty = tid >> 4;
  float acc[5][4][4];
#pragma unroll
  for (int f = 0; f < 5; f++)
#pragma unroll
    for (int i = 0; i < 4; i++)
#pragma unroll
      for (int j = 0; j < 4; j++) acc[f][i][j] = 0.f;

#pragma unroll
  for (int f = 0; f < 5; f++) {
    {
      int k4 = (tid & 7) * 4;
      int row = tid >> 3;
      const float* src = t5 + (size_t)(m0 + row) * 160 + f * 32 + k4;
      float4 v0 = *(const float4*)src;
      float4 v1 = *(const float4*)(src + 32 * 160);
      *(float4*)(&As[row][k4]) = v0;
      *(float4*)(&As[row + 32][k4]) = v1;
    }
    {
      int col = (tid & 15) * 4, kk = tid >> 4;
      const float* src = maa_w2 + (size_t)(f * 32 + kk) * C + n0 + col;
      *(float4*)(&Bs[kk][col]) = *(const float4*)src;
      *(float4*)(&Bs[kk + 16][col]) = *(const float4*)(src + (size_t)16 * C);
    }
    __syncthreads();
#pragma unroll
    for (int kk = 0; kk < 32; kk++) {
      float4 b4 = *(const float4*)(&Bs[kk][tx * 4]);
#pragma unroll
      for (int i = 0; i < 4; i++) {
        float a = As[ty * 4 + i][kk];
        acc[f][i][0] = fmaf(a, b4.x, acc[f][i][0]);
        acc[f][i][1] = fmaf(a, b4.y, acc[f][i][1]);
        acc[f][i][2] = fmaf(a, b4.z, acc[f][i][2]);
        acc[f][i][3] = fmaf(a, b4.w, acc[f][i][3]);
      }
    }
    __syncthreads();
  }
  int cb = n0 + tx * 4;
  float4 mw = *(const float4*)(maa_w + cb);
  float4 mk = *(const float4*)(maa_k + cb);
  float4 mv = *(const float4*)(maa_v + cb);
  float4 mr = *(const float4*)(maa_r + cb);
  float4 mg = *(const float4*)(maa_g + cb);
#pragma unroll
  for (int i = 0; i < 4; i++) {
    size_t off = (size_t)(m0 + ty * 4 + i) * C + cb;
    float4 xv = *(const float4*)(x + off);
    float4 dd = *(const float4*)(xx + off);
    float4 o;
    o.x = xv.x + dd.x * (mw.x + acc[0][i][0]);
    o.y = xv.y + dd.y * (mw.y + acc[0][i][1]);
    o.z = xv.z + dd.z * (mw.z + acc[0][i][2]);
    o.w = xv.w + dd.w * (mw.w + acc[0][i][3]);
    *(float4*)(xw + off) = o;
    ushort4 ob;
    ob.x = f2bf(xv.x + dd.x * (mk.x + acc[1][i][0]));
    ob.y = f2bf(xv.y + dd.y * (mk.y + acc[1][i][1]));
    ob.z = f2bf(xv.z + dd.z * (mk.z + acc[1][i][2]));
    ob.w = f2bf(xv.w + dd.w * (mk.w + acc[1][i][3]));
    *(ushort4*)(xk + off) = ob;
    ob.x = f2bf(xv.x + dd.x * (mv.x + acc[2][i][0]));
    ob.y = f2bf(xv.y + dd.y * (mv.y + acc[2][i][1]));
    ob.z = f2bf(xv.z + dd.z * (mv.z + acc[2][i][2]));
    ob.w = f2bf(xv.w + dd.w * (mv.w + acc[2][i][3]));
    *(ushort4*)(xvb + off) = ob;
    ob.x = f2bf(xv.x + dd.x * (mr.x + acc[3][i][0]));
    ob.y = f2bf(xv.y + dd.y * (mr.y + acc[3][i][1]));
    ob.z = f2bf(xv.z + dd.z * (mr.z + acc[3][i][2]));
    ob.w = f2bf(xv.w + dd.w * (mr.w + acc[3][i][3]));
    *(ushort4*)(xr + off) = ob;
    ob.x = f2bf(xv.x + dd.x * (mg.x + acc[4][i][0]));
    ob.y = f2bf(xv.y + dd.y * (mg.y + acc[4][i][1]));
    ob.z = f2bf(xv.z + dd.z * (mg.z + acc[4][i][2]));
    ob.w = f2bf(xv.w + dd.w * (mg.w + acc[4][i][3]));
    *(ushort4*)(xg + off) = ob;
  }
}

// ------------------------------------------------------- fp32 -> bf16 cvt --
__global__ __launch_bounds__(256) void k_cvt_bf(
    const float* __restrict__ s, ushort* __restrict__ d, int n) {
  int i = (blockIdx.x * 256 + threadIdx.x) * 4;
  if (i >= n) return;
  float4 v = *(const float4*)(s + i);
  ushort4 o;
  o.x = f2bf(v.x); o.y = f2bf(v.y); o.z = f2bf(v.z); o.w = f2bf(v.w);
  *(ushort4*)(d + i) = o;
}

// ----------------------------------------------------- bf16 MFMA GEMM ------
// C[m,n] = act( sum_k A[m,k] * W[n,k] ), A/W bf16, C fp32.
// 128x128 tile, BK=32, 4 waves each computing 64x64 via 4x4 16x16x32 frags.
template <int EPI>
__global__ __launch_bounds__(256) void k_gemm_bf(
    const ushort* __restrict__ A, const ushort* __restrict__ W,
    float* __restrict__ Cm, int M, int N, int K) {
  __shared__ ushort Al[128 * 32];
  __shared__ ushort Bl[128 * 32];
  int tid = threadIdx.x;
  int m0 = blockIdx.y * 128, n0 = blockIdx.x * 128;
  int lane = tid & 63, wave = tid >> 6;
  int wm = (wave >> 1) * 64, wn = (wave & 1) * 64;
  int lm = lane & 15, lk = (lane >> 4) * 8;
  f32x4 acc[4][4];
#pragma unroll
  for (int i = 0; i < 4; i++)
#pragma unroll
    for (int j = 0; j < 4; j++) acc[i][j] = (f32x4){0.f, 0.f, 0.f, 0.f};

  int arow = tid >> 2, achunk = (tid & 3) * 8;   // 64 rows / issue, 16B chunks
  const ushort* Ag = A + (size_t)(m0 + arow) * K + achunk;
  const ushort* Wg = W + (size_t)(n0 + arow) * K + achunk;
  ushort* Ald = Al + tid * 8;
  ushort* Bld = Bl + tid * 8;

  for (int k0 = 0; k0 < K; k0 += 32) {
    GLDS16(Ag + k0, Ald);
    GLDS16(Ag + (size_t)64 * K + k0, Ald + 2048);
    GLDS16(Wg + k0, Bld);
    GLDS16(Wg + (size_t)64 * K + k0, Bld + 2048);
    __syncthreads();
    bf16x8 af[4], bf[4];
#pragma unroll
    for (int i = 0; i < 4; i++)
      af[i] = *(const bf16x8*)&Al[(wm + i * 16 + lm) * 32 + lk];
#pragma unroll
    for (int j = 0; j < 4; j++)
      bf[j] = *(const bf16x8*)&Bl[(wn + j * 16 + lm) * 32 + lk];
#pragma unroll
    for (int i = 0; i < 4; i++)
#pragma unroll
      for (int j = 0; j < 4; j++)
        acc[i][j] = __builtin_amdgcn_mfma_f32_16x16x32_bf16(
            af[i], bf[j], acc[i][j], 0, 0, 0);
    __syncthreads();
  }
  int rq = (lane >> 4) * 4;
#pragma unroll
  for (int i = 0; i < 4; i++) {
#pragma unroll
    for (int j = 0; j < 4; j++) {
      int gn = n0 + wn + j * 16 + lm;
#pragma unroll
      for (int q = 0; q < 4; q++) {
        int gm = m0 + wm + i * 16 + rq + q;
        float val = acc[i][j][q];
        if (EPI == EPI_RELU) val = fmaxf(val, 0.f);
        Cm[(size_t)gm * N + gn] = val;
      }
    }
  }
}

// -------------------------------------------------------------- fp32 gemm --
template <int EPI, bool BT>
__global__ __launch_bounds__(256) void k_gemm(
    const float* __restrict__ A, const float* __restrict__ Bm,
    const float* __restrict__ bias, float* __restrict__ Cm,
    int M, int N, int K) {
  const int BMt = 64, BNt = 64, BKt = 16;
  __shared__ float As[BKt][BMt];
  __shared__ float Bs[BKt][BNt];
  int tid = (int)threadIdx.x;
  int m0 = blockIdx.y * BMt, n0 = blockIdx.x * BNt;
  int tx = tid & 15, ty = tid >> 4;
  float acc[4][4];
#pragma unroll
  for (int i = 0; i < 4; i++)
#pragma unroll
    for (int j = 0; j < 4; j++) acc[i][j] = 0.f;

  for (int k0 = 0; k0 < K; k0 += BKt) {
#pragma unroll
    for (int i = 0; i < 4; i++) {
      int idx = tid + i * 256;
      int am = idx >> 4, ak = idx & 15;
      int gm = m0 + am, gk = k0 + ak;
      float va = 0.f;
      if (gm < M && gk < K) va = A[(size_t)gm * K + gk];
      As[ak][am] = va;
    }
#pragma unroll
    for (int i = 0; i < 4; i++) {
      int idx = tid + i * 256;
      float vb = 0.f;
      if (BT) {
        int bn = idx >> 4, bk = idx & 15;
        int gn = n0 + bn, gk = k0 + bk;
        if (gn < N && gk < K) vb = Bm[(size_t)gn * K + gk];
        Bs[bk][bn] = vb;
      } else {
        int bk = idx >> 6, bn = idx & 63;
        int gk = k0 + bk, gn = n0 + bn;
        if (gk < K && gn < N) vb = Bm[(size_t)gk * N + gn];
        Bs[bk][bn] = vb;
      }
    }
    __syncthreads();
#pragma unroll
    for (int kk = 0; kk < BKt; kk++) {
      float a[4], b[4];
#pragma unroll
      for (int i = 0; i < 4; i++) a[i] = As[kk][ty * 4 + i];
#pragma unroll
      for (int j = 0; j < 4; j++) b[j] = Bs[kk][tx * 4 + j];
#pragma unroll
      for (int i = 0; i < 4; i++)
#pragma unroll
        for (int j = 0; j < 4; j++) acc[i][j] = fmaf(a[i], b[j], acc[i][j]);
    }
    __syncthreads();
  }
#pragma unroll
  for (int i = 0; i < 4; i++) {
    int gm = m0 + ty * 4 + i;
    if (gm >= M) continue;
#pragma unroll
    for (int j = 0; j < 4; j++) {
      int gn = n0 + tx * 4 + j;
      if (gn >= N) continue;
      float c = acc[i][j];
      if (EPI == EPI_BIAS) c += bias[gn];
      if (EPI == EPI_TANH) c = tanhf(c);
      if (EPI == EPI_RELU) c = fmaxf(c, 0.f);
      Cm[(size_t)gm * N + gn] = c;
    }
  }
}

// ------------------------------------------------- chunked WKV: phase pre --
__global__ __launch_bounds__(64) void k_wkv_pre(
    const float* __restrict__ r, const float* __restrict__ k,
    const float* __restrict__ w, const float* __restrict__ u,
    float* __restrict__ rt, float* __restrict__ kt,
    float* __restrict__ aL, float* __restrict__ pdiag,
    int B, int T, int C, int H, int L) {
  int nch = T / L;
  int blk = blockIdx.x;
  int bh = blk / nch, c = blk - bh * nch;
  int b = bh / H, h = bh - b * H;
  int j = threadIdx.x;
  float uj = u[h * 64 + j];
  float cum = 0.f;
  long base = ((long)b * T + (long)c * L) * C + h * 64 + j;
  for (int tau = 0; tau < L; tau++) {
    long off = base + (long)tau * C;
    float wv = w[off];
    float rv = r[off];
    float kv = k[off];
    float e = expf(wv);
    rt[off] = rv * expf(-cum);
    cum += e;
    kt[off] = kv * expf(cum);
    float pd = rv * uj * kv;
#pragma unroll
    for (int o = 32; o >= 1; o >>= 1) pd += __shfl_xor(pd, o, 64);
    if (j == 0) pdiag[(long)bh * T + c * L + tau] = pd;
  }
  aL[((long)bh * nch + c) * 64 + j] = expf(-cum);
}

// ----------------------------------------------- chunked WKV: state prop ---
__global__ __launch_bounds__(256) void k_wkv_state(
    const float* __restrict__ rt, const float* __restrict__ kt,
    const float* __restrict__ v, const float* __restrict__ aL,
    float* __restrict__ y, int B, int T, int C, int H, int L) {
  int bh = blockIdx.x;
  int b = bh / H, h = bh - b * H;
  int nch = T / L;
  __shared__ float Rs[64 * LPAD];
  __shared__ float Ks[64 * LPAD];
  __shared__ float Vs[64 * LPAD];
  __shared__ float Yp[4][512];
  int tid = threadIdx.x;
  int lane = tid & 63;
  int jg = tid >> 6;
  float S[16];
#pragma unroll
  for (int q = 0; q < 16; q++) S[q] = 0.f;
  long hbase = (long)b * T * C + h * 64;
  for (int c = 0; c < nch; c++) {
    long cbase = hbase + (long)c * L * C;
#pragma unroll
    for (int q = 0; q < 4; q++) {
      int idx = tid + q * 256;
      int row = idx >> 4, col = (idx & 15) * 4;
      long g = cbase + (long)row * C + col;
      *(float4*)(Rs + row * LPAD + col) = *(const float4*)(rt + g);
      *(float4*)(Ks + row * LPAD + col) = *(const float4*)(kt + g);
      *(float4*)(Vs + row * LPAD + col) = *(const float4*)(v + g);
    }
    __syncthreads();
    for (int p = 0; p < 8; p++) {
      float acc[8];
#pragma unroll
      for (int t8 = 0; t8 < 8; t8++) {
        int tau = p * 8 + t8;
        float a0 = 0.f, a1 = 0.f, a2 = 0.f, a3 = 0.f;
#pragma unroll
        for (int q4 = 0; q4 < 4; q4++) {
          float4 rr = *(const float4*)(Rs + tau * LPAD + jg * 16 + q4 * 4);
          a0 = fmaf(rr.x, S[q4 * 4 + 0], a0);
          a1 = fmaf(rr.y, S[q4 * 4 + 1], a1);
          a2 = fmaf(rr.z, S[q4 * 4 + 2], a2);
          a3 = fmaf(rr.w, S[q4 * 4 + 3], a3);
        }
        acc[t8] = (a0 + a1) + (a2 + a3);
      }
#pragma unroll
      for (int t8 = 0; t8 < 8; t8++) Yp[jg][t8 * 64 + lane] = acc[t8];
      __syncthreads();
      {
        int ii = tid & 63;
#pragma unroll
        for (int s = 0; s < 2; s++) {
          int t8 = (tid >> 6) + s * 4;
          float sum = Yp[0][t8 * 64 + ii] + Yp[1][t8 * 64 + ii] +
                      Yp[2][t8 * 64 + ii] + Yp[3][t8 * 64 + ii];
          y[cbase + (long)(p * 8 + t8) * C + ii] = sum;
        }
      }
      __syncthreads();
    }
    float acc2[16];
#pragma unroll
    for (int q = 0; q < 16; q++) acc2[q] = 0.f;
    for (int s = 0; s < 64; s++) {
      float vi = Vs[s * LPAD + lane];
#pragma unroll
      for (int q4 = 0; q4 < 4; q4++) {
        float4 kk = *(const float4*)(Ks + s * LPAD + jg * 16 + q4 * 4);
        acc2[q4 * 4 + 0] = fmaf(kk.x, vi, acc2[q4 * 4 + 0]);
        acc2[q4 * 4 + 1] = fmaf(kk.y, vi, acc2[q4 * 4 + 1]);
        acc2[q4 * 4 + 2] = fmaf(kk.z, vi, acc2[q4 * 4 + 2]);
        acc2[q4 * 4 + 3] = fmaf(kk.w, vi, acc2[q4 * 4 + 3]);
      }
    }
    const float* aLc = aL + ((long)bh * nch + c) * 64 + jg * 16;
#pragma unroll
    for (int q = 0; q < 16; q++) S[q] = aLc[q] * (S[q] + acc2[q]);
    __syncthreads();
  }
}

// ---------------------------------------------- chunked WKV: intra-chunk ---
__global__ __launch_bounds__(256) void k_wkv_intra(
    const float* __restrict__ rt, const float* __restrict__ kt,
    const float* __restrict__ v, const float* __restrict__ pdiag,
    float* __restrict__ y, int B, int T, int C, int H, int L) {
  int nch = T / L;
  int blk = blockIdx.x;
  int bh = blk / nch, c = blk - bh * nch;
  int b = bh / H, h = bh - b * H;
  __shared__ float RPs[64 * LPAD];
  __shared__ float Ks[64 * LPAD];
  __shared__ float Vs[64 * LPAD];
  int tid = threadIdx.x;
  long cbase = ((long)b * T + (long)c * L) * C + h * 64;
#pragma unroll
  for (int q = 0; q < 4; q++) {
    int idx = tid + q * 256;
    int row = idx >> 4, col = (idx & 15) * 4;
    long g = cbase + (long)row * C + col;
    *(float4*)(RPs + row * LPAD + col) = *(const float4*)(rt + g);
    *(float4*)(Ks + row * LPAD + col) = *(const float4*)(kt + g);
    *(float4*)(Vs + row * LPAD + col) = *(const float4*)(v + g);
  }
  __syncthreads();
  int tau = tid & 63, sg = tid >> 6;
  float4 rreg[16];
#pragma unroll
  for (int q = 0; q < 16; q++)
    rreg[q] = *(const float4*)(RPs + tau * LPAD + q * 4);
  float pd = pdiag[(long)bh * T + c * L + tau];
  __syncthreads();
#pragma unroll 2
  for (int ss = 0; ss < 16; ss++) {
    int s = sg * 16 + ss;
    float a0 = 0.f, a1 = 0.f, a2 = 0.f, a3 = 0.f;
#pragma unroll
    for (int q = 0; q < 16; q++) {
      float4 kk = *(const float4*)(Ks + s * LPAD + q * 4);
      a0 = fmaf(rreg[q].x, kk.x, a0);
      a1 = fmaf(rreg[q].y, kk.y, a1);
      a2 = fmaf(rreg[q].z, kk.z, a2);
      a3 = fmaf(rreg[q].w, kk.w, a3);
    }
    float a = (a0 + a1) + (a2 + a3);
    float val = (s < tau) ? a : (s == tau ? pd : 0.f);
    RPs[s * LPAD + tau] = val;
  }
  __syncthreads();
  int i = tid & 63, tg = tid >> 6;
  float acc[16];
#pragma unroll
  for (int q = 0; q < 16; q++) acc[q] = 0.f;
  for (int s = 0; s < 64; s++) {
    float vi = Vs[s * LPAD + i];
#pragma unroll
    for (int q4 = 0; q4 < 4; q4++) {
      float4 pp = *(const float4*)(RPs + s * LPAD + tg * 16 + q4 * 4);
      acc[q4 * 4 + 0] = fmaf(pp.x, vi, acc[q4 * 4 + 0]);
      acc[q4 * 4 + 1] = fmaf(pp.y, vi, acc[q4 * 4 + 1]);
      acc[q4 * 4 + 2] = fmaf(pp.z, vi, acc[q4 * 4 + 2]);
      acc[q4 * 4 + 3] = fmaf(pp.w, vi, acc[q4 * 4 + 3]);
    }
  }
#pragma unroll
  for (int q = 0; q < 16; q++) {
    long off = cbase + (long)(tg * 16 + q) * C + i;
    y[off] += acc[q];
  }
}

// ----------------------------------------------------- groupnorm * gate ---
__global__ __launch_bounds__(768) void k_gnmul(
    const float* __restrict__ y, const float* __restrict__ g,
    const float* __restrict__ ln_w, const float* __restrict__ ln_b,
    ushort* __restrict__ z, int C) {
  long row = blockIdx.x;
  int c = threadIdx.x;
  long off = row * C + c;
  float val = y[off];
  float s = val;
#pragma unroll
  for (int o = 32; o >= 1; o >>= 1) s += __shfl_xor(s, o, 64);
  float mu = s * (1.f / 64.f);
  float d = val - mu;
  float vs = d * d;
#pragma unroll
  for (int o = 32; o >= 1; o >>= 1) vs += __shfl_xor(vs, o, 64);
  float var = vs * (1.f / 64.f);
  float nrm = d * rsqrtf(var + 1e-5f);
  z[off] = f2bf((nrm * ln_w[c] + ln_b[c]) * g[off]);
}

// ---------------------------------------------------------------- launch ---
extern "C" void kernel_launch(void* const* d_in, const int* in_sizes, int n_in,
                              void* d_out, int out_size, void* d_ws, size_t ws_size,
                              hipStream_t stream) {
  const int B = 8, T = 1024, C = 768, H = 12, ph = 32, pw = 32;
  const int M = B * T;
  const int L = 64, NCH = T / L;

  const float* x        = (const float*)d_in[0];
  const float* W_r      = (const float*)d_in[1];
  const float* W_k      = (const float*)d_in[2];
  const float* W_v      = (const float*)d_in[3];
  const float* W_g      = (const float*)d_in[4];
  const float* W_o      = (const float*)d_in[5];
  const float* maa_x    = (const float*)d_in[6];
  const float* maa_w    = (const float*)d_in[7];
  const float* maa_k    = (const float*)d_in[8];
  const float* maa_v    = (const float*)d_in[9];
  const float* maa_r    = (const float*)d_in[10];
  const float* maa_g    = (const float*)d_in[11];
  const float* maa_w1   = (const float*)d_in[12];
  const float* maa_w2   = (const float*)d_in[13];
  const float* time_dec = (const float*)d_in[14];
  const float* dec_w1   = (const float*)d_in[15];
  const float* dec_w2   = (const float*)d_in[16];
  const float* faaaa    = (const float*)d_in[17];
  const float* ln_w     = (const float*)d_in[18];
  const float* ln_b     = (const float*)d_in[19];

  float* ws = (float*)d_ws;
  const size_t S = (size_t)M * C;          // 6291456
  float* F0 = ws + 0 * S;   // xx   -> r
  float* F1 = ws + 1 * S;   // xxx  -> k -> y
  float* F2 = ws + 2 * S;   // xw   -> w -> Kt (in place)
  float* F3 = ws + 3 * S;   // v
  float* F4 = ws + 4 * S;   // g
  float* F5 = ws + 5 * S;   // xr_bf | xk_bf  -> Rt (fp32)
  float* F6 = ws + 6 * S;   // xv_bf | xg_bf  -> z_bf
  float* t5    = ws + 7 * S;            // [M,160] -> bf16 weights W_r..W_g
  float* t6    = t5 + (size_t)M * 160;  // [M,64]  -> bf16 W_o
  float* aLb   = t6 + (size_t)M * 64;
  float* pdiag = aLb + (size_t)B * H * NCH * 64;

  ushort* xr_bf = (ushort*)F5;
  ushort* xk_bf = xr_bf + S;
  ushort* xv_bf = (ushort*)F6;
  ushort* xg_bf = xv_bf + S;
  ushort* z_bf  = (ushort*)F6;          // reuses xv_bf region (dead by then)
  const int WSZ = C * C;                // 589824
  ushort* wr_bf = (ushort*)t5;
  ushort* wk_bf = wr_bf + WSZ;
  ushort* wv_bf = wk_bf + WSZ;
  ushort* wg_bf = wv_bf + WSZ;
  ushort* wo_bf = (ushort*)t6;

  // 1. qshift
  {
    long total = (long)M * C;
    k_qshift<<<(int)((total + 255) / 256), 256, 0, stream>>>(
        x, maa_x, F0, F1, B, T, C, ph, pw);
  }
  // 2. t5 = tanh(xxx @ maa_w1)
  {
    dim3 grid(3, M / 64);
    k_gemm<EPI_TANH, false><<<grid, 256, 0, stream>>>(F1, maa_w1, nullptr, t5, M, 160, C);
  }
  // 3. mix5 (xw fp32, xk/xv/xr/xg bf16)
  {
    dim3 grid(C / 64, M / 64);
    k_mix5f<<<grid, 256, 0, stream>>>(t5, maa_w2, x, F0, maa_w, maa_k, maa_v,
                                      maa_r, maa_g, F2, xk_bf, xv_bf, xr_bf, xg_bf, C);
  }
  // 4. weight conversion (t5 dead now)
  {
    int blocks = (WSZ / 4 + 255) / 256;
    k_cvt_bf<<<blocks, 256, 0, stream>>>(W_r, wr_bf, WSZ);
    k_cvt_bf<<<blocks, 256, 0, stream>>>(W_k, wk_bf, WSZ);
    k_cvt_bf<<<blocks, 256, 0, stream>>>(W_v, wv_bf, WSZ);
    k_cvt_bf<<<blocks, 256, 0, stream>>>(W_g, wg_bf, WSZ);
  }
  // 5. big projections: bf16 MFMA
  {
    dim3 grid(C / 128, M / 128);
    k_gemm_bf<EPI_NONE><<<grid, 256, 0, stream>>>(xr_bf, wr_bf, F0, M, C, C);
    k_gemm_bf<EPI_NONE><<<grid, 256, 0, stream>>>(xk_bf, wk_bf, F1, M, C, C);
    k_gemm_bf<EPI_NONE><<<grid, 256, 0, stream>>>(xv_bf, wv_bf, F3, M, C, C);
    k_gemm_bf<EPI_RELU><<<grid, 256, 0, stream>>>(xg_bf, wg_bf, F4, M, C, C);
  }
  // 6. decay path (fp32)
  {
    dim3 grid1(1, M / 64);
    k_gemm<EPI_TANH, false><<<grid1, 256, 0, stream>>>(F2, dec_w1, nullptr, t6, M, 64, C);
    dim3 grid(C / 64, M / 64);
    k_gemm<EPI_BIAS, false><<<grid, 256, 0, stream>>>(t6, dec_w2, time_dec, F2, M, C, 64);
  }
  // 7. W_o conversion (t6 dead now)
  k_cvt_bf<<<(WSZ / 4 + 255) / 256, 256, 0, stream>>>(W_o, wo_bf, WSZ);
  // 8. chunked wkv6: r=F0, k=F1, w=F2 -> Rt=F5, Kt=F2(inplace), y=F1
  k_wkv_pre<<<B * H * NCH, 64, 0, stream>>>(F0, F1, F2, faaaa, F5, F2,
                                            aLb, pdiag, B, T, C, H, L);
  k_wkv_state<<<B * H, 256, 0, stream>>>(F5, F2, F3, aLb, F1, B, T, C, H, L);
  k_wkv_intra<<<B * H * NCH, 256, 0, stream>>>(F5, F2, F3, pdiag, F1, B, T, C, H, L);
  // 9. groupnorm * gate -> z bf16
  k_gnmul<<<M, 768, 0, stream>>>(F1, F4, ln_w, ln_b, z_bf, C);
  // 10. out = z @ W_o^T (bf16 MFMA)
  {
    dim3 grid(C / 128, M / 128);
    k_gemm_bf<EPI_NONE><<<grid, 256, 0, stream>>>(z_bf, wo_bf, (float*)d_out, M, C, C);
  }
}

// Round 5
// 886.963 us; speedup vs baseline: 4.1637x; 1.1284x over previous
//
#include <hip/hip_runtime.h>
#include <math.h>

// ---------------------------------------------------------------------------
// TimeMix (RWKV-6 vision block) — round 5: spill-free mix5f (per-f epilogue).
// B=8, T=1024 (32x32), C=768, H=12 heads of 64, M=8192.
// ---------------------------------------------------------------------------

#define EPI_NONE 0
#define EPI_TANH 1
#define EPI_RELU 2
#define EPI_BIAS 3

#define LPAD 68   // LDS row stride (floats) for 64-wide chunk tiles

typedef float f32x4 __attribute__((ext_vector_type(4)));
typedef __bf16 bf16x8 __attribute__((ext_vector_type(8)));

__device__ __forceinline__ ushort f2bf(float x) {
  unsigned u = __float_as_uint(x);
  return (ushort)((u + 0x7fffu + ((u >> 16) & 1u)) >> 16);
}

#define GLDS16(gp, lp)                                                   \
  __builtin_amdgcn_global_load_lds(                                      \
      (const __attribute__((address_space(1))) void*)(gp),               \
      (__attribute__((address_space(3))) void*)(lp), 16, 0, 0)

// ---------------------------------------------------------------- qshift ---
__global__ __launch_bounds__(256) void k_qshift(
    const float* __restrict__ x, const float* __restrict__ maa_x,
    float* __restrict__ xx, float* __restrict__ xxx,
    int B, int T, int C, int ph, int pw) {
  long idx = (long)blockIdx.x * blockDim.x + threadIdx.x;
  long total = (long)B * T * C;
  if (idx >= total) return;
  int c = (int)(idx % C);
  long bt = idx / C;
  int t = (int)(bt % T);
  int quarter = (c & 63) >> 4;
  int hh = t / pw;
  int ww = t - hh * pw;
  long rowbase = (bt - t) * C;
  float sval = 0.f;
  int st = -1;
  if (quarter == 0)      { if (ww >= 1)      st = t - 1;  }
  else if (quarter == 1) { if (ww < pw - 1)  st = t + 1;  }
  else if (quarter == 2) { if (hh >= 1)      st = t - pw; }
  else                   { if (hh < ph - 1)  st = t + pw; }
  if (st >= 0) sval = x[rowbase + (long)st * C + c];
  float xval = x[idx];
  float d = sval - xval;
  xx[idx] = d;
  xxx[idx] = xval + d * maa_x[c];
}

// ---------------------------------------------- mix5 fused GEMM+epilogue ---
// Spill-free: per-f acc[4][4] only; each output stored right after its slice.
// xw fp32 (decay path); xk/xv/xr/xg bf16 (MFMA GEMM inputs).
__global__ __launch_bounds__(256) void k_mix5f(
    const float* __restrict__ t5, const float* __restrict__ maa_w2,
    const float* __restrict__ x, const float* __restrict__ xx,
    const float* __restrict__ maa_w, const float* __restrict__ maa_k,
    const float* __restrict__ maa_v, const float* __restrict__ maa_r,
    const float* __restrict__ maa_g,
    float* __restrict__ xw, ushort* __restrict__ xk, ushort* __restrict__ xvb,
    ushort* __restrict__ xr, ushort* __restrict__ xg, int C) {
  __shared__ float As[64][36];
  __shared__ float Bs[32][64];
  int tid = threadIdx.x;
  int m0 = blockIdx.y * 64, n0 = blockIdx.x * 64;
  int tx = tid & 15, ty = tid >> 4;
  int cb = n0 + tx * 4;
  // preload this thread's x/xx patch (4 rows x 4 cols)
  float4 xv4[4], dd4[4];
#pragma unroll
  for (int i = 0; i < 4; i++) {
    size_t off = (size_t)(m0 + ty * 4 + i) * C + cb;
    xv4[i] = *(const float4*)(x + off);
    dd4[i] = *(const float4*)(xx + off);
  }

#pragma unroll
  for (int f = 0; f < 5; f++) {
    {  // t5 slice rows m0..m0+63, cols f*32..f*32+31
      int k4 = (tid & 7) * 4;
      int row = tid >> 3;
      const float* src = t5 + (size_t)(m0 + row) * 160 + f * 32 + k4;
      float4 v0 = *(const float4*)src;
      float4 v1 = *(const float4*)(src + 32 * 160);
      *(float4*)(&As[row][k4]) = v0;
      *(float4*)(&As[row + 32][k4]) = v1;
    }
    {  // maa_w2 slice rows f*32..+31, cols n0..n0+63
      int col = (tid & 15) * 4, kk = tid >> 4;
      const float* src = maa_w2 + (size_t)(f * 32 + kk) * C + n0 + col;
      *(float4*)(&Bs[kk][col]) = *(const float4*)src;
      *(float4*)(&Bs[kk + 16][col]) = *(const float4*)(src + (size_t)16 * C);
    }
    __syncthreads();
    float acc[4][4];
#pragma unroll
    for (int i = 0; i < 4; i++)
#pragma unroll
      for (int j = 0; j < 4; j++) acc[i][j] = 0.f;
#pragma unroll
    for (int kk = 0; kk < 32; kk++) {
      float4 b4 = *(const float4*)(&Bs[kk][tx * 4]);
#pragma unroll
      for (int i = 0; i < 4; i++) {
        float a = As[ty * 4 + i][kk];
        acc[i][0] = fmaf(a, b4.x, acc[i][0]);
        acc[i][1] = fmaf(a, b4.y, acc[i][1]);
        acc[i][2] = fmaf(a, b4.z, acc[i][2]);
        acc[i][3] = fmaf(a, b4.w, acc[i][3]);
      }
    }
    __syncthreads();
    // immediate epilogue for this f
    const float* maa_f = (f == 0) ? maa_w : (f == 1) ? maa_k
                        : (f == 2) ? maa_v : (f == 3) ? maa_r : maa_g;
    float4 mf = *(const float4*)(maa_f + cb);
    if (f == 0) {
#pragma unroll
      for (int i = 0; i < 4; i++) {
        size_t off = (size_t)(m0 + ty * 4 + i) * C + cb;
        float4 o;
        o.x = xv4[i].x + dd4[i].x * (mf.x + acc[i][0]);
        o.y = xv4[i].y + dd4[i].y * (mf.y + acc[i][1]);
        o.z = xv4[i].z + dd4[i].z * (mf.z + acc[i][2]);
        o.w = xv4[i].w + dd4[i].w * (mf.w + acc[i][3]);
        *(float4*)(xw + off) = o;
      }
    } else {
      ushort* dst = (f == 1) ? xk : (f == 2) ? xvb : (f == 3) ? xr : xg;
#pragma unroll
      for (int i = 0; i < 4; i++) {
        size_t off = (size_t)(m0 + ty * 4 + i) * C + cb;
        ushort4 ob;
        ob.x = f2bf(xv4[i].x + dd4[i].x * (mf.x + acc[i][0]));
        ob.y = f2bf(xv4[i].y + dd4[i].y * (mf.y + acc[i][1]));
        ob.z = f2bf(xv4[i].z + dd4[i].z * (mf.z + acc[i][2]));
        ob.w = f2bf(xv4[i].w + dd4[i].w * (mf.w + acc[i][3]));
        *(ushort4*)(dst + off) = ob;
      }
    }
  }
}

// -------------------------------------------- fp32 -> bf16 cvt (5 arrays) --
__global__ __launch_bounds__(256) void k_cvt5(
    const float* __restrict__ s0, const float* __restrict__ s1,
    const float* __restrict__ s2, const float* __restrict__ s3,
    const float* __restrict__ s4,
    ushort* __restrict__ d0, ushort* __restrict__ d1,
    ushort* __restrict__ d2, ushort* __restrict__ d3,
    ushort* __restrict__ d4, int n) {
  const float* s;
  ushort* d;
  switch (blockIdx.y) {
    case 0: s = s0; d = d0; break;
    case 1: s = s1; d = d1; break;
    case 2: s = s2; d = d2; break;
    case 3: s = s3; d = d3; break;
    default: s = s4; d = d4; break;
  }
  int i = (blockIdx.x * 256 + threadIdx.x) * 4;
  if (i >= n) return;
  float4 v = *(const float4*)(s + i);
  ushort4 o;
  o.x = f2bf(v.x); o.y = f2bf(v.y); o.z = f2bf(v.z); o.w = f2bf(v.w);
  *(ushort4*)(d + i) = o;
}

// ----------------------------------------------------- bf16 MFMA GEMM ------
// C[m,n] = act( sum_k A[m,k] * W[n,k] ), A/W bf16, C fp32.
template <int EPI>
__global__ __launch_bounds__(256) void k_gemm_bf(
    const ushort* __restrict__ A, const ushort* __restrict__ W,
    float* __restrict__ Cm, int M, int N, int K) {
  __shared__ ushort Al[128 * 32];
  __shared__ ushort Bl[128 * 32];
  int tid = threadIdx.x;
  int m0 = blockIdx.y * 128, n0 = blockIdx.x * 128;
  int lane = tid & 63, wave = tid >> 6;
  int wm = (wave >> 1) * 64, wn = (wave & 1) * 64;
  int lm = lane & 15, lk = (lane >> 4) * 8;
  f32x4 acc[4][4];
#pragma unroll
  for (int i = 0; i < 4; i++)
#pragma unroll
    for (int j = 0; j < 4; j++) acc[i][j] = (f32x4){0.f, 0.f, 0.f, 0.f};

  int arow = tid >> 2, achunk = (tid & 3) * 8;
  const ushort* Ag = A + (size_t)(m0 + arow) * K + achunk;
  const ushort* Wg = W + (size_t)(n0 + arow) * K + achunk;
  ushort* Ald = Al + tid * 8;
  ushort* Bld = Bl + tid * 8;

  for (int k0 = 0; k0 < K; k0 += 32) {
    GLDS16(Ag + k0, Ald);
    GLDS16(Ag + (size_t)64 * K + k0, Ald + 2048);
    GLDS16(Wg + k0, Bld);
    GLDS16(Wg + (size_t)64 * K + k0, Bld + 2048);
    __syncthreads();
    bf16x8 af[4], bf[4];
#pragma unroll
    for (int i = 0; i < 4; i++)
      af[i] = *(const bf16x8*)&Al[(wm + i * 16 + lm) * 32 + lk];
#pragma unroll
    for (int j = 0; j < 4; j++)
      bf[j] = *(const bf16x8*)&Bl[(wn + j * 16 + lm) * 32 + lk];
#pragma unroll
    for (int i = 0; i < 4; i++)
#pragma unroll
      for (int j = 0; j < 4; j++)
        acc[i][j] = __builtin_amdgcn_mfma_f32_16x16x32_bf16(
            af[i], bf[j], acc[i][j], 0, 0, 0);
    __syncthreads();
  }
  int rq = (lane >> 4) * 4;
#pragma unroll
  for (int i = 0; i < 4; i++) {
#pragma unroll
    for (int j = 0; j < 4; j++) {
      int gn = n0 + wn + j * 16 + lm;
#pragma unroll
      for (int q = 0; q < 4; q++) {
        int gm = m0 + wm + i * 16 + rq + q;
        float val = acc[i][j][q];
        if (EPI == EPI_RELU) val = fmaxf(val, 0.f);
        Cm[(size_t)gm * N + gn] = val;
      }
    }
  }
}

// -------------------------------------------------------------- fp32 gemm --
template <int EPI, bool BT>
__global__ __launch_bounds__(256) void k_gemm(
    const float* __restrict__ A, const float* __restrict__ Bm,
    const float* __restrict__ bias, float* __restrict__ Cm,
    int M, int N, int K) {
  const int BMt = 64, BNt = 64, BKt = 16;
  __shared__ float As[BKt][BMt];
  __shared__ float Bs[BKt][BNt];
  int tid = (int)threadIdx.x;
  int m0 = blockIdx.y * BMt, n0 = blockIdx.x * BNt;
  int tx = tid & 15, ty = tid >> 4;
  float acc[4][4];
#pragma unroll
  for (int i = 0; i < 4; i++)
#pragma unroll
    for (int j = 0; j < 4; j++) acc[i][j] = 0.f;

  for (int k0 = 0; k0 < K; k0 += BKt) {
#pragma unroll
    for (int i = 0; i < 4; i++) {
      int idx = tid + i * 256;
      int am = idx >> 4, ak = idx & 15;
      int gm = m0 + am, gk = k0 + ak;
      float va = 0.f;
      if (gm < M && gk < K) va = A[(size_t)gm * K + gk];
      As[ak][am] = va;
    }
#pragma unroll
    for (int i = 0; i < 4; i++) {
      int idx = tid + i * 256;
      float vb = 0.f;
      if (BT) {
        int bn = idx >> 4, bk = idx & 15;
        int gn = n0 + bn, gk = k0 + bk;
        if (gn < N && gk < K) vb = Bm[(size_t)gn * K + gk];
        Bs[bk][bn] = vb;
      } else {
        int bk = idx >> 6, bn = idx & 63;
        int gk = k0 + bk, gn = n0 + bn;
        if (gk < K && gn < N) vb = Bm[(size_t)gk * N + gn];
        Bs[bk][bn] = vb;
      }
    }
    __syncthreads();
#pragma unroll
    for (int kk = 0; kk < BKt; kk++) {
      float a[4], b[4];
#pragma unroll
      for (int i = 0; i < 4; i++) a[i] = As[kk][ty * 4 + i];
#pragma unroll
      for (int j = 0; j < 4; j++) b[j] = Bs[kk][tx * 4 + j];
#pragma unroll
      for (int i = 0; i < 4; i++)
#pragma unroll
        for (int j = 0; j < 4; j++) acc[i][j] = fmaf(a[i], b[j], acc[i][j]);
    }
    __syncthreads();
  }
#pragma unroll
  for (int i = 0; i < 4; i++) {
    int gm = m0 + ty * 4 + i;
    if (gm >= M) continue;
#pragma unroll
    for (int j = 0; j < 4; j++) {
      int gn = n0 + tx * 4 + j;
      if (gn >= N) continue;
      float c = acc[i][j];
      if (EPI == EPI_BIAS) c += bias[gn];
      if (EPI == EPI_TANH) c = tanhf(c);
      if (EPI == EPI_RELU) c = fmaxf(c, 0.f);
      Cm[(size_t)gm * N + gn] = c;
    }
  }
}

// ------------------------------------------------- chunked WKV: phase pre --
__global__ __launch_bounds__(64) void k_wkv_pre(
    const float* __restrict__ r, const float* __restrict__ k,
    const float* __restrict__ w, const float* __restrict__ u,
    float* __restrict__ rt, float* __restrict__ kt,
    float* __restrict__ aL, float* __restrict__ pdiag,
    int B, int T, int C, int H, int L) {
  int nch = T / L;
  int blk = blockIdx.x;
  int bh = blk / nch, c = blk - bh * nch;
  int b = bh / H, h = bh - b * H;
  int j = threadIdx.x;
  float uj = u[h * 64 + j];
  float cum = 0.f;
  long base = ((long)b * T + (long)c * L) * C + h * 64 + j;
  for (int tau = 0; tau < L; tau++) {
    long off = base + (long)tau * C;
    float wv = w[off];
    float rv = r[off];
    float kv = k[off];
    float e = expf(wv);
    rt[off] = rv * expf(-cum);
    cum += e;
    kt[off] = kv * expf(cum);
    float pd = rv * uj * kv;
#pragma unroll
    for (int o = 32; o >= 1; o >>= 1) pd += __shfl_xor(pd, o, 64);
    if (j == 0) pdiag[(long)bh * T + c * L + tau] = pd;
  }
  aL[((long)bh * nch + c) * 64 + j] = expf(-cum);
}

// ----------------------------------------------- chunked WKV: state prop ---
__global__ __launch_bounds__(256) void k_wkv_state(
    const float* __restrict__ rt, const float* __restrict__ kt,
    const float* __restrict__ v, const float* __restrict__ aL,
    float* __restrict__ y, int B, int T, int C, int H, int L) {
  int bh = blockIdx.x;
  int b = bh / H, h = bh - b * H;
  int nch = T / L;
  __shared__ float Rs[64 * LPAD];
  __shared__ float Ks[64 * LPAD];
  __shared__ float Vs[64 * LPAD];
  __shared__ float Yp[4][512];
  int tid = threadIdx.x;
  int lane = tid & 63;
  int jg = tid >> 6;
  float S[16];
#pragma unroll
  for (int q = 0; q < 16; q++) S[q] = 0.f;
  long hbase = (long)b * T * C + h * 64;
  for (int c = 0; c < nch; c++) {
    long cbase = hbase + (long)c * L * C;
#pragma unroll
    for (int q = 0; q < 4; q++) {
      int idx = tid + q * 256;
      int row = idx >> 4, col = (idx & 15) * 4;
      long g = cbase + (long)row * C + col;
      *(float4*)(Rs + row * LPAD + col) = *(const float4*)(rt + g);
      *(float4*)(Ks + row * LPAD + col) = *(const float4*)(kt + g);
      *(float4*)(Vs + row * LPAD + col) = *(const float4*)(v + g);
    }
    __syncthreads();
    for (int p = 0; p < 8; p++) {
      float acc[8];
#pragma unroll
      for (int t8 = 0; t8 < 8; t8++) {
        int tau = p * 8 + t8;
        float a0 = 0.f, a1 = 0.f, a2 = 0.f, a3 = 0.f;
#pragma unroll
        for (int q4 = 0; q4 < 4; q4++) {
          float4 rr = *(const float4*)(Rs + tau * LPAD + jg * 16 + q4 * 4);
          a0 = fmaf(rr.x, S[q4 * 4 + 0], a0);
          a1 = fmaf(rr.y, S[q4 * 4 + 1], a1);
          a2 = fmaf(rr.z, S[q4 * 4 + 2], a2);
          a3 = fmaf(rr.w, S[q4 * 4 + 3], a3);
        }
        acc[t8] = (a0 + a1) + (a2 + a3);
      }
#pragma unroll
      for (int t8 = 0; t8 < 8; t8++) Yp[jg][t8 * 64 + lane] = acc[t8];
      __syncthreads();
      {
        int ii = tid & 63;
#pragma unroll
        for (int s = 0; s < 2; s++) {
          int t8 = (tid >> 6) + s * 4;
          float sum = Yp[0][t8 * 64 + ii] + Yp[1][t8 * 64 + ii] +
                      Yp[2][t8 * 64 + ii] + Yp[3][t8 * 64 + ii];
          y[cbase + (long)(p * 8 + t8) * C + ii] = sum;
        }
      }
      __syncthreads();
    }
    float acc2[16];
#pragma unroll
    for (int q = 0; q < 16; q++) acc2[q] = 0.f;
    for (int s = 0; s < 64; s++) {
      float vi = Vs[s * LPAD + lane];
#pragma unroll
      for (int q4 = 0; q4 < 4; q4++) {
        float4 kk = *(const float4*)(Ks + s * LPAD + jg * 16 + q4 * 4);
        acc2[q4 * 4 + 0] = fmaf(kk.x, vi, acc2[q4 * 4 + 0]);
        acc2[q4 * 4 + 1] = fmaf(kk.y, vi, acc2[q4 * 4 + 1]);
        acc2[q4 * 4 + 2] = fmaf(kk.z, vi, acc2[q4 * 4 + 2]);
        acc2[q4 * 4 + 3] = fmaf(kk.w, vi, acc2[q4 * 4 + 3]);
      }
    }
    const float* aLc = aL + ((long)bh * nch + c) * 64 + jg * 16;
#pragma unroll
    for (int q = 0; q < 16; q++) S[q] = aLc[q] * (S[q] + acc2[q]);
    __syncthreads();
  }
}

// ---------------------------------------------- chunked WKV: intra-chunk ---
__global__ __launch_bounds__(256) void k_wkv_intra(
    const float* __restrict__ rt, const float* __restrict__ kt,
    const float* __restrict__ v, const float* __restrict__ pdiag,
    float* __restrict__ y, int B, int T, int C, int H, int L) {
  int nch = T / L;
  int blk = blockIdx.x;
  int bh = blk / nch, c = blk - bh * nch;
  int b = bh / H, h = bh - b * H;
  __shared__ float RPs[64 * LPAD];
  __shared__ float Ks[64 * LPAD];
  __shared__ float Vs[64 * LPAD];
  int tid = threadIdx.x;
  long cbase = ((long)b * T + (long)c * L) * C + h * 64;
#pragma unroll
  for (int q = 0; q < 4; q++) {
    int idx = tid + q * 256;
    int row = idx >> 4, col = (idx & 15) * 4;
    long g = cbase + (long)row * C + col;
    *(float4*)(RPs + row * LPAD + col) = *(const float4*)(rt + g);
    *(float4*)(Ks + row * LPAD + col) = *(const float4*)(kt + g);
    *(float4*)(Vs + row * LPAD + col) = *(const float4*)(v + g);
  }
  __syncthreads();
  int tau = tid & 63, sg = tid >> 6;
  float4 rreg[16];
#pragma unroll
  for (int q = 0; q < 16; q++)
    rreg[q] = *(const float4*)(RPs + tau * LPAD + q * 4);
  float pd = pdiag[(long)bh * T + c * L + tau];
  __syncthreads();
#pragma unroll 2
  for (int ss = 0; ss < 16; ss++) {
    int s = sg * 16 + ss;
    float a0 = 0.f, a1 = 0.f, a2 = 0.f, a3 = 0.f;
#pragma unroll
    for (int q = 0; q < 16; q++) {
      float4 kk = *(const float4*)(Ks + s * LPAD + q * 4);
      a0 = fmaf(rreg[q].x, kk.x, a0);
      a1 = fmaf(rreg[q].y, kk.y, a1);
      a2 = fmaf(rreg[q].z, kk.z, a2);
      a3 = fmaf(rreg[q].w, kk.w, a3);
    }
    float a = (a0 + a1) + (a2 + a3);
    float val = (s < tau) ? a : (s == tau ? pd : 0.f);
    RPs[s * LPAD + tau] = val;
  }
  __syncthreads();
  int i = tid & 63, tg = tid >> 6;
  float acc[16];
#pragma unroll
  for (int q = 0; q < 16; q++) acc[q] = 0.f;
  for (int s = 0; s < 64; s++) {
    float vi = Vs[s * LPAD + i];
#pragma unroll
    for (int q4 = 0; q4 < 4; q4++) {
      float4 pp = *(const float4*)(RPs + s * LPAD + tg * 16 + q4 * 4);
      acc[q4 * 4 + 0] = fmaf(pp.x, vi, acc[q4 * 4 + 0]);
      acc[q4 * 4 + 1] = fmaf(pp.y, vi, acc[q4 * 4 + 1]);
      acc[q4 * 4 + 2] = fmaf(pp.z, vi, acc[q4 * 4 + 2]);
      acc[q4 * 4 + 3] = fmaf(pp.w, vi, acc[q4 * 4 + 3]);
    }
  }
#pragma unroll
  for (int q = 0; q < 16; q++) {
    long off = cbase + (long)(tg * 16 + q) * C + i;
    y[off] += acc[q];
  }
}

// ----------------------------------------------------- groupnorm * gate ---
__global__ __launch_bounds__(768) void k_gnmul(
    const float* __restrict__ y, const float* __restrict__ g,
    const float* __restrict__ ln_w, const float* __restrict__ ln_b,
    ushort* __restrict__ z, int C) {
  long row = blockIdx.x;
  int c = threadIdx.x;
  long off = row * C + c;
  float val = y[off];
  float s = val;
#pragma unroll
  for (int o = 32; o >= 1; o >>= 1) s += __shfl_xor(s, o, 64);
  float mu = s * (1.f / 64.f);
  float d = val - mu;
  float vs = d * d;
#pragma unroll
  for (int o = 32; o >= 1; o >>= 1) vs += __shfl_xor(vs, o, 64);
  float var = vs * (1.f / 64.f);
  float nrm = d * rsqrtf(var + 1e-5f);
  z[off] = f2bf((nrm * ln_w[c] + ln_b[c]) * g[off]);
}

// ---------------------------------------------------------------- launch ---
extern "C" void kernel_launch(void* const* d_in, const int* in_sizes, int n_in,
                              void* d_out, int out_size, void* d_ws, size_t ws_size,
                              hipStream_t stream) {
  const int B = 8, T = 1024, C = 768, H = 12, ph = 32, pw = 32;
  const int M = B * T;
  const int L = 64, NCH = T / L;

  const float* x        = (const float*)d_in[0];
  const float* W_r      = (const float*)d_in[1];
  const float* W_k      = (const float*)d_in[2];
  const float* W_v      = (const float*)d_in[3];
  const float* W_g      = (const float*)d_in[4];
  const float* W_o      = (const float*)d_in[5];
  const float* maa_x    = (const float*)d_in[6];
  const float* maa_w    = (const float*)d_in[7];
  const float* maa_k    = (const float*)d_in[8];
  const float* maa_v    = (const float*)d_in[9];
  const float* maa_r    = (const float*)d_in[10];
  const float* maa_g    = (const float*)d_in[11];
  const float* maa_w1   = (const float*)d_in[12];
  const float* maa_w2   = (const float*)d_in[13];
  const float* time_dec = (const float*)d_in[14];
  const float* dec_w1   = (const float*)d_in[15];
  const float* dec_w2   = (const float*)d_in[16];
  const float* faaaa    = (const float*)d_in[17];
  const float* ln_w     = (const float*)d_in[18];
  const float* ln_b     = (const float*)d_in[19];

  float* ws = (float*)d_ws;
  const size_t S = (size_t)M * C;
  float* F0 = ws + 0 * S;   // xx   -> r
  float* F1 = ws + 1 * S;   // xxx  -> k -> y
  float* F2 = ws + 2 * S;   // xw   -> w -> Kt (in place)
  float* F3 = ws + 3 * S;   // v
  float* F4 = ws + 4 * S;   // g
  float* F5 = ws + 5 * S;   // xr_bf | xk_bf  -> Rt (fp32)
  float* F6 = ws + 6 * S;   // xv_bf | xg_bf  -> z_bf
  float* t5    = ws + 7 * S;            // [M,160] -> bf16 weights W_r..W_g
  float* t6    = t5 + (size_t)M * 160;  // [M,64]  -> bf16 W_o
  float* aLb   = t6 + (size_t)M * 64;
  float* pdiag = aLb + (size_t)B * H * NCH * 64;

  ushort* xr_bf = (ushort*)F5;
  ushort* xk_bf = xr_bf + S;
  ushort* xv_bf = (ushort*)F6;
  ushort* xg_bf = xv_bf + S;
  ushort* z_bf  = (ushort*)F6;
  const int WSZ = C * C;
  ushort* wr_bf = (ushort*)t5;
  ushort* wk_bf = wr_bf + WSZ;
  ushort* wv_bf = wk_bf + WSZ;
  ushort* wg_bf = wv_bf + WSZ;
  ushort* wo_bf = (ushort*)t6;

  // 1. qshift
  {
    long total = (long)M * C;
    k_qshift<<<(int)((total + 255) / 256), 256, 0, stream>>>(
        x, maa_x, F0, F1, B, T, C, ph, pw);
  }
  // 2. t5 = tanh(xxx @ maa_w1)
  {
    dim3 grid(3, M / 64);
    k_gemm<EPI_TANH, false><<<grid, 256, 0, stream>>>(F1, maa_w1, nullptr, t5, M, 160, C);
  }
  // 3. mix5 (xw fp32, xk/xv/xr/xg bf16) — spill-free per-f version
  {
    dim3 grid(C / 64, M / 64);
    k_mix5f<<<grid, 256, 0, stream>>>(t5, maa_w2, x, F0, maa_w, maa_k, maa_v,
                                      maa_r, maa_g, F2, xk_bf, xv_bf, xr_bf, xg_bf, C);
  }
  // 4. weight conversion (t5/t6 dead now): one dispatch for all 5
  {
    dim3 grid((WSZ / 4 + 255) / 256, 5);
    k_cvt5<<<grid, 256, 0, stream>>>(W_r, W_k, W_v, W_g, W_o,
                                     wr_bf, wk_bf, wv_bf, wg_bf, wo_bf, WSZ);
  }
  // 5. big projections: bf16 MFMA
  {
    dim3 grid(C / 128, M / 128);
    k_gemm_bf<EPI_NONE><<<grid, 256, 0, stream>>>(xr_bf, wr_bf, F0, M, C, C);
    k_gemm_bf<EPI_NONE><<<grid, 256, 0, stream>>>(xk_bf, wk_bf, F1, M, C, C);
    k_gemm_bf<EPI_NONE><<<grid, 256, 0, stream>>>(xv_bf, wv_bf, F3, M, C, C);
    k_gemm_bf<EPI_RELU><<<grid, 256, 0, stream>>>(xg_bf, wg_bf, F4, M, C, C);
  }
  // 6. decay path (fp32) — t6 region holds bf16 W_o now, so use pdiag+T*B*H
  //    scratch for the [M,64] intermediate instead.
  float* dec_t = pdiag + (size_t)B * H * T;  // [M,64] fp32 scratch
  {
    dim3 grid1(1, M / 64);
    k_gemm<EPI_TANH, false><<<grid1, 256, 0, stream>>>(F2, dec_w1, nullptr, dec_t, M, 64, C);
    dim3 grid(C / 64, M / 64);
    k_gemm<EPI_BIAS, false><<<grid, 256, 0, stream>>>(dec_t, dec_w2, time_dec, F2, M, C, 64);
  }
  // 7. chunked wkv6: r=F0, k=F1, w=F2 -> Rt=F5, Kt=F2(inplace), y=F1
  k_wkv_pre<<<B * H * NCH, 64, 0, stream>>>(F0, F1, F2, faaaa, F5, F2,
                                            aLb, pdiag, B, T, C, H, L);
  k_wkv_state<<<B * H, 256, 0, stream>>>(F5, F2, F3, aLb, F1, B, T, C, H, L);
  k_wkv_intra<<<B * H * NCH, 256, 0, stream>>>(F5, F2, F3, pdiag, F1, B, T, C, H, L);
  // 8. groupnorm * gate -> z bf16
  k_gnmul<<<M, 768, 0, stream>>>(F1, F4, ln_w, ln_b, z_bf, C);
  // 9. out = z @ W_o^T (bf16 MFMA)
  {
    dim3 grid(C / 128, M / 128);
    k_gemm_bf<EPI_NONE><<<grid, 256, 0, stream>>>(z_bf, wo_bf, (float*)d_out, M, C, C);
  }
}

// Round 6
// 699.804 us; speedup vs baseline: 5.2773x; 1.2674x over previous
//
#include <hip/hip_runtime.h>
#include <math.h>

// ---------------------------------------------------------------------------
// TimeMix (RWKV-6 vision block) — round 6: parallel WKV state (kv+scan+aug
// intra), bf16 t5 GEMM. B=8, T=1024, C=768, H=12 heads of 64, M=8192.
// ---------------------------------------------------------------------------

#define EPI_NONE 0
#define EPI_TANH 1
#define EPI_RELU 2
#define EPI_BIAS 3

#define LPAD 68   // LDS row stride (floats) for 64-wide chunk tiles

typedef float f32x4 __attribute__((ext_vector_type(4)));
typedef __bf16 bf16x8 __attribute__((ext_vector_type(8)));

__device__ __forceinline__ ushort f2bf(float x) {
  unsigned u = __float_as_uint(x);
  return (ushort)((u + 0x7fffu + ((u >> 16) & 1u)) >> 16);
}

#define GLDS16(gp, lp)                                                   \
  __builtin_amdgcn_global_load_lds(                                      \
      (const __attribute__((address_space(1))) void*)(gp),               \
      (__attribute__((address_space(3))) void*)(lp), 16, 0, 0)

// ---------------------------------------------------------------- qshift ---
// xx fp32 (mix5f input), xxx bf16 (t5 MFMA GEMM input).
__global__ __launch_bounds__(256) void k_qshift(
    const float* __restrict__ x, const float* __restrict__ maa_x,
    float* __restrict__ xx, ushort* __restrict__ xxx_bf,
    int B, int T, int C, int ph, int pw) {
  long idx = (long)blockIdx.x * blockDim.x + threadIdx.x;
  long total = (long)B * T * C;
  if (idx >= total) return;
  int c = (int)(idx % C);
  long bt = idx / C;
  int t = (int)(bt % T);
  int quarter = (c & 63) >> 4;
  int hh = t / pw;
  int ww = t - hh * pw;
  long rowbase = (bt - t) * C;
  float sval = 0.f;
  int st = -1;
  if (quarter == 0)      { if (ww >= 1)      st = t - 1;  }
  else if (quarter == 1) { if (ww < pw - 1)  st = t + 1;  }
  else if (quarter == 2) { if (hh >= 1)      st = t - pw; }
  else                   { if (hh < ph - 1)  st = t + pw; }
  if (st >= 0) sval = x[rowbase + (long)st * C + c];
  float xval = x[idx];
  float d = sval - xval;
  xx[idx] = d;
  xxx_bf[idx] = f2bf(xval + d * maa_x[c]);
}

// ------------------------------------- maa_w1 transpose+convert to bf16 ----
// out[n][k] = maa_w1[k][n] for n<160, 0 for 160<=n<256. out is [256,768] bf16.
__global__ __launch_bounds__(256) void k_w1t(
    const float* __restrict__ w1, ushort* __restrict__ out) {
  int n = blockIdx.y;
  int k = blockIdx.x * 256 + threadIdx.x;
  float v = (n < 160) ? w1[(size_t)k * 160 + n] : 0.f;
  out[(size_t)n * 768 + k] = f2bf(v);
}

// ---------------------------------------------- mix5 fused GEMM+epilogue ---
__global__ __launch_bounds__(256) void k_mix5f(
    const float* __restrict__ t5, const float* __restrict__ maa_w2,
    const float* __restrict__ x, const float* __restrict__ xx,
    const float* __restrict__ maa_w, const float* __restrict__ maa_k,
    const float* __restrict__ maa_v, const float* __restrict__ maa_r,
    const float* __restrict__ maa_g,
    float* __restrict__ xw, ushort* __restrict__ xk, ushort* __restrict__ xvb,
    ushort* __restrict__ xr, ushort* __restrict__ xg, int C) {
  __shared__ float As[64][36];
  __shared__ float Bs[32][64];
  int tid = threadIdx.x;
  int m0 = blockIdx.y * 64, n0 = blockIdx.x * 64;
  int tx = tid & 15, ty = tid >> 4;
  int cb = n0 + tx * 4;
  float4 xv4[4], dd4[4];
#pragma unroll
  for (int i = 0; i < 4; i++) {
    size_t off = (size_t)(m0 + ty * 4 + i) * C + cb;
    xv4[i] = *(const float4*)(x + off);
    dd4[i] = *(const float4*)(xx + off);
  }

#pragma unroll
  for (int f = 0; f < 5; f++) {
    {
      int k4 = (tid & 7) * 4;
      int row = tid >> 3;
      const float* src = t5 + (size_t)(m0 + row) * 160 + f * 32 + k4;
      float4 v0 = *(const float4*)src;
      float4 v1 = *(const float4*)(src + 32 * 160);
      *(float4*)(&As[row][k4]) = v0;
      *(float4*)(&As[row + 32][k4]) = v1;
    }
    {
      int col = (tid & 15) * 4, kk = tid >> 4;
      const float* src = maa_w2 + (size_t)(f * 32 + kk) * C + n0 + col;
      *(float4*)(&Bs[kk][col]) = *(const float4*)src;
      *(float4*)(&Bs[kk + 16][col]) = *(const float4*)(src + (size_t)16 * C);
    }
    __syncthreads();
    float acc[4][4];
#pragma unroll
    for (int i = 0; i < 4; i++)
#pragma unroll
      for (int j = 0; j < 4; j++) acc[i][j] = 0.f;
#pragma unroll
    for (int kk = 0; kk < 32; kk++) {
      float4 b4 = *(const float4*)(&Bs[kk][tx * 4]);
#pragma unroll
      for (int i = 0; i < 4; i++) {
        float a = As[ty * 4 + i][kk];
        acc[i][0] = fmaf(a, b4.x, acc[i][0]);
        acc[i][1] = fmaf(a, b4.y, acc[i][1]);
        acc[i][2] = fmaf(a, b4.z, acc[i][2]);
        acc[i][3] = fmaf(a, b4.w, acc[i][3]);
      }
    }
    __syncthreads();
    const float* maa_f = (f == 0) ? maa_w : (f == 1) ? maa_k
                        : (f == 2) ? maa_v : (f == 3) ? maa_r : maa_g;
    float4 mf = *(const float4*)(maa_f + cb);
    if (f == 0) {
#pragma unroll
      for (int i = 0; i < 4; i++) {
        size_t off = (size_t)(m0 + ty * 4 + i) * C + cb;
        float4 o;
        o.x = xv4[i].x + dd4[i].x * (mf.x + acc[i][0]);
        o.y = xv4[i].y + dd4[i].y * (mf.y + acc[i][1]);
        o.z = xv4[i].z + dd4[i].z * (mf.z + acc[i][2]);
        o.w = xv4[i].w + dd4[i].w * (mf.w + acc[i][3]);
        *(float4*)(xw + off) = o;
      }
    } else {
      ushort* dst = (f == 1) ? xk : (f == 2) ? xvb : (f == 3) ? xr : xg;
#pragma unroll
      for (int i = 0; i < 4; i++) {
        size_t off = (size_t)(m0 + ty * 4 + i) * C + cb;
        ushort4 ob;
        ob.x = f2bf(xv4[i].x + dd4[i].x * (mf.x + acc[i][0]));
        ob.y = f2bf(xv4[i].y + dd4[i].y * (mf.y + acc[i][1]));
        ob.z = f2bf(xv4[i].z + dd4[i].z * (mf.z + acc[i][2]));
        ob.w = f2bf(xv4[i].w + dd4[i].w * (mf.w + acc[i][3]));
        *(ushort4*)(dst + off) = ob;
      }
    }
  }
}

// -------------------------------------------- fp32 -> bf16 cvt (5 arrays) --
__global__ __launch_bounds__(256) void k_cvt5(
    const float* __restrict__ s0, const float* __restrict__ s1,
    const float* __restrict__ s2, const float* __restrict__ s3,
    const float* __restrict__ s4,
    ushort* __restrict__ d0, ushort* __restrict__ d1,
    ushort* __restrict__ d2, ushort* __restrict__ d3,
    ushort* __restrict__ d4, int n) {
  const float* s;
  ushort* d;
  switch (blockIdx.y) {
    case 0: s = s0; d = d0; break;
    case 1: s = s1; d = d1; break;
    case 2: s = s2; d = d2; break;
    case 3: s = s3; d = d3; break;
    default: s = s4; d = d4; break;
  }
  int i = (blockIdx.x * 256 + threadIdx.x) * 4;
  if (i >= n) return;
  float4 v = *(const float4*)(s + i);
  ushort4 o;
  o.x = f2bf(v.x); o.y = f2bf(v.y); o.z = f2bf(v.z); o.w = f2bf(v.w);
  *(ushort4*)(d + i) = o;
}

// ----------------------------------------------------- bf16 MFMA GEMM ------
// C[m,n] = act( sum_k A[m,k] * W[n,k] ), A/W bf16, C fp32.
// NMASK: guard stores with gn < N (W buffer must still have ceil128 rows).
template <int EPI, bool NMASK>
__global__ __launch_bounds__(256) void k_gemm_bf(
    const ushort* __restrict__ A, const ushort* __restrict__ W,
    float* __restrict__ Cm, int M, int N, int K) {
  __shared__ ushort Al[128 * 32];
  __shared__ ushort Bl[128 * 32];
  int tid = threadIdx.x;
  int m0 = blockIdx.y * 128, n0 = blockIdx.x * 128;
  int lane = tid & 63, wave = tid >> 6;
  int wm = (wave >> 1) * 64, wn = (wave & 1) * 64;
  int lm = lane & 15, lk = (lane >> 4) * 8;
  f32x4 acc[4][4];
#pragma unroll
  for (int i = 0; i < 4; i++)
#pragma unroll
    for (int j = 0; j < 4; j++) acc[i][j] = (f32x4){0.f, 0.f, 0.f, 0.f};

  int arow = tid >> 2, achunk = (tid & 3) * 8;
  const ushort* Ag = A + (size_t)(m0 + arow) * K + achunk;
  const ushort* Wg = W + (size_t)(n0 + arow) * K + achunk;
  ushort* Ald = Al + tid * 8;
  ushort* Bld = Bl + tid * 8;

  for (int k0 = 0; k0 < K; k0 += 32) {
    GLDS16(Ag + k0, Ald);
    GLDS16(Ag + (size_t)64 * K + k0, Ald + 2048);
    GLDS16(Wg + k0, Bld);
    GLDS16(Wg + (size_t)64 * K + k0, Bld + 2048);
    __syncthreads();
    bf16x8 af[4], bf[4];
#pragma unroll
    for (int i = 0; i < 4; i++)
      af[i] = *(const bf16x8*)&Al[(wm + i * 16 + lm) * 32 + lk];
#pragma unroll
    for (int j = 0; j < 4; j++)
      bf[j] = *(const bf16x8*)&Bl[(wn + j * 16 + lm) * 32 + lk];
#pragma unroll
    for (int i = 0; i < 4; i++)
#pragma unroll
      for (int j = 0; j < 4; j++)
        acc[i][j] = __builtin_amdgcn_mfma_f32_16x16x32_bf16(
            af[i], bf[j], acc[i][j], 0, 0, 0);
    __syncthreads();
  }
  int rq = (lane >> 4) * 4;
#pragma unroll
  for (int i = 0; i < 4; i++) {
#pragma unroll
    for (int j = 0; j < 4; j++) {
      int gn = n0 + wn + j * 16 + lm;
      if (NMASK && gn >= N) continue;
#pragma unroll
      for (int q = 0; q < 4; q++) {
        int gm = m0 + wm + i * 16 + rq + q;
        float val = acc[i][j][q];
        if (EPI == EPI_RELU) val = fmaxf(val, 0.f);
        if (EPI == EPI_TANH) val = tanhf(val);
        Cm[(size_t)gm * N + gn] = val;
      }
    }
  }
}

// -------------------------------------------------------------- fp32 gemm --
template <int EPI, bool BT>
__global__ __launch_bounds__(256) void k_gemm(
    const float* __restrict__ A, const float* __restrict__ Bm,
    const float* __restrict__ bias, float* __restrict__ Cm,
    int M, int N, int K) {
  const int BMt = 64, BNt = 64, BKt = 16;
  __shared__ float As[BKt][BMt];
  __shared__ float Bs[BKt][BNt];
  int tid = (int)threadIdx.x;
  int m0 = blockIdx.y * BMt, n0 = blockIdx.x * BNt;
  int tx = tid & 15, ty = tid >> 4;
  float acc[4][4];
#pragma unroll
  for (int i = 0; i < 4; i++)
#pragma unroll
    for (int j = 0; j < 4; j++) acc[i][j] = 0.f;

  for (int k0 = 0; k0 < K; k0 += BKt) {
#pragma unroll
    for (int i = 0; i < 4; i++) {
      int idx = tid + i * 256;
      int am = idx >> 4, ak = idx & 15;
      int gm = m0 + am, gk = k0 + ak;
      float va = 0.f;
      if (gm < M && gk < K) va = A[(size_t)gm * K + gk];
      As[ak][am] = va;
    }
#pragma unroll
    for (int i = 0; i < 4; i++) {
      int idx = tid + i * 256;
      float vb = 0.f;
      if (BT) {
        int bn = idx >> 4, bk = idx & 15;
        int gn = n0 + bn, gk = k0 + bk;
        if (gn < N && gk < K) vb = Bm[(size_t)gn * K + gk];
        Bs[bk][bn] = vb;
      } else {
        int bk = idx >> 6, bn = idx & 63;
        int gk = k0 + bk, gn = n0 + bn;
        if (gk < K && gn < N) vb = Bm[(size_t)gk * N + gn];
        Bs[bk][bn] = vb;
      }
    }
    __syncthreads();
#pragma unroll
    for (int kk = 0; kk < BKt; kk++) {
      float a[4], b[4];
#pragma unroll
      for (int i = 0; i < 4; i++) a[i] = As[kk][ty * 4 + i];
#pragma unroll
      for (int j = 0; j < 4; j++) b[j] = Bs[kk][tx * 4 + j];
#pragma unroll
      for (int i = 0; i < 4; i++)
#pragma unroll
        for (int j = 0; j < 4; j++) acc[i][j] = fmaf(a[i], b[j], acc[i][j]);
    }
    __syncthreads();
  }
#pragma unroll
  for (int i = 0; i < 4; i++) {
    int gm = m0 + ty * 4 + i;
    if (gm >= M) continue;
#pragma unroll
    for (int j = 0; j < 4; j++) {
      int gn = n0 + tx * 4 + j;
      if (gn >= N) continue;
      float c = acc[i][j];
      if (EPI == EPI_BIAS) c += bias[gn];
      if (EPI == EPI_TANH) c = tanhf(c);
      if (EPI == EPI_RELU) c = fmaxf(c, 0.f);
      Cm[(size_t)gm * N + gn] = c;
    }
  }
}

// ------------------------------------------------- chunked WKV: phase pre --
__global__ __launch_bounds__(64) void k_wkv_pre(
    const float* __restrict__ r, const float* __restrict__ k,
    const float* __restrict__ w, const float* __restrict__ u,
    float* __restrict__ rt, float* __restrict__ kt,
    float* __restrict__ aL, float* __restrict__ pdiag,
    int B, int T, int C, int H, int L) {
  int nch = T / L;
  int blk = blockIdx.x;
  int bh = blk / nch, c = blk - bh * nch;
  int b = bh / H, h = bh - b * H;
  int j = threadIdx.x;
  float uj = u[h * 64 + j];
  float cum = 0.f;
  long base = ((long)b * T + (long)c * L) * C + h * 64 + j;
  for (int tau = 0; tau < L; tau++) {
    long off = base + (long)tau * C;
    float wv = w[off];
    float rv = r[off];
    float kv = k[off];
    float e = expf(wv);
    rt[off] = rv * expf(-cum);
    cum += e;
    kt[off] = kv * expf(cum);
    float pd = rv * uj * kv;
#pragma unroll
    for (int o = 32; o >= 1; o >>= 1) pd += __shfl_xor(pd, o, 64);
    if (j == 0) pdiag[(long)bh * T + c * L + tau] = pd;
  }
  aL[((long)bh * nch + c) * 64 + j] = expf(-cum);
}

// --------------------------------------- chunked WKV: per-chunk KV outer ---
// grid = B*H*nch, 256 thr. kvb[bh,c,j,i] = sum_s Kt[s,j]*V[s,i]. Parallel.
__global__ __launch_bounds__(256) void k_wkv_kv(
    const float* __restrict__ kt, const float* __restrict__ v,
    float* __restrict__ kvb, int B, int T, int C, int H, int L) {
  int nch = T / L;
  int blk = blockIdx.x;
  int bh = blk / nch, c = blk - bh * nch;
  int b = bh / H, h = bh - b * H;
  __shared__ float Ks[64 * LPAD];
  __shared__ float Vs[64 * LPAD];
  int tid = threadIdx.x;
  int lane = tid & 63, jg = tid >> 6;
  long cbase = ((long)b * T + (long)c * L) * C + h * 64;
#pragma unroll
  for (int q = 0; q < 4; q++) {
    int idx = tid + q * 256;
    int row = idx >> 4, col = (idx & 15) * 4;
    long g = cbase + (long)row * C + col;
    *(float4*)(Ks + row * LPAD + col) = *(const float4*)(kt + g);
    *(float4*)(Vs + row * LPAD + col) = *(const float4*)(v + g);
  }
  __syncthreads();
  float acc[16];
#pragma unroll
  for (int q = 0; q < 16; q++) acc[q] = 0.f;
  for (int s = 0; s < 64; s++) {
    float vi = Vs[s * LPAD + lane];
#pragma unroll
    for (int q4 = 0; q4 < 4; q4++) {
      float4 kk = *(const float4*)(Ks + s * LPAD + jg * 16 + q4 * 4);
      acc[q4 * 4 + 0] = fmaf(kk.x, vi, acc[q4 * 4 + 0]);
      acc[q4 * 4 + 1] = fmaf(kk.y, vi, acc[q4 * 4 + 1]);
      acc[q4 * 4 + 2] = fmaf(kk.z, vi, acc[q4 * 4 + 2]);
      acc[q4 * 4 + 3] = fmaf(kk.w, vi, acc[q4 * 4 + 3]);
    }
  }
  float* out = kvb + ((long)bh * nch + c) * 4096;
#pragma unroll
  for (int q = 0; q < 16; q++) out[(jg * 16 + q) * 64 + lane] = acc[q];
}

// ---------------------------------------- chunked WKV: state prefix scan ---
// grid = B*H, 256 thr (16 state elems each). Scb[bh,c] = state ENTERING c.
__global__ __launch_bounds__(256) void k_wkv_scan(
    const float* __restrict__ kvb, const float* __restrict__ aL,
    float* __restrict__ Scb, int nch) {
  int bh = blockIdx.x;
  int tid = threadIdx.x;
  float S[16];
#pragma unroll
  for (int q = 0; q < 16; q++) S[q] = 0.f;
  for (int c = 0; c < nch; c++) {
    const float* kv = kvb + ((long)bh * nch + c) * 4096;
    float* sc = Scb + ((long)bh * nch + c) * 4096;
    const float* aLc = aL + ((long)bh * nch + c) * 64;
#pragma unroll
    for (int q = 0; q < 16; q++) {
      int e = q * 256 + tid;
      sc[e] = S[q];
      S[q] = aLc[e >> 6] * (S[q] + kv[e]);
    }
  }
}

// --------------------------- chunked WKV: intra + inter (augmented matmul) -
// y = mask(Rt Kt^T + diag) @ V + Rt @ S_prev. Fully parallel, 1536 blocks.
__global__ __launch_bounds__(256) void k_wkv_intra(
    const float* __restrict__ rt, const float* __restrict__ kt,
    const float* __restrict__ v, const float* __restrict__ pdiag,
    const float* __restrict__ Scb, float* __restrict__ y,
    int B, int T, int C, int H, int L) {
  int nch = T / L;
  int blk = blockIdx.x;
  int bh = blk / nch, c = blk - bh * nch;
  int b = bh / H, h = bh - b * H;
  __shared__ float RPs[64 * LPAD];   // Rt tile -> P^T
  __shared__ float Ks[64 * LPAD];    // Kt tile -> Rt^T
  __shared__ float Vs[64 * LPAD];
  __shared__ float Ss[64 * 64];      // S_prev
  int tid = threadIdx.x;
  long cbase = ((long)b * T + (long)c * L) * C + h * 64;
  const float* scp = Scb + ((long)bh * nch + c) * 4096;
#pragma unroll
  for (int q = 0; q < 4; q++) {
    int idx = tid + q * 256;
    int row = idx >> 4, col = (idx & 15) * 4;
    long g = cbase + (long)row * C + col;
    *(float4*)(RPs + row * LPAD + col) = *(const float4*)(rt + g);
    *(float4*)(Ks + row * LPAD + col) = *(const float4*)(kt + g);
    *(float4*)(Vs + row * LPAD + col) = *(const float4*)(v + g);
  }
#pragma unroll
  for (int q = 0; q < 4; q++) {
    int e = (tid & 63) * 4 + (tid >> 6) * 1024 + (q & 1) * 256 + (q >> 1) * 512;
    // simpler: contiguous float4 copy
  }
#pragma unroll
  for (int q = 0; q < 4; q++) {
    int e4 = (tid + q * 256) * 4;
    *(float4*)(Ss + e4) = *(const float4*)(scp + e4);
  }
  __syncthreads();
  int tau = tid & 63, sg = tid >> 6;
  float4 rreg[16];
#pragma unroll
  for (int q = 0; q < 16; q++)
    rreg[q] = *(const float4*)(RPs + tau * LPAD + q * 4);
  float pd = pdiag[(long)bh * T + c * L + tau];
  __syncthreads();   // Rt reads done; RPs becomes P^T storage
#pragma unroll 2
  for (int ss = 0; ss < 16; ss++) {
    int s = sg * 16 + ss;
    float a0 = 0.f, a1 = 0.f, a2 = 0.f, a3 = 0.f;
#pragma unroll
    for (int q = 0; q < 16; q++) {
      float4 kk = *(const float4*)(Ks + s * LPAD + q * 4);
      a0 = fmaf(rreg[q].x, kk.x, a0);
      a1 = fmaf(rreg[q].y, kk.y, a1);
      a2 = fmaf(rreg[q].z, kk.z, a2);
      a3 = fmaf(rreg[q].w, kk.w, a3);
    }
    float a = (a0 + a1) + (a2 + a3);
    float val = (s < tau) ? a : (s == tau ? pd : 0.f);
    RPs[s * LPAD + tau] = val;
  }
  __syncthreads();   // Kt reads done; Ks becomes Rt^T storage
#pragma unroll
  for (int qq = 0; qq < 16; qq++) {
    const float* rr = (const float*)&rreg[sg * 4 + (qq >> 2)];
    Ks[(sg * 16 + qq) * LPAD + tau] = rr[qq & 3];
  }
  __syncthreads();
  int i = tid & 63, tg = tid >> 6;
  float acc[16];
#pragma unroll
  for (int q = 0; q < 16; q++) acc[q] = 0.f;
  for (int s = 0; s < 64; s++) {       // intra: P @ V
    float vi = Vs[s * LPAD + i];
#pragma unroll
    for (int q4 = 0; q4 < 4; q4++) {
      float4 pp = *(const float4*)(RPs + s * LPAD + tg * 16 + q4 * 4);
      acc[q4 * 4 + 0] = fmaf(pp.x, vi, acc[q4 * 4 + 0]);
      acc[q4 * 4 + 1] = fmaf(pp.y, vi, acc[q4 * 4 + 1]);
      acc[q4 * 4 + 2] = fmaf(pp.z, vi, acc[q4 * 4 + 2]);
      acc[q4 * 4 + 3] = fmaf(pp.w, vi, acc[q4 * 4 + 3]);
    }
  }
  for (int j = 0; j < 64; j++) {       // inter: Rt @ S_prev
    float si = Ss[j * 64 + i];
#pragma unroll
    for (int q4 = 0; q4 < 4; q4++) {
      float4 pp = *(const float4*)(Ks + j * LPAD + tg * 16 + q4 * 4);
      acc[q4 * 4 + 0] = fmaf(pp.x, si, acc[q4 * 4 + 0]);
      acc[q4 * 4 + 1] = fmaf(pp.y, si, acc[q4 * 4 + 1]);
      acc[q4 * 4 + 2] = fmaf(pp.z, si, acc[q4 * 4 + 2]);
      acc[q4 * 4 + 3] = fmaf(pp.w, si, acc[q4 * 4 + 3]);
    }
  }
#pragma unroll
  for (int q = 0; q < 16; q++) {
    long off = cbase + (long)(tg * 16 + q) * C + i;
    y[off] = acc[q];
  }
}

// ----------------------------------------------------- groupnorm * gate ---
__global__ __launch_bounds__(768) void k_gnmul(
    const float* __restrict__ y, const float* __restrict__ g,
    const float* __restrict__ ln_w, const float* __restrict__ ln_b,
    ushort* __restrict__ z, int C) {
  long row = blockIdx.x;
  int c = threadIdx.x;
  long off = row * C + c;
  float val = y[off];
  float s = val;
#pragma unroll
  for (int o = 32; o >= 1; o >>= 1) s += __shfl_xor(s, o, 64);
  float mu = s * (1.f / 64.f);
  float d = val - mu;
  float vs = d * d;
#pragma unroll
  for (int o = 32; o >= 1; o >>= 1) vs += __shfl_xor(vs, o, 64);
  float var = vs * (1.f / 64.f);
  float nrm = d * rsqrtf(var + 1e-5f);
  z[off] = f2bf((nrm * ln_w[c] + ln_b[c]) * g[off]);
}

// ---------------------------------------------------------------- launch ---
extern "C" void kernel_launch(void* const* d_in, const int* in_sizes, int n_in,
                              void* d_out, int out_size, void* d_ws, size_t ws_size,
                              hipStream_t stream) {
  const int B = 8, T = 1024, C = 768, H = 12, ph = 32, pw = 32;
  const int M = B * T;
  const int L = 64, NCH = T / L;

  const float* x        = (const float*)d_in[0];
  const float* W_r      = (const float*)d_in[1];
  const float* W_k      = (const float*)d_in[2];
  const float* W_v      = (const float*)d_in[3];
  const float* W_g      = (const float*)d_in[4];
  const float* W_o      = (const float*)d_in[5];
  const float* maa_x    = (const float*)d_in[6];
  const float* maa_w    = (const float*)d_in[7];
  const float* maa_k    = (const float*)d_in[8];
  const float* maa_v    = (const float*)d_in[9];
  const float* maa_r    = (const float*)d_in[10];
  const float* maa_g    = (const float*)d_in[11];
  const float* maa_w1   = (const float*)d_in[12];
  const float* maa_w2   = (const float*)d_in[13];
  const float* time_dec = (const float*)d_in[14];
  const float* dec_w1   = (const float*)d_in[15];
  const float* dec_w2   = (const float*)d_in[16];
  const float* faaaa    = (const float*)d_in[17];
  const float* ln_w     = (const float*)d_in[18];
  const float* ln_b     = (const float*)d_in[19];

  float* ws = (float*)d_ws;
  const size_t S = (size_t)M * C;
  float* F0 = ws + 0 * S;   // xx -> r -> kvb -> y
  float* F1 = ws + 1 * S;   // xxx_bf -> k -> Scb
  float* F2 = ws + 2 * S;   // xw -> w -> Kt (in place)
  float* F3 = ws + 3 * S;   // v
  float* F4 = ws + 4 * S;   // g
  float* F5 = ws + 5 * S;   // xr_bf | xk_bf -> Rt (fp32)
  float* F6 = ws + 6 * S;   // xv_bf | xg_bf -> z_bf
  float* t5    = ws + 7 * S;            // [M,160] fp32 -> bf16 W_r..W_g
  float* t6    = t5 + (size_t)M * 160;  // bf16 W_o + maa1T
  float* aLb   = t6 + (size_t)M * 64;
  float* pdiag = aLb + (size_t)B * H * NCH * 64;
  float* dec_t = pdiag + (size_t)B * H * T;   // [M,64] fp32 scratch

  ushort* xxx_bf = (ushort*)F1;
  ushort* xr_bf = (ushort*)F5;
  ushort* xk_bf = xr_bf + S;
  ushort* xv_bf = (ushort*)F6;
  ushort* xg_bf = xv_bf + S;
  ushort* z_bf  = (ushort*)F6;
  float* kvb = F0;
  float* Scb = F1;
  const int WSZ = C * C;
  ushort* wr_bf = (ushort*)t5;
  ushort* wk_bf = wr_bf + WSZ;
  ushort* wv_bf = wk_bf + WSZ;
  ushort* wg_bf = wv_bf + WSZ;
  ushort* wo_bf = (ushort*)t6;
  ushort* maa1T = wo_bf + WSZ;          // [256,768] bf16, fits in t6 region

  // 1. qshift (xx fp32, xxx bf16)
  {
    long total = (long)M * C;
    k_qshift<<<(int)((total + 255) / 256), 256, 0, stream>>>(
        x, maa_x, F0, xxx_bf, B, T, C, ph, pw);
  }
  // 2. maa_w1 transpose->bf16, then t5 = tanh(xxx @ maa_w1) via MFMA
  {
    dim3 gt(3, 256);
    k_w1t<<<gt, 256, 0, stream>>>(maa_w1, maa1T);
    dim3 grid(2, M / 128);
    k_gemm_bf<EPI_TANH, true><<<grid, 256, 0, stream>>>(xxx_bf, maa1T, t5, M, 160, C);
  }
  // 3. mix5 (xw fp32, xk/xv/xr/xg bf16)
  {
    dim3 grid(C / 64, M / 64);
    k_mix5f<<<grid, 256, 0, stream>>>(t5, maa_w2, x, F0, maa_w, maa_k, maa_v,
                                      maa_r, maa_g, F2, xk_bf, xv_bf, xr_bf, xg_bf, C);
  }
  // 4. weight conversion (t5 data dead now)
  {
    dim3 grid((WSZ / 4 + 255) / 256, 5);
    k_cvt5<<<grid, 256, 0, stream>>>(W_r, W_k, W_v, W_g, W_o,
                                     wr_bf, wk_bf, wv_bf, wg_bf, wo_bf, WSZ);
  }
  // 5. big projections: bf16 MFMA
  {
    dim3 grid(C / 128, M / 128);
    k_gemm_bf<EPI_NONE, false><<<grid, 256, 0, stream>>>(xr_bf, wr_bf, F0, M, C, C);
    k_gemm_bf<EPI_NONE, false><<<grid, 256, 0, stream>>>(xk_bf, wk_bf, F1, M, C, C);
    k_gemm_bf<EPI_NONE, false><<<grid, 256, 0, stream>>>(xv_bf, wv_bf, F3, M, C, C);
    k_gemm_bf<EPI_RELU, false><<<grid, 256, 0, stream>>>(xg_bf, wg_bf, F4, M, C, C);
  }
  // 6. decay path (fp32)
  {
    dim3 grid1(1, M / 64);
    k_gemm<EPI_TANH, false><<<grid1, 256, 0, stream>>>(F2, dec_w1, nullptr, dec_t, M, 64, C);
    dim3 grid(C / 64, M / 64);
    k_gemm<EPI_BIAS, false><<<grid, 256, 0, stream>>>(dec_t, dec_w2, time_dec, F2, M, C, 64);
  }
  // 7. chunked wkv6: pre -> kv -> scan -> intra(full y)
  k_wkv_pre<<<B * H * NCH, 64, 0, stream>>>(F0, F1, F2, faaaa, F5, F2,
                                            aLb, pdiag, B, T, C, H, L);
  k_wkv_kv<<<B * H * NCH, 256, 0, stream>>>(F2, F3, kvb, B, T, C, H, L);
  k_wkv_scan<<<B * H, 256, 0, stream>>>(kvb, aLb, Scb, NCH);
  k_wkv_intra<<<B * H * NCH, 256, 0, stream>>>(F5, F2, F3, pdiag, Scb, F0,
                                               B, T, C, H, L);
  // 8. groupnorm * gate -> z bf16
  k_gnmul<<<M, 768, 0, stream>>>(F0, F4, ln_w, ln_b, z_bf, C);
  // 9. out = z @ W_o^T (bf16 MFMA)
  {
    dim3 grid(C / 128, M / 128);
    k_gemm_bf<EPI_NONE, false><<<grid, 256, 0, stream>>>(z_bf, wo_bf, (float*)d_out, M, C, C);
  }
}

// Round 7
// 571.914 us; speedup vs baseline: 6.4574x; 1.2236x over previous
//
#include <hip/hip_runtime.h>
#include <math.h>

// ---------------------------------------------------------------------------
// TimeMix (RWKV-6 vision block) — round 7: decay LoRA on bf16 MFMA path.
// B=8, T=1024, C=768, H=12 heads of 64, M=8192.
// ---------------------------------------------------------------------------

#define EPI_NONE 0
#define EPI_TANH 1
#define EPI_RELU 2
#define EPI_BIAS 3

#define LPAD 68   // LDS row stride (floats) for 64-wide chunk tiles

typedef float f32x4 __attribute__((ext_vector_type(4)));
typedef __bf16 bf16x8 __attribute__((ext_vector_type(8)));

__device__ __forceinline__ ushort f2bf(float x) {
  unsigned u = __float_as_uint(x);
  return (ushort)((u + 0x7fffu + ((u >> 16) & 1u)) >> 16);
}

#define GLDS16(gp, lp)                                                   \
  __builtin_amdgcn_global_load_lds(                                      \
      (const __attribute__((address_space(1))) void*)(gp),               \
      (__attribute__((address_space(3))) void*)(lp), 16, 0, 0)

// ---------------------------------------------------------------- qshift ---
__global__ __launch_bounds__(256) void k_qshift(
    const float* __restrict__ x, const float* __restrict__ maa_x,
    float* __restrict__ xx, ushort* __restrict__ xxx_bf,
    int B, int T, int C, int ph, int pw) {
  long idx = (long)blockIdx.x * blockDim.x + threadIdx.x;
  long total = (long)B * T * C;
  if (idx >= total) return;
  int c = (int)(idx % C);
  long bt = idx / C;
  int t = (int)(bt % T);
  int quarter = (c & 63) >> 4;
  int hh = t / pw;
  int ww = t - hh * pw;
  long rowbase = (bt - t) * C;
  float sval = 0.f;
  int st = -1;
  if (quarter == 0)      { if (ww >= 1)      st = t - 1;  }
  else if (quarter == 1) { if (ww < pw - 1)  st = t + 1;  }
  else if (quarter == 2) { if (hh >= 1)      st = t - pw; }
  else                   { if (hh < ph - 1)  st = t + pw; }
  if (st >= 0) sval = x[rowbase + (long)st * C + c];
  float xval = x[idx];
  float d = sval - xval;
  xx[idx] = d;
  xxx_bf[idx] = f2bf(xval + d * maa_x[c]);
}

// ------------------------------------- maa_w1 transpose+convert to bf16 ----
// out[n][k] = maa_w1[k][n] for n<160, 0 for 160<=n<256. out is [256,768] bf16.
__global__ __launch_bounds__(256) void k_w1t(
    const float* __restrict__ w1, ushort* __restrict__ out) {
  int n = blockIdx.y;
  int k = blockIdx.x * 256 + threadIdx.x;
  float v = (n < 160) ? w1[(size_t)k * 160 + n] : 0.f;
  out[(size_t)n * 768 + k] = f2bf(v);
}

// -------------------------- dec_w1 / dec_w2 transpose+convert to bf16 ------
// w1dT[n][k] = dec_w1[k][n], n<64 (zeros 64..127), [128,768].
// w2dT[n][k] = dec_w2[k][n], [768,64].
__global__ __launch_bounds__(256) void k_decT(
    const float* __restrict__ w1, const float* __restrict__ w2,
    ushort* __restrict__ w1dT, ushort* __restrict__ w2dT) {
  int idx = blockIdx.x * 256 + threadIdx.x;
  if (idx < 128 * 768) {
    int n = idx / 768, k = idx - n * 768;
    float v = (n < 64) ? w1[(size_t)k * 64 + n] : 0.f;
    w1dT[idx] = f2bf(v);
  } else {
    int j = idx - 128 * 768;   // 768*64 entries
    int n = j >> 6, k = j & 63;
    w2dT[j] = f2bf(w2[(size_t)k * 768 + n]);
  }
}

// ---------------------------------------------- mix5 fused GEMM+epilogue ---
// All 5 outputs bf16.
__global__ __launch_bounds__(256) void k_mix5f(
    const float* __restrict__ t5, const float* __restrict__ maa_w2,
    const float* __restrict__ x, const float* __restrict__ xx,
    const float* __restrict__ maa_w, const float* __restrict__ maa_k,
    const float* __restrict__ maa_v, const float* __restrict__ maa_r,
    const float* __restrict__ maa_g,
    ushort* __restrict__ xw, ushort* __restrict__ xk, ushort* __restrict__ xvb,
    ushort* __restrict__ xr, ushort* __restrict__ xg, int C) {
  __shared__ float As[64][36];
  __shared__ float Bs[32][64];
  int tid = threadIdx.x;
  int m0 = blockIdx.y * 64, n0 = blockIdx.x * 64;
  int tx = tid & 15, ty = tid >> 4;
  int cb = n0 + tx * 4;
  float4 xv4[4], dd4[4];
#pragma unroll
  for (int i = 0; i < 4; i++) {
    size_t off = (size_t)(m0 + ty * 4 + i) * C + cb;
    xv4[i] = *(const float4*)(x + off);
    dd4[i] = *(const float4*)(xx + off);
  }

#pragma unroll
  for (int f = 0; f < 5; f++) {
    {
      int k4 = (tid & 7) * 4;
      int row = tid >> 3;
      const float* src = t5 + (size_t)(m0 + row) * 160 + f * 32 + k4;
      float4 v0 = *(const float4*)src;
      float4 v1 = *(const float4*)(src + 32 * 160);
      *(float4*)(&As[row][k4]) = v0;
      *(float4*)(&As[row + 32][k4]) = v1;
    }
    {
      int col = (tid & 15) * 4, kk = tid >> 4;
      const float* src = maa_w2 + (size_t)(f * 32 + kk) * C + n0 + col;
      *(float4*)(&Bs[kk][col]) = *(const float4*)src;
      *(float4*)(&Bs[kk + 16][col]) = *(const float4*)(src + (size_t)16 * C);
    }
    __syncthreads();
    float acc[4][4];
#pragma unroll
    for (int i = 0; i < 4; i++)
#pragma unroll
      for (int j = 0; j < 4; j++) acc[i][j] = 0.f;
#pragma unroll
    for (int kk = 0; kk < 32; kk++) {
      float4 b4 = *(const float4*)(&Bs[kk][tx * 4]);
#pragma unroll
      for (int i = 0; i < 4; i++) {
        float a = As[ty * 4 + i][kk];
        acc[i][0] = fmaf(a, b4.x, acc[i][0]);
        acc[i][1] = fmaf(a, b4.y, acc[i][1]);
        acc[i][2] = fmaf(a, b4.z, acc[i][2]);
        acc[i][3] = fmaf(a, b4.w, acc[i][3]);
      }
    }
    __syncthreads();
    const float* maa_f = (f == 0) ? maa_w : (f == 1) ? maa_k
                        : (f == 2) ? maa_v : (f == 3) ? maa_r : maa_g;
    ushort* dst = (f == 0) ? xw : (f == 1) ? xk
                 : (f == 2) ? xvb : (f == 3) ? xr : xg;
    float4 mf = *(const float4*)(maa_f + cb);
#pragma unroll
    for (int i = 0; i < 4; i++) {
      size_t off = (size_t)(m0 + ty * 4 + i) * C + cb;
      ushort4 ob;
      ob.x = f2bf(xv4[i].x + dd4[i].x * (mf.x + acc[i][0]));
      ob.y = f2bf(xv4[i].y + dd4[i].y * (mf.y + acc[i][1]));
      ob.z = f2bf(xv4[i].z + dd4[i].z * (mf.z + acc[i][2]));
      ob.w = f2bf(xv4[i].w + dd4[i].w * (mf.w + acc[i][3]));
      *(ushort4*)(dst + off) = ob;
    }
  }
}

// -------------------------------------------- fp32 -> bf16 cvt (5 arrays) --
__global__ __launch_bounds__(256) void k_cvt5(
    const float* __restrict__ s0, const float* __restrict__ s1,
    const float* __restrict__ s2, const float* __restrict__ s3,
    const float* __restrict__ s4,
    ushort* __restrict__ d0, ushort* __restrict__ d1,
    ushort* __restrict__ d2, ushort* __restrict__ d3,
    ushort* __restrict__ d4, int n) {
  const float* s;
  ushort* d;
  switch (blockIdx.y) {
    case 0: s = s0; d = d0; break;
    case 1: s = s1; d = d1; break;
    case 2: s = s2; d = d2; break;
    case 3: s = s3; d = d3; break;
    default: s = s4; d = d4; break;
  }
  int i = (blockIdx.x * 256 + threadIdx.x) * 4;
  if (i >= n) return;
  float4 v = *(const float4*)(s + i);
  ushort4 o;
  o.x = f2bf(v.x); o.y = f2bf(v.y); o.z = f2bf(v.z); o.w = f2bf(v.w);
  *(ushort4*)(d + i) = o;
}

// ----------------------------------------------------- bf16 MFMA GEMM ------
// C[m,n] = act( sum_k A[m,k] * W[n,k] [+ bias[n]] ), A/W bf16.
// NMASK: guard stores gn<N (W buffer must still have ceil128 readable rows).
// OBF16: write bf16 output instead of fp32.
template <int EPI, bool NMASK, bool OBF16>
__global__ __launch_bounds__(256) void k_gemm_bf(
    const ushort* __restrict__ A, const ushort* __restrict__ W,
    const float* __restrict__ bias, void* __restrict__ Cm,
    int M, int N, int K) {
  __shared__ ushort Al[128 * 32];
  __shared__ ushort Bl[128 * 32];
  int tid = threadIdx.x;
  int m0 = blockIdx.y * 128, n0 = blockIdx.x * 128;
  int lane = tid & 63, wave = tid >> 6;
  int wm = (wave >> 1) * 64, wn = (wave & 1) * 64;
  int lm = lane & 15, lk = (lane >> 4) * 8;
  f32x4 acc[4][4];
#pragma unroll
  for (int i = 0; i < 4; i++)
#pragma unroll
    for (int j = 0; j < 4; j++) acc[i][j] = (f32x4){0.f, 0.f, 0.f, 0.f};

  int arow = tid >> 2, achunk = (tid & 3) * 8;
  const ushort* Ag = A + (size_t)(m0 + arow) * K + achunk;
  const ushort* Wg = W + (size_t)(n0 + arow) * K + achunk;
  ushort* Ald = Al + tid * 8;
  ushort* Bld = Bl + tid * 8;

  for (int k0 = 0; k0 < K; k0 += 32) {
    GLDS16(Ag + k0, Ald);
    GLDS16(Ag + (size_t)64 * K + k0, Ald + 2048);
    GLDS16(Wg + k0, Bld);
    GLDS16(Wg + (size_t)64 * K + k0, Bld + 2048);
    __syncthreads();
    bf16x8 af[4], bf[4];
#pragma unroll
    for (int i = 0; i < 4; i++)
      af[i] = *(const bf16x8*)&Al[(wm + i * 16 + lm) * 32 + lk];
#pragma unroll
    for (int j = 0; j < 4; j++)
      bf[j] = *(const bf16x8*)&Bl[(wn + j * 16 + lm) * 32 + lk];
#pragma unroll
    for (int i = 0; i < 4; i++)
#pragma unroll
      for (int j = 0; j < 4; j++)
        acc[i][j] = __builtin_amdgcn_mfma_f32_16x16x32_bf16(
            af[i], bf[j], acc[i][j], 0, 0, 0);
    __syncthreads();
  }
  int rq = (lane >> 4) * 4;
#pragma unroll
  for (int i = 0; i < 4; i++) {
#pragma unroll
    for (int j = 0; j < 4; j++) {
      int gn = n0 + wn + j * 16 + lm;
      if (NMASK && gn >= N) continue;
      float bv = (EPI == EPI_BIAS) ? bias[gn] : 0.f;
#pragma unroll
      for (int q = 0; q < 4; q++) {
        int gm = m0 + wm + i * 16 + rq + q;
        float val = acc[i][j][q];
        if (EPI == EPI_BIAS) val += bv;
        if (EPI == EPI_RELU) val = fmaxf(val, 0.f);
        if (EPI == EPI_TANH) val = tanhf(val);
        if (OBF16) ((ushort*)Cm)[(size_t)gm * N + gn] = f2bf(val);
        else       ((float*)Cm)[(size_t)gm * N + gn] = val;
      }
    }
  }
}

// ------------------------------------------------- chunked WKV: phase pre --
__global__ __launch_bounds__(64) void k_wkv_pre(
    const float* __restrict__ r, const float* __restrict__ k,
    const float* __restrict__ w, const float* __restrict__ u,
    float* __restrict__ rt, float* __restrict__ kt,
    float* __restrict__ aL, float* __restrict__ pdiag,
    int B, int T, int C, int H, int L) {
  int nch = T / L;
  int blk = blockIdx.x;
  int bh = blk / nch, c = blk - bh * nch;
  int b = bh / H, h = bh - b * H;
  int j = threadIdx.x;
  float uj = u[h * 64 + j];
  float cum = 0.f;
  long base = ((long)b * T + (long)c * L) * C + h * 64 + j;
  for (int tau = 0; tau < L; tau++) {
    long off = base + (long)tau * C;
    float wv = w[off];
    float rv = r[off];
    float kv = k[off];
    float e = expf(wv);
    rt[off] = rv * expf(-cum);
    cum += e;
    kt[off] = kv * expf(cum);
    float pd = rv * uj * kv;
#pragma unroll
    for (int o = 32; o >= 1; o >>= 1) pd += __shfl_xor(pd, o, 64);
    if (j == 0) pdiag[(long)bh * T + c * L + tau] = pd;
  }
  aL[((long)bh * nch + c) * 64 + j] = expf(-cum);
}

// --------------------------------------- chunked WKV: per-chunk KV outer ---
__global__ __launch_bounds__(256) void k_wkv_kv(
    const float* __restrict__ kt, const float* __restrict__ v,
    float* __restrict__ kvb, int B, int T, int C, int H, int L) {
  int nch = T / L;
  int blk = blockIdx.x;
  int bh = blk / nch, c = blk - bh * nch;
  int b = bh / H, h = bh - b * H;
  __shared__ float Ks[64 * LPAD];
  __shared__ float Vs[64 * LPAD];
  int tid = threadIdx.x;
  int lane = tid & 63, jg = tid >> 6;
  long cbase = ((long)b * T + (long)c * L) * C + h * 64;
#pragma unroll
  for (int q = 0; q < 4; q++) {
    int idx = tid + q * 256;
    int row = idx >> 4, col = (idx & 15) * 4;
    long g = cbase + (long)row * C + col;
    *(float4*)(Ks + row * LPAD + col) = *(const float4*)(kt + g);
    *(float4*)(Vs + row * LPAD + col) = *(const float4*)(v + g);
  }
  __syncthreads();
  float acc[16];
#pragma unroll
  for (int q = 0; q < 16; q++) acc[q] = 0.f;
  for (int s = 0; s < 64; s++) {
    float vi = Vs[s * LPAD + lane];
#pragma unroll
    for (int q4 = 0; q4 < 4; q4++) {
      float4 kk = *(const float4*)(Ks + s * LPAD + jg * 16 + q4 * 4);
      acc[q4 * 4 + 0] = fmaf(kk.x, vi, acc[q4 * 4 + 0]);
      acc[q4 * 4 + 1] = fmaf(kk.y, vi, acc[q4 * 4 + 1]);
      acc[q4 * 4 + 2] = fmaf(kk.z, vi, acc[q4 * 4 + 2]);
      acc[q4 * 4 + 3] = fmaf(kk.w, vi, acc[q4 * 4 + 3]);
    }
  }
  float* out = kvb + ((long)bh * nch + c) * 4096;
#pragma unroll
  for (int q = 0; q < 16; q++) out[(jg * 16 + q) * 64 + lane] = acc[q];
}

// ---------------------------------------- chunked WKV: state prefix scan ---
__global__ __launch_bounds__(256) void k_wkv_scan(
    const float* __restrict__ kvb, const float* __restrict__ aL,
    float* __restrict__ Scb, int nch) {
  int bh = blockIdx.x;
  int tid = threadIdx.x;
  float S[16];
#pragma unroll
  for (int q = 0; q < 16; q++) S[q] = 0.f;
  for (int c = 0; c < nch; c++) {
    const float* kv = kvb + ((long)bh * nch + c) * 4096;
    float* sc = Scb + ((long)bh * nch + c) * 4096;
    const float* aLc = aL + ((long)bh * nch + c) * 64;
#pragma unroll
    for (int q = 0; q < 16; q++) {
      int e = q * 256 + tid;
      sc[e] = S[q];
      S[q] = aLc[e >> 6] * (S[q] + kv[e]);
    }
  }
}

// --------------------------- chunked WKV: intra + inter (augmented matmul) -
__global__ __launch_bounds__(256) void k_wkv_intra(
    const float* __restrict__ rt, const float* __restrict__ kt,
    const float* __restrict__ v, const float* __restrict__ pdiag,
    const float* __restrict__ Scb, float* __restrict__ y,
    int B, int T, int C, int H, int L) {
  int nch = T / L;
  int blk = blockIdx.x;
  int bh = blk / nch, c = blk - bh * nch;
  int b = bh / H, h = bh - b * H;
  __shared__ float RPs[64 * LPAD];   // Rt tile -> P^T
  __shared__ float Ks[64 * LPAD];    // Kt tile -> Rt^T
  __shared__ float Vs[64 * LPAD];
  __shared__ float Ss[64 * 64];      // S_prev
  int tid = threadIdx.x;
  long cbase = ((long)b * T + (long)c * L) * C + h * 64;
  const float* scp = Scb + ((long)bh * nch + c) * 4096;
#pragma unroll
  for (int q = 0; q < 4; q++) {
    int idx = tid + q * 256;
    int row = idx >> 4, col = (idx & 15) * 4;
    long g = cbase + (long)row * C + col;
    *(float4*)(RPs + row * LPAD + col) = *(const float4*)(rt + g);
    *(float4*)(Ks + row * LPAD + col) = *(const float4*)(kt + g);
    *(float4*)(Vs + row * LPAD + col) = *(const float4*)(v + g);
  }
#pragma unroll
  for (int q = 0; q < 4; q++) {
    int e4 = (tid + q * 256) * 4;
    *(float4*)(Ss + e4) = *(const float4*)(scp + e4);
  }
  __syncthreads();
  int tau = tid & 63, sg = tid >> 6;
  float4 rreg[16];
#pragma unroll
  for (int q = 0; q < 16; q++)
    rreg[q] = *(const float4*)(RPs + tau * LPAD + q * 4);
  float pd = pdiag[(long)bh * T + c * L + tau];
  __syncthreads();   // Rt reads done; RPs becomes P^T storage
#pragma unroll 2
  for (int ss = 0; ss < 16; ss++) {
    int s = sg * 16 + ss;
    float a0 = 0.f, a1 = 0.f, a2 = 0.f, a3 = 0.f;
#pragma unroll
    for (int q = 0; q < 16; q++) {
      float4 kk = *(const float4*)(Ks + s * LPAD + q * 4);
      a0 = fmaf(rreg[q].x, kk.x, a0);
      a1 = fmaf(rreg[q].y, kk.y, a1);
      a2 = fmaf(rreg[q].z, kk.z, a2);
      a3 = fmaf(rreg[q].w, kk.w, a3);
    }
    float a = (a0 + a1) + (a2 + a3);
    float val = (s < tau) ? a : (s == tau ? pd : 0.f);
    RPs[s * LPAD + tau] = val;
  }
  __syncthreads();   // Kt reads done; Ks becomes Rt^T storage
#pragma unroll
  for (int qq = 0; qq < 16; qq++) {
    const float* rr = (const float*)&rreg[sg * 4 + (qq >> 2)];
    Ks[(sg * 16 + qq) * LPAD + tau] = rr[qq & 3];
  }
  __syncthreads();
  int i = tid & 63, tg = tid >> 6;
  float acc[16];
#pragma unroll
  for (int q = 0; q < 16; q++) acc[q] = 0.f;
  for (int s = 0; s < 64; s++) {       // intra: P @ V
    float vi = Vs[s * LPAD + i];
#pragma unroll
    for (int q4 = 0; q4 < 4; q4++) {
      float4 pp = *(const float4*)(RPs + s * LPAD + tg * 16 + q4 * 4);
      acc[q4 * 4 + 0] = fmaf(pp.x, vi, acc[q4 * 4 + 0]);
      acc[q4 * 4 + 1] = fmaf(pp.y, vi, acc[q4 * 4 + 1]);
      acc[q4 * 4 + 2] = fmaf(pp.z, vi, acc[q4 * 4 + 2]);
      acc[q4 * 4 + 3] = fmaf(pp.w, vi, acc[q4 * 4 + 3]);
    }
  }
  for (int j = 0; j < 64; j++) {       // inter: Rt @ S_prev
    float si = Ss[j * 64 + i];
#pragma unroll
    for (int q4 = 0; q4 < 4; q4++) {
      float4 pp = *(const float4*)(Ks + j * LPAD + tg * 16 + q4 * 4);
      acc[q4 * 4 + 0] = fmaf(pp.x, si, acc[q4 * 4 + 0]);
      acc[q4 * 4 + 1] = fmaf(pp.y, si, acc[q4 * 4 + 1]);
      acc[q4 * 4 + 2] = fmaf(pp.z, si, acc[q4 * 4 + 2]);
      acc[q4 * 4 + 3] = fmaf(pp.w, si, acc[q4 * 4 + 3]);
    }
  }
#pragma unroll
  for (int q = 0; q < 16; q++) {
    long off = cbase + (long)(tg * 16 + q) * C + i;
    y[off] = acc[q];
  }
}

// ----------------------------------------------------- groupnorm * gate ---
__global__ __launch_bounds__(768) void k_gnmul(
    const float* __restrict__ y, const float* __restrict__ g,
    const float* __restrict__ ln_w, const float* __restrict__ ln_b,
    ushort* __restrict__ z, int C) {
  long row = blockIdx.x;
  int c = threadIdx.x;
  long off = row * C + c;
  float val = y[off];
  float s = val;
#pragma unroll
  for (int o = 32; o >= 1; o >>= 1) s += __shfl_xor(s, o, 64);
  float mu = s * (1.f / 64.f);
  float d = val - mu;
  float vs = d * d;
#pragma unroll
  for (int o = 32; o >= 1; o >>= 1) vs += __shfl_xor(vs, o, 64);
  float var = vs * (1.f / 64.f);
  float nrm = d * rsqrtf(var + 1e-5f);
  z[off] = f2bf((nrm * ln_w[c] + ln_b[c]) * g[off]);
}

// ---------------------------------------------------------------- launch ---
extern "C" void kernel_launch(void* const* d_in, const int* in_sizes, int n_in,
                              void* d_out, int out_size, void* d_ws, size_t ws_size,
                              hipStream_t stream) {
  const int B = 8, T = 1024, C = 768, H = 12, ph = 32, pw = 32;
  const int M = B * T;
  const int L = 64, NCH = T / L;

  const float* x        = (const float*)d_in[0];
  const float* W_r      = (const float*)d_in[1];
  const float* W_k      = (const float*)d_in[2];
  const float* W_v      = (const float*)d_in[3];
  const float* W_g      = (const float*)d_in[4];
  const float* W_o      = (const float*)d_in[5];
  const float* maa_x    = (const float*)d_in[6];
  const float* maa_w    = (const float*)d_in[7];
  const float* maa_k    = (const float*)d_in[8];
  const float* maa_v    = (const float*)d_in[9];
  const float* maa_r    = (const float*)d_in[10];
  const float* maa_g    = (const float*)d_in[11];
  const float* maa_w1   = (const float*)d_in[12];
  const float* maa_w2   = (const float*)d_in[13];
  const float* time_dec = (const float*)d_in[14];
  const float* dec_w1   = (const float*)d_in[15];
  const float* dec_w2   = (const float*)d_in[16];
  const float* faaaa    = (const float*)d_in[17];
  const float* ln_w     = (const float*)d_in[18];
  const float* ln_b     = (const float*)d_in[19];

  float* ws = (float*)d_ws;
  const size_t S = (size_t)M * C;
  float* F0 = ws + 0 * S;   // xx -> r -> kvb -> y
  float* F1 = ws + 1 * S;   // xxx_bf -> k -> Scb
  float* F2 = ws + 2 * S;   // xw_bf -> w -> Kt (in place)
  float* F3 = ws + 3 * S;   // v
  float* F4 = ws + 4 * S;   // g
  float* F5 = ws + 5 * S;   // xr_bf | xk_bf -> Rt (fp32)
  float* F6 = ws + 6 * S;   // xv_bf | xg_bf -> z_bf
  float* t5    = ws + 7 * S;            // [M,160] fp32 -> bf16 W_r..W_g
  float* t6    = t5 + (size_t)M * 160;  // bf16 W_o + maa1T + decT
  float* aLb   = t6 + (size_t)M * 64;
  float* pdiag = aLb + (size_t)B * H * NCH * 64;
  float* dec_t = pdiag + (size_t)B * H * T;   // [M,64] t_bf scratch

  ushort* xxx_bf = (ushort*)F1;
  ushort* xw_bf = (ushort*)F2;
  ushort* xr_bf = (ushort*)F5;
  ushort* xk_bf = xr_bf + S;
  ushort* xv_bf = (ushort*)F6;
  ushort* xg_bf = xv_bf + S;
  ushort* z_bf  = (ushort*)F6;
  ushort* t_bf  = (ushort*)dec_t;       // [M,64] bf16
  float* kvb = F0;
  float* Scb = F1;
  const int WSZ = C * C;
  ushort* wr_bf = (ushort*)t5;
  ushort* wk_bf = wr_bf + WSZ;
  ushort* wv_bf = wk_bf + WSZ;
  ushort* wg_bf = wv_bf + WSZ;
  ushort* wo_bf = (ushort*)t6;
  ushort* maa1T = wo_bf + WSZ;          // [256,768]
  ushort* w1dT  = maa1T + 256 * 768;    // [128,768]
  ushort* w2dT  = w1dT + 128 * 768;     // [768,64]

  // 1. qshift (xx fp32, xxx bf16)
  {
    long total = (long)M * C;
    k_qshift<<<(int)((total + 255) / 256), 256, 0, stream>>>(
        x, maa_x, F0, xxx_bf, B, T, C, ph, pw);
  }
  // 2. maa_w1/dec transposes -> bf16; t5 = tanh(xxx @ maa_w1) via MFMA
  {
    dim3 gt(3, 256);
    k_w1t<<<gt, 256, 0, stream>>>(maa_w1, maa1T);
    k_decT<<<(128 * 768 + 768 * 64) / 256, 256, 0, stream>>>(
        dec_w1, dec_w2, w1dT, w2dT);
    dim3 grid(2, M / 128);
    k_gemm_bf<EPI_TANH, true, false><<<grid, 256, 0, stream>>>(
        xxx_bf, maa1T, nullptr, t5, M, 160, C);
  }
  // 3. mix5 (all outputs bf16)
  {
    dim3 grid(C / 64, M / 64);
    k_mix5f<<<grid, 256, 0, stream>>>(t5, maa_w2, x, F0, maa_w, maa_k, maa_v,
                                      maa_r, maa_g, xw_bf, xk_bf, xv_bf, xr_bf,
                                      xg_bf, C);
  }
  // 4. weight conversion (t5 data dead now)
  {
    dim3 grid((WSZ / 4 + 255) / 256, 5);
    k_cvt5<<<grid, 256, 0, stream>>>(W_r, W_k, W_v, W_g, W_o,
                                     wr_bf, wk_bf, wv_bf, wg_bf, wo_bf, WSZ);
  }
  // 5. big projections: bf16 MFMA
  {
    dim3 grid(C / 128, M / 128);
    k_gemm_bf<EPI_NONE, false, false><<<grid, 256, 0, stream>>>(
        xr_bf, wr_bf, nullptr, F0, M, C, C);
    k_gemm_bf<EPI_NONE, false, false><<<grid, 256, 0, stream>>>(
        xk_bf, wk_bf, nullptr, F1, M, C, C);
    k_gemm_bf<EPI_NONE, false, false><<<grid, 256, 0, stream>>>(
        xv_bf, wv_bf, nullptr, F3, M, C, C);
    k_gemm_bf<EPI_RELU, false, false><<<grid, 256, 0, stream>>>(
        xg_bf, wg_bf, nullptr, F4, M, C, C);
  }
  // 6. decay path on MFMA: t_bf = tanh(xw @ dec_w1) bf16; w = t_bf@dec_w2 + td
  {
    dim3 g1(1, M / 128);
    k_gemm_bf<EPI_TANH, true, true><<<g1, 256, 0, stream>>>(
        xw_bf, w1dT, nullptr, t_bf, M, 64, C);
    dim3 g2(C / 128, M / 128);
    k_gemm_bf<EPI_BIAS, false, false><<<g2, 256, 0, stream>>>(
        t_bf, w2dT, time_dec, F2, M, C, 64);
  }
  // 7. chunked wkv6: pre -> kv -> scan -> intra(full y)
  k_wkv_pre<<<B * H * NCH, 64, 0, stream>>>(F0, F1, F2, faaaa, F5, F2,
                                            aLb, pdiag, B, T, C, H, L);
  k_wkv_kv<<<B * H * NCH, 256, 0, stream>>>(F2, F3, kvb, B, T, C, H, L);
  k_wkv_scan<<<B * H, 256, 0, stream>>>(kvb, aLb, Scb, NCH);
  k_wkv_intra<<<B * H * NCH, 256, 0, stream>>>(F5, F2, F3, pdiag, Scb, F0,
                                               B, T, C, H, L);
  // 8. groupnorm * gate -> z bf16
  k_gnmul<<<M, 768, 0, stream>>>(F0, F4, ln_w, ln_b, z_bf, C);
  // 9. out = z @ W_o^T (bf16 MFMA)
  {
    dim3 grid(C / 128, M / 128);
    k_gemm_bf<EPI_NONE, false, false><<<grid, 256, 0, stream>>>(
        z_bf, wo_bf, nullptr, (float*)d_out, M, C, C);
  }
}

// Round 8
// 558.700 us; speedup vs baseline: 6.6101x; 1.0237x over previous
//
#include <hip/hip_runtime.h>
#include <math.h>

// ---------------------------------------------------------------------------
// TimeMix (RWKV-6 vision block) — round 8: intra+GN fusion (3 blk/CU),
// batched projection GEMMs. B=8, T=1024, C=768, H=12 heads of 64, M=8192.
// ---------------------------------------------------------------------------

#define EPI_NONE 0
#define EPI_TANH 1
#define EPI_RELU 2
#define EPI_BIAS 3

#define LPAD 68   // LDS row stride (floats) for 64-wide chunk tiles

typedef float f32x4 __attribute__((ext_vector_type(4)));
typedef __bf16 bf16x8 __attribute__((ext_vector_type(8)));

__device__ __forceinline__ ushort f2bf(float x) {
  unsigned u = __float_as_uint(x);
  return (ushort)((u + 0x7fffu + ((u >> 16) & 1u)) >> 16);
}

#define GLDS16(gp, lp)                                                   \
  __builtin_amdgcn_global_load_lds(                                      \
      (const __attribute__((address_space(1))) void*)(gp),               \
      (__attribute__((address_space(3))) void*)(lp), 16, 0, 0)

// ---------------------------------------------------------------- qshift ---
__global__ __launch_bounds__(256) void k_qshift(
    const float* __restrict__ x, const float* __restrict__ maa_x,
    float* __restrict__ xx, ushort* __restrict__ xxx_bf,
    int B, int T, int C, int ph, int pw) {
  long idx = (long)blockIdx.x * blockDim.x + threadIdx.x;
  long total = (long)B * T * C;
  if (idx >= total) return;
  int c = (int)(idx % C);
  long bt = idx / C;
  int t = (int)(bt % T);
  int quarter = (c & 63) >> 4;
  int hh = t / pw;
  int ww = t - hh * pw;
  long rowbase = (bt - t) * C;
  float sval = 0.f;
  int st = -1;
  if (quarter == 0)      { if (ww >= 1)      st = t - 1;  }
  else if (quarter == 1) { if (ww < pw - 1)  st = t + 1;  }
  else if (quarter == 2) { if (hh >= 1)      st = t - pw; }
  else                   { if (hh < ph - 1)  st = t + pw; }
  if (st >= 0) sval = x[rowbase + (long)st * C + c];
  float xval = x[idx];
  float d = sval - xval;
  xx[idx] = d;
  xxx_bf[idx] = f2bf(xval + d * maa_x[c]);
}

// ------------------------------------- maa_w1 transpose+convert to bf16 ----
__global__ __launch_bounds__(256) void k_w1t(
    const float* __restrict__ w1, ushort* __restrict__ out) {
  int n = blockIdx.y;
  int k = blockIdx.x * 256 + threadIdx.x;
  float v = (n < 160) ? w1[(size_t)k * 160 + n] : 0.f;
  out[(size_t)n * 768 + k] = f2bf(v);
}

// -------------------------- dec_w1 / dec_w2 transpose+convert to bf16 ------
__global__ __launch_bounds__(256) void k_decT(
    const float* __restrict__ w1, const float* __restrict__ w2,
    ushort* __restrict__ w1dT, ushort* __restrict__ w2dT) {
  int idx = blockIdx.x * 256 + threadIdx.x;
  if (idx < 128 * 768) {
    int n = idx / 768, k = idx - n * 768;
    float v = (n < 64) ? w1[(size_t)k * 64 + n] : 0.f;
    w1dT[idx] = f2bf(v);
  } else {
    int j = idx - 128 * 768;
    int n = j >> 6, k = j & 63;
    w2dT[j] = f2bf(w2[(size_t)k * 768 + n]);
  }
}

// ---------------------------------------------- mix5 fused GEMM+epilogue ---
__global__ __launch_bounds__(256) void k_mix5f(
    const float* __restrict__ t5, const float* __restrict__ maa_w2,
    const float* __restrict__ x, const float* __restrict__ xx,
    const float* __restrict__ maa_w, const float* __restrict__ maa_k,
    const float* __restrict__ maa_v, const float* __restrict__ maa_r,
    const float* __restrict__ maa_g,
    ushort* __restrict__ xw, ushort* __restrict__ xk, ushort* __restrict__ xvb,
    ushort* __restrict__ xr, ushort* __restrict__ xg, int C) {
  __shared__ float As[64][36];
  __shared__ float Bs[32][64];
  int tid = threadIdx.x;
  int m0 = blockIdx.y * 64, n0 = blockIdx.x * 64;
  int tx = tid & 15, ty = tid >> 4;
  int cb = n0 + tx * 4;
  float4 xv4[4], dd4[4];
#pragma unroll
  for (int i = 0; i < 4; i++) {
    size_t off = (size_t)(m0 + ty * 4 + i) * C + cb;
    xv4[i] = *(const float4*)(x + off);
    dd4[i] = *(const float4*)(xx + off);
  }

#pragma unroll
  for (int f = 0; f < 5; f++) {
    {
      int k4 = (tid & 7) * 4;
      int row = tid >> 3;
      const float* src = t5 + (size_t)(m0 + row) * 160 + f * 32 + k4;
      float4 v0 = *(const float4*)src;
      float4 v1 = *(const float4*)(src + 32 * 160);
      *(float4*)(&As[row][k4]) = v0;
      *(float4*)(&As[row + 32][k4]) = v1;
    }
    {
      int col = (tid & 15) * 4, kk = tid >> 4;
      const float* src = maa_w2 + (size_t)(f * 32 + kk) * C + n0 + col;
      *(float4*)(&Bs[kk][col]) = *(const float4*)src;
      *(float4*)(&Bs[kk + 16][col]) = *(const float4*)(src + (size_t)16 * C);
    }
    __syncthreads();
    float acc[4][4];
#pragma unroll
    for (int i = 0; i < 4; i++)
#pragma unroll
      for (int j = 0; j < 4; j++) acc[i][j] = 0.f;
#pragma unroll
    for (int kk = 0; kk < 32; kk++) {
      float4 b4 = *(const float4*)(&Bs[kk][tx * 4]);
#pragma unroll
      for (int i = 0; i < 4; i++) {
        float a = As[ty * 4 + i][kk];
        acc[i][0] = fmaf(a, b4.x, acc[i][0]);
        acc[i][1] = fmaf(a, b4.y, acc[i][1]);
        acc[i][2] = fmaf(a, b4.z, acc[i][2]);
        acc[i][3] = fmaf(a, b4.w, acc[i][3]);
      }
    }
    __syncthreads();
    const float* maa_f = (f == 0) ? maa_w : (f == 1) ? maa_k
                        : (f == 2) ? maa_v : (f == 3) ? maa_r : maa_g;
    ushort* dst = (f == 0) ? xw : (f == 1) ? xk
                 : (f == 2) ? xvb : (f == 3) ? xr : xg;
    float4 mf = *(const float4*)(maa_f + cb);
#pragma unroll
    for (int i = 0; i < 4; i++) {
      size_t off = (size_t)(m0 + ty * 4 + i) * C + cb;
      ushort4 ob;
      ob.x = f2bf(xv4[i].x + dd4[i].x * (mf.x + acc[i][0]));
      ob.y = f2bf(xv4[i].y + dd4[i].y * (mf.y + acc[i][1]));
      ob.z = f2bf(xv4[i].z + dd4[i].z * (mf.z + acc[i][2]));
      ob.w = f2bf(xv4[i].w + dd4[i].w * (mf.w + acc[i][3]));
      *(ushort4*)(dst + off) = ob;
    }
  }
}

// -------------------------------------------- fp32 -> bf16 cvt (5 arrays) --
__global__ __launch_bounds__(256) void k_cvt5(
    const float* __restrict__ s0, const float* __restrict__ s1,
    const float* __restrict__ s2, const float* __restrict__ s3,
    const float* __restrict__ s4,
    ushort* __restrict__ d0, ushort* __restrict__ d1,
    ushort* __restrict__ d2, ushort* __restrict__ d3,
    ushort* __restrict__ d4, int n) {
  const float* s;
  ushort* d;
  switch (blockIdx.y) {
    case 0: s = s0; d = d0; break;
    case 1: s = s1; d = d1; break;
    case 2: s = s2; d = d2; break;
    case 3: s = s3; d = d3; break;
    default: s = s4; d = d4; break;
  }
  int i = (blockIdx.x * 256 + threadIdx.x) * 4;
  if (i >= n) return;
  float4 v = *(const float4*)(s + i);
  ushort4 o;
  o.x = f2bf(v.x); o.y = f2bf(v.y); o.z = f2bf(v.z); o.w = f2bf(v.w);
  *(ushort4*)(d + i) = o;
}

// ----------------------------------------------------- bf16 MFMA GEMM ------
template <int EPI, bool NMASK, bool OBF16>
__global__ __launch_bounds__(256) void k_gemm_bf(
    const ushort* __restrict__ A, const ushort* __restrict__ W,
    const float* __restrict__ bias, void* __restrict__ Cm,
    int M, int N, int K) {
  __shared__ ushort Al[128 * 32];
  __shared__ ushort Bl[128 * 32];
  int tid = threadIdx.x;
  int m0 = blockIdx.y * 128, n0 = blockIdx.x * 128;
  int lane = tid & 63, wave = tid >> 6;
  int wm = (wave >> 1) * 64, wn = (wave & 1) * 64;
  int lm = lane & 15, lk = (lane >> 4) * 8;
  f32x4 acc[4][4];
#pragma unroll
  for (int i = 0; i < 4; i++)
#pragma unroll
    for (int j = 0; j < 4; j++) acc[i][j] = (f32x4){0.f, 0.f, 0.f, 0.f};

  int arow = tid >> 2, achunk = (tid & 3) * 8;
  const ushort* Ag = A + (size_t)(m0 + arow) * K + achunk;
  const ushort* Wg = W + (size_t)(n0 + arow) * K + achunk;
  ushort* Ald = Al + tid * 8;
  ushort* Bld = Bl + tid * 8;

  for (int k0 = 0; k0 < K; k0 += 32) {
    GLDS16(Ag + k0, Ald);
    GLDS16(Ag + (size_t)64 * K + k0, Ald + 2048);
    GLDS16(Wg + k0, Bld);
    GLDS16(Wg + (size_t)64 * K + k0, Bld + 2048);
    __syncthreads();
    bf16x8 af[4], bf[4];
#pragma unroll
    for (int i = 0; i < 4; i++)
      af[i] = *(const bf16x8*)&Al[(wm + i * 16 + lm) * 32 + lk];
#pragma unroll
    for (int j = 0; j < 4; j++)
      bf[j] = *(const bf16x8*)&Bl[(wn + j * 16 + lm) * 32 + lk];
#pragma unroll
    for (int i = 0; i < 4; i++)
#pragma unroll
      for (int j = 0; j < 4; j++)
        acc[i][j] = __builtin_amdgcn_mfma_f32_16x16x32_bf16(
            af[i], bf[j], acc[i][j], 0, 0, 0);
    __syncthreads();
  }
  int rq = (lane >> 4) * 4;
#pragma unroll
  for (int i = 0; i < 4; i++) {
#pragma unroll
    for (int j = 0; j < 4; j++) {
      int gn = n0 + wn + j * 16 + lm;
      if (NMASK && gn >= N) continue;
      float bv = (EPI == EPI_BIAS) ? bias[gn] : 0.f;
#pragma unroll
      for (int q = 0; q < 4; q++) {
        int gm = m0 + wm + i * 16 + rq + q;
        float val = acc[i][j][q];
        if (EPI == EPI_BIAS) val += bv;
        if (EPI == EPI_RELU) val = fmaxf(val, 0.f);
        if (EPI == EPI_TANH) val = tanhf(val);
        if (OBF16) ((ushort*)Cm)[(size_t)gm * N + gn] = f2bf(val);
        else       ((float*)Cm)[(size_t)gm * N + gn] = val;
      }
    }
  }
}

// --------------------------------- batched 4-projection bf16 MFMA GEMM -----
// blockIdx.z selects (A,W,C) tuple; z==3 applies ReLU. All M x C, K = C.
__global__ __launch_bounds__(256) void k_proj4(
    const ushort* __restrict__ A0, const ushort* __restrict__ A1,
    const ushort* __restrict__ A2, const ushort* __restrict__ A3,
    const ushort* __restrict__ W0, const ushort* __restrict__ W1,
    const ushort* __restrict__ W2, const ushort* __restrict__ W3,
    float* __restrict__ C0, float* __restrict__ C1,
    float* __restrict__ C2, float* __restrict__ C3,
    int M, int N, int K) {
  int z = blockIdx.z;
  const ushort* A = (z == 0) ? A0 : (z == 1) ? A1 : (z == 2) ? A2 : A3;
  const ushort* W = (z == 0) ? W0 : (z == 1) ? W1 : (z == 2) ? W2 : W3;
  float* Cm       = (z == 0) ? C0 : (z == 1) ? C1 : (z == 2) ? C2 : C3;
  __shared__ ushort Al[128 * 32];
  __shared__ ushort Bl[128 * 32];
  int tid = threadIdx.x;
  int m0 = blockIdx.y * 128, n0 = blockIdx.x * 128;
  int lane = tid & 63, wave = tid >> 6;
  int wm = (wave >> 1) * 64, wn = (wave & 1) * 64;
  int lm = lane & 15, lk = (lane >> 4) * 8;
  f32x4 acc[4][4];
#pragma unroll
  for (int i = 0; i < 4; i++)
#pragma unroll
    for (int j = 0; j < 4; j++) acc[i][j] = (f32x4){0.f, 0.f, 0.f, 0.f};

  int arow = tid >> 2, achunk = (tid & 3) * 8;
  const ushort* Ag = A + (size_t)(m0 + arow) * K + achunk;
  const ushort* Wg = W + (size_t)(n0 + arow) * K + achunk;
  ushort* Ald = Al + tid * 8;
  ushort* Bld = Bl + tid * 8;

  for (int k0 = 0; k0 < K; k0 += 32) {
    GLDS16(Ag + k0, Ald);
    GLDS16(Ag + (size_t)64 * K + k0, Ald + 2048);
    GLDS16(Wg + k0, Bld);
    GLDS16(Wg + (size_t)64 * K + k0, Bld + 2048);
    __syncthreads();
    bf16x8 af[4], bf[4];
#pragma unroll
    for (int i = 0; i < 4; i++)
      af[i] = *(const bf16x8*)&Al[(wm + i * 16 + lm) * 32 + lk];
#pragma unroll
    for (int j = 0; j < 4; j++)
      bf[j] = *(const bf16x8*)&Bl[(wn + j * 16 + lm) * 32 + lk];
#pragma unroll
    for (int i = 0; i < 4; i++)
#pragma unroll
      for (int j = 0; j < 4; j++)
        acc[i][j] = __builtin_amdgcn_mfma_f32_16x16x32_bf16(
            af[i], bf[j], acc[i][j], 0, 0, 0);
    __syncthreads();
  }
  bool relu = (z == 3);
  int rq = (lane >> 4) * 4;
#pragma unroll
  for (int i = 0; i < 4; i++) {
#pragma unroll
    for (int j = 0; j < 4; j++) {
      int gn = n0 + wn + j * 16 + lm;
#pragma unroll
      for (int q = 0; q < 4; q++) {
        int gm = m0 + wm + i * 16 + rq + q;
        float val = acc[i][j][q];
        if (relu) val = fmaxf(val, 0.f);
        Cm[(size_t)gm * N + gn] = val;
      }
    }
  }
}

// ------------------------------------------------- chunked WKV: phase pre --
__global__ __launch_bounds__(64) void k_wkv_pre(
    const float* __restrict__ r, const float* __restrict__ k,
    const float* __restrict__ w, const float* __restrict__ u,
    float* __restrict__ rt, float* __restrict__ kt,
    float* __restrict__ aL, float* __restrict__ pdiag,
    int B, int T, int C, int H, int L) {
  int nch = T / L;
  int blk = blockIdx.x;
  int bh = blk / nch, c = blk - bh * nch;
  int b = bh / H, h = bh - b * H;
  int j = threadIdx.x;
  float uj = u[h * 64 + j];
  float cum = 0.f;
  long base = ((long)b * T + (long)c * L) * C + h * 64 + j;
  for (int tau = 0; tau < L; tau++) {
    long off = base + (long)tau * C;
    float wv = w[off];
    float rv = r[off];
    float kv = k[off];
    float e = expf(wv);
    rt[off] = rv * expf(-cum);
    cum += e;
    kt[off] = kv * expf(cum);
    float pd = rv * uj * kv;
#pragma unroll
    for (int o = 32; o >= 1; o >>= 1) pd += __shfl_xor(pd, o, 64);
    if (j == 0) pdiag[(long)bh * T + c * L + tau] = pd;
  }
  aL[((long)bh * nch + c) * 64 + j] = expf(-cum);
}

// --------------------------------------- chunked WKV: per-chunk KV outer ---
__global__ __launch_bounds__(256) void k_wkv_kv(
    const float* __restrict__ kt, const float* __restrict__ v,
    float* __restrict__ kvb, int B, int T, int C, int H, int L) {
  int nch = T / L;
  int blk = blockIdx.x;
  int bh = blk / nch, c = blk - bh * nch;
  int b = bh / H, h = bh - b * H;
  __shared__ float Ks[64 * LPAD];
  __shared__ float Vs[64 * LPAD];
  int tid = threadIdx.x;
  int lane = tid & 63, jg = tid >> 6;
  long cbase = ((long)b * T + (long)c * L) * C + h * 64;
#pragma unroll
  for (int q = 0; q < 4; q++) {
    int idx = tid + q * 256;
    int row = idx >> 4, col = (idx & 15) * 4;
    long g = cbase + (long)row * C + col;
    *(float4*)(Ks + row * LPAD + col) = *(const float4*)(kt + g);
    *(float4*)(Vs + row * LPAD + col) = *(const float4*)(v + g);
  }
  __syncthreads();
  float acc[16];
#pragma unroll
  for (int q = 0; q < 16; q++) acc[q] = 0.f;
  for (int s = 0; s < 64; s++) {
    float vi = Vs[s * LPAD + lane];
#pragma unroll
    for (int q4 = 0; q4 < 4; q4++) {
      float4 kk = *(const float4*)(Ks + s * LPAD + jg * 16 + q4 * 4);
      acc[q4 * 4 + 0] = fmaf(kk.x, vi, acc[q4 * 4 + 0]);
      acc[q4 * 4 + 1] = fmaf(kk.y, vi, acc[q4 * 4 + 1]);
      acc[q4 * 4 + 2] = fmaf(kk.z, vi, acc[q4 * 4 + 2]);
      acc[q4 * 4 + 3] = fmaf(kk.w, vi, acc[q4 * 4 + 3]);
    }
  }
  float* out = kvb + ((long)bh * nch + c) * 4096;
#pragma unroll
  for (int q = 0; q < 16; q++) out[(jg * 16 + q) * 64 + lane] = acc[q];
}

// ---------------------------------------- chunked WKV: state prefix scan ---
__global__ __launch_bounds__(256) void k_wkv_scan(
    const float* __restrict__ kvb, const float* __restrict__ aL,
    float* __restrict__ Scb, int nch) {
  int bh = blockIdx.x;
  int tid = threadIdx.x;
  float S[16];
#pragma unroll
  for (int q = 0; q < 16; q++) S[q] = 0.f;
  for (int c = 0; c < nch; c++) {
    const float* kv = kvb + ((long)bh * nch + c) * 4096;
    float* sc = Scb + ((long)bh * nch + c) * 4096;
    const float* aLc = aL + ((long)bh * nch + c) * 64;
#pragma unroll
    for (int q = 0; q < 16; q++) {
      int e = q * 256 + tid;
      sc[e] = S[q];
      S[q] = aLc[e >> 6] * (S[q] + kv[e]);
    }
  }
}

// ------------- chunked WKV: intra + inter + groupnorm*gate (fused) ---------
// y = mask(Rt Kt^T + diag) @ V + Rt @ S_prev, then per-row GN over the 64
// head channels (exactly this block's columns) and gate -> z bf16.
__global__ __launch_bounds__(256, 3) void k_wkv_intra(
    const float* __restrict__ rt, const float* __restrict__ kt,
    const float* __restrict__ v, const float* __restrict__ pdiag,
    const float* __restrict__ Scb, const float* __restrict__ g,
    const float* __restrict__ ln_w, const float* __restrict__ ln_b,
    ushort* __restrict__ z, int B, int T, int C, int H, int L) {
  int nch = T / L;
  int blk = blockIdx.x;
  int bh = blk / nch, c = blk - bh * nch;
  int b = bh / H, h = bh - b * H;
  __shared__ float RPs[64 * LPAD];   // Rt tile -> P^T
  __shared__ float Ks[64 * LPAD];    // Kt tile -> Rt^T
  __shared__ float Vs[64 * LPAD];
  int tid = threadIdx.x;
  long cbase = ((long)b * T + (long)c * L) * C + h * 64;
  const float* scp = Scb + ((long)bh * nch + c) * 4096;
#pragma unroll
  for (int q = 0; q < 4; q++) {
    int idx = tid + q * 256;
    int row = idx >> 4, col = (idx & 15) * 4;
    long g4 = cbase + (long)row * C + col;
    *(float4*)(RPs + row * LPAD + col) = *(const float4*)(rt + g4);
    *(float4*)(Ks + row * LPAD + col) = *(const float4*)(kt + g4);
    *(float4*)(Vs + row * LPAD + col) = *(const float4*)(v + g4);
  }
  __syncthreads();
  int tau = tid & 63, sg = tid >> 6;
  float4 rreg[16];
#pragma unroll
  for (int q = 0; q < 16; q++)
    rreg[q] = *(const float4*)(RPs + tau * LPAD + q * 4);
  float pd = pdiag[(long)bh * T + c * L + tau];
  __syncthreads();   // Rt reads done; RPs becomes P^T storage
#pragma unroll 2
  for (int ss = 0; ss < 16; ss++) {
    int s = sg * 16 + ss;
    float a0 = 0.f, a1 = 0.f, a2 = 0.f, a3 = 0.f;
#pragma unroll
    for (int q = 0; q < 16; q++) {
      float4 kk = *(const float4*)(Ks + s * LPAD + q * 4);
      a0 = fmaf(rreg[q].x, kk.x, a0);
      a1 = fmaf(rreg[q].y, kk.y, a1);
      a2 = fmaf(rreg[q].z, kk.z, a2);
      a3 = fmaf(rreg[q].w, kk.w, a3);
    }
    float a = (a0 + a1) + (a2 + a3);
    float val = (s < tau) ? a : (s == tau ? pd : 0.f);
    RPs[s * LPAD + tau] = val;
  }
  __syncthreads();   // Kt reads done; Ks becomes Rt^T storage
#pragma unroll
  for (int qq = 0; qq < 16; qq++) {
    const float* rr = (const float*)&rreg[sg * 4 + (qq >> 2)];
    Ks[(sg * 16 + qq) * LPAD + tau] = rr[qq & 3];
  }
  // prefetch S column into registers (rreg is dead now); coalesced per j.
  int i = tid & 63, tg = tid >> 6;
  float sreg[64];
#pragma unroll
  for (int j = 0; j < 64; j++) sreg[j] = scp[j * 64 + i];
  __syncthreads();
  float acc[16];
#pragma unroll
  for (int q = 0; q < 16; q++) acc[q] = 0.f;
  for (int s = 0; s < 64; s++) {       // intra: P @ V
    float vi = Vs[s * LPAD + i];
#pragma unroll
    for (int q4 = 0; q4 < 4; q4++) {
      float4 pp = *(const float4*)(RPs + s * LPAD + tg * 16 + q4 * 4);
      acc[q4 * 4 + 0] = fmaf(pp.x, vi, acc[q4 * 4 + 0]);
      acc[q4 * 4 + 1] = fmaf(pp.y, vi, acc[q4 * 4 + 1]);
      acc[q4 * 4 + 2] = fmaf(pp.z, vi, acc[q4 * 4 + 2]);
      acc[q4 * 4 + 3] = fmaf(pp.w, vi, acc[q4 * 4 + 3]);
    }
  }
#pragma unroll 8
  for (int j = 0; j < 64; j++) {       // inter: Rt @ S_prev
    float si = sreg[j];
#pragma unroll
    for (int q4 = 0; q4 < 4; q4++) {
      float4 pp = *(const float4*)(Ks + j * LPAD + tg * 16 + q4 * 4);
      acc[q4 * 4 + 0] = fmaf(pp.x, si, acc[q4 * 4 + 0]);
      acc[q4 * 4 + 1] = fmaf(pp.y, si, acc[q4 * 4 + 1]);
      acc[q4 * 4 + 2] = fmaf(pp.z, si, acc[q4 * 4 + 2]);
      acc[q4 * 4 + 3] = fmaf(pp.w, si, acc[q4 * 4 + 3]);
    }
  }
  // fused groupnorm (per row over this head's 64 channels) * gate -> z bf16
  int ch = h * 64 + i;
  float lw = ln_w[ch], lb = ln_b[ch];
#pragma unroll
  for (int q = 0; q < 16; q++) {
    float val = acc[q];
    float s = val;
#pragma unroll
    for (int o = 32; o >= 1; o >>= 1) s += __shfl_xor(s, o, 64);
    float mu = s * (1.f / 64.f);
    float d = val - mu;
    float vs = d * d;
#pragma unroll
    for (int o = 32; o >= 1; o >>= 1) vs += __shfl_xor(vs, o, 64);
    float var = vs * (1.f / 64.f);
    float nrm = d * rsqrtf(var + 1e-5f);
    long off = cbase + (long)(tg * 16 + q) * C + i;
    z[off] = f2bf((nrm * lw + lb) * g[off]);
  }
}

// ---------------------------------------------------------------- launch ---
extern "C" void kernel_launch(void* const* d_in, const int* in_sizes, int n_in,
                              void* d_out, int out_size, void* d_ws, size_t ws_size,
                              hipStream_t stream) {
  const int B = 8, T = 1024, C = 768, H = 12, ph = 32, pw = 32;
  const int M = B * T;
  const int L = 64, NCH = T / L;

  const float* x        = (const float*)d_in[0];
  const float* W_r      = (const float*)d_in[1];
  const float* W_k      = (const float*)d_in[2];
  const float* W_v      = (const float*)d_in[3];
  const float* W_g      = (const float*)d_in[4];
  const float* W_o      = (const float*)d_in[5];
  const float* maa_x    = (const float*)d_in[6];
  const float* maa_w    = (const float*)d_in[7];
  const float* maa_k    = (const float*)d_in[8];
  const float* maa_v    = (const float*)d_in[9];
  const float* maa_r    = (const float*)d_in[10];
  const float* maa_g    = (const float*)d_in[11];
  const float* maa_w1   = (const float*)d_in[12];
  const float* maa_w2   = (const float*)d_in[13];
  const float* time_dec = (const float*)d_in[14];
  const float* dec_w1   = (const float*)d_in[15];
  const float* dec_w2   = (const float*)d_in[16];
  const float* faaaa    = (const float*)d_in[17];
  const float* ln_w     = (const float*)d_in[18];
  const float* ln_b     = (const float*)d_in[19];

  float* ws = (float*)d_ws;
  const size_t S = (size_t)M * C;
  float* F0 = ws + 0 * S;   // xx -> r -> kvb
  float* F1 = ws + 1 * S;   // xxx_bf -> k -> Scb
  float* F2 = ws + 2 * S;   // xw_bf -> w -> Kt (in place)
  float* F3 = ws + 3 * S;   // v
  float* F4 = ws + 4 * S;   // g
  float* F5 = ws + 5 * S;   // xr_bf | xk_bf -> Rt (fp32)
  float* F6 = ws + 6 * S;   // xv_bf | xg_bf -> z_bf
  float* t5    = ws + 7 * S;            // [M,160] fp32 -> bf16 W_r..W_g
  float* t6    = t5 + (size_t)M * 160;  // bf16 W_o + maa1T + decT
  float* aLb   = t6 + (size_t)M * 64;
  float* pdiag = aLb + (size_t)B * H * NCH * 64;
  float* dec_t = pdiag + (size_t)B * H * T;   // [M,64] t_bf scratch

  ushort* xxx_bf = (ushort*)F1;
  ushort* xw_bf = (ushort*)F2;
  ushort* xr_bf = (ushort*)F5;
  ushort* xk_bf = xr_bf + S;
  ushort* xv_bf = (ushort*)F6;
  ushort* xg_bf = xv_bf + S;
  ushort* z_bf  = (ushort*)F6;
  ushort* t_bf  = (ushort*)dec_t;       // [M,64] bf16
  float* kvb = F0;
  float* Scb = F1;
  const int WSZ = C * C;
  ushort* wr_bf = (ushort*)t5;
  ushort* wk_bf = wr_bf + WSZ;
  ushort* wv_bf = wk_bf + WSZ;
  ushort* wg_bf = wv_bf + WSZ;
  ushort* wo_bf = (ushort*)t6;
  ushort* maa1T = wo_bf + WSZ;          // [256,768]
  ushort* w1dT  = maa1T + 256 * 768;    // [128,768]
  ushort* w2dT  = w1dT + 128 * 768;     // [768,64]

  // 1. qshift (xx fp32, xxx bf16)
  {
    long total = (long)M * C;
    k_qshift<<<(int)((total + 255) / 256), 256, 0, stream>>>(
        x, maa_x, F0, xxx_bf, B, T, C, ph, pw);
  }
  // 2. maa_w1/dec transposes -> bf16; t5 = tanh(xxx @ maa_w1) via MFMA
  {
    dim3 gt(3, 256);
    k_w1t<<<gt, 256, 0, stream>>>(maa_w1, maa1T);
    k_decT<<<(128 * 768 + 768 * 64) / 256, 256, 0, stream>>>(
        dec_w1, dec_w2, w1dT, w2dT);
    dim3 grid(2, M / 128);
    k_gemm_bf<EPI_TANH, true, false><<<grid, 256, 0, stream>>>(
        xxx_bf, maa1T, nullptr, t5, M, 160, C);
  }
  // 3. mix5 (all outputs bf16)
  {
    dim3 grid(C / 64, M / 64);
    k_mix5f<<<grid, 256, 0, stream>>>(t5, maa_w2, x, F0, maa_w, maa_k, maa_v,
                                      maa_r, maa_g, xw_bf, xk_bf, xv_bf, xr_bf,
                                      xg_bf, C);
  }
  // 4. weight conversion (t5 data dead now)
  {
    dim3 grid((WSZ / 4 + 255) / 256, 5);
    k_cvt5<<<grid, 256, 0, stream>>>(W_r, W_k, W_v, W_g, W_o,
                                     wr_bf, wk_bf, wv_bf, wg_bf, wo_bf, WSZ);
  }
  // 5. big projections: ONE batched bf16 MFMA dispatch (grid.z = 4)
  {
    dim3 grid(C / 128, M / 128, 4);
    k_proj4<<<grid, 256, 0, stream>>>(xr_bf, xk_bf, xv_bf, xg_bf,
                                      wr_bf, wk_bf, wv_bf, wg_bf,
                                      F0, F1, F3, F4, M, C, C);
  }
  // 6. decay path on MFMA
  {
    dim3 g1(1, M / 128);
    k_gemm_bf<EPI_TANH, true, true><<<g1, 256, 0, stream>>>(
        xw_bf, w1dT, nullptr, t_bf, M, 64, C);
    dim3 g2(C / 128, M / 128);
    k_gemm_bf<EPI_BIAS, false, false><<<g2, 256, 0, stream>>>(
        t_bf, w2dT, time_dec, F2, M, C, 64);
  }
  // 7. chunked wkv6: pre -> kv -> scan -> intra(+GN+gate -> z bf16)
  k_wkv_pre<<<B * H * NCH, 64, 0, stream>>>(F0, F1, F2, faaaa, F5, F2,
                                            aLb, pdiag, B, T, C, H, L);
  k_wkv_kv<<<B * H * NCH, 256, 0, stream>>>(F2, F3, kvb, B, T, C, H, L);
  k_wkv_scan<<<B * H, 256, 0, stream>>>(kvb, aLb, Scb, NCH);
  k_wkv_intra<<<B * H * NCH, 256, 0, stream>>>(F5, F2, F3, pdiag, Scb, F4,
                                               ln_w, ln_b, z_bf, B, T, C, H, L);
  // 8. out = z @ W_o^T (bf16 MFMA)
  {
    dim3 grid(C / 128, M / 128);
    k_gemm_bf<EPI_NONE, false, false><<<grid, 256, 0, stream>>>(
        z_bf, wo_bf, nullptr, (float*)d_out, M, C, C);
  }
}

// Round 9
// 537.770 us; speedup vs baseline: 6.8674x; 1.0389x over previous
//
#include <hip/hip_runtime.h>
#include <math.h>

// ---------------------------------------------------------------------------
// TimeMix (RWKV-6 vision block) — round 9: fix intra scratch spill (S read
// in-loop from global, interleaved contraction). B=8, T=1024, C=768, H=12.
// ---------------------------------------------------------------------------

#define EPI_NONE 0
#define EPI_TANH 1
#define EPI_RELU 2
#define EPI_BIAS 3

#define LPAD 68   // LDS row stride (floats) for 64-wide chunk tiles

typedef float f32x4 __attribute__((ext_vector_type(4)));
typedef __bf16 bf16x8 __attribute__((ext_vector_type(8)));

__device__ __forceinline__ ushort f2bf(float x) {
  unsigned u = __float_as_uint(x);
  return (ushort)((u + 0x7fffu + ((u >> 16) & 1u)) >> 16);
}

#define GLDS16(gp, lp)                                                   \
  __builtin_amdgcn_global_load_lds(                                      \
      (const __attribute__((address_space(1))) void*)(gp),               \
      (__attribute__((address_space(3))) void*)(lp), 16, 0, 0)

// ---------------------------------------------------------------- qshift ---
__global__ __launch_bounds__(256) void k_qshift(
    const float* __restrict__ x, const float* __restrict__ maa_x,
    float* __restrict__ xx, ushort* __restrict__ xxx_bf,
    int B, int T, int C, int ph, int pw) {
  long idx = (long)blockIdx.x * blockDim.x + threadIdx.x;
  long total = (long)B * T * C;
  if (idx >= total) return;
  int c = (int)(idx % C);
  long bt = idx / C;
  int t = (int)(bt % T);
  int quarter = (c & 63) >> 4;
  int hh = t / pw;
  int ww = t - hh * pw;
  long rowbase = (bt - t) * C;
  float sval = 0.f;
  int st = -1;
  if (quarter == 0)      { if (ww >= 1)      st = t - 1;  }
  else if (quarter == 1) { if (ww < pw - 1)  st = t + 1;  }
  else if (quarter == 2) { if (hh >= 1)      st = t - pw; }
  else                   { if (hh < ph - 1)  st = t + pw; }
  if (st >= 0) sval = x[rowbase + (long)st * C + c];
  float xval = x[idx];
  float d = sval - xval;
  xx[idx] = d;
  xxx_bf[idx] = f2bf(xval + d * maa_x[c]);
}

// ------------------------------------- maa_w1 transpose+convert to bf16 ----
__global__ __launch_bounds__(256) void k_w1t(
    const float* __restrict__ w1, ushort* __restrict__ out) {
  int n = blockIdx.y;
  int k = blockIdx.x * 256 + threadIdx.x;
  float v = (n < 160) ? w1[(size_t)k * 160 + n] : 0.f;
  out[(size_t)n * 768 + k] = f2bf(v);
}

// -------------------------- dec_w1 / dec_w2 transpose+convert to bf16 ------
__global__ __launch_bounds__(256) void k_decT(
    const float* __restrict__ w1, const float* __restrict__ w2,
    ushort* __restrict__ w1dT, ushort* __restrict__ w2dT) {
  int idx = blockIdx.x * 256 + threadIdx.x;
  if (idx < 128 * 768) {
    int n = idx / 768, k = idx - n * 768;
    float v = (n < 64) ? w1[(size_t)k * 64 + n] : 0.f;
    w1dT[idx] = f2bf(v);
  } else {
    int j = idx - 128 * 768;
    int n = j >> 6, k = j & 63;
    w2dT[j] = f2bf(w2[(size_t)k * 768 + n]);
  }
}

// ---------------------------------------------- mix5 fused GEMM+epilogue ---
__global__ __launch_bounds__(256) void k_mix5f(
    const float* __restrict__ t5, const float* __restrict__ maa_w2,
    const float* __restrict__ x, const float* __restrict__ xx,
    const float* __restrict__ maa_w, const float* __restrict__ maa_k,
    const float* __restrict__ maa_v, const float* __restrict__ maa_r,
    const float* __restrict__ maa_g,
    ushort* __restrict__ xw, ushort* __restrict__ xk, ushort* __restrict__ xvb,
    ushort* __restrict__ xr, ushort* __restrict__ xg, int C) {
  __shared__ float As[64][36];
  __shared__ float Bs[32][64];
  int tid = threadIdx.x;
  int m0 = blockIdx.y * 64, n0 = blockIdx.x * 64;
  int tx = tid & 15, ty = tid >> 4;
  int cb = n0 + tx * 4;
  float4 xv4[4], dd4[4];
#pragma unroll
  for (int i = 0; i < 4; i++) {
    size_t off = (size_t)(m0 + ty * 4 + i) * C + cb;
    xv4[i] = *(const float4*)(x + off);
    dd4[i] = *(const float4*)(xx + off);
  }

#pragma unroll
  for (int f = 0; f < 5; f++) {
    {
      int k4 = (tid & 7) * 4;
      int row = tid >> 3;
      const float* src = t5 + (size_t)(m0 + row) * 160 + f * 32 + k4;
      float4 v0 = *(const float4*)src;
      float4 v1 = *(const float4*)(src + 32 * 160);
      *(float4*)(&As[row][k4]) = v0;
      *(float4*)(&As[row + 32][k4]) = v1;
    }
    {
      int col = (tid & 15) * 4, kk = tid >> 4;
      const float* src = maa_w2 + (size_t)(f * 32 + kk) * C + n0 + col;
      *(float4*)(&Bs[kk][col]) = *(const float4*)src;
      *(float4*)(&Bs[kk + 16][col]) = *(const float4*)(src + (size_t)16 * C);
    }
    __syncthreads();
    float acc[4][4];
#pragma unroll
    for (int i = 0; i < 4; i++)
#pragma unroll
      for (int j = 0; j < 4; j++) acc[i][j] = 0.f;
#pragma unroll
    for (int kk = 0; kk < 32; kk++) {
      float4 b4 = *(const float4*)(&Bs[kk][tx * 4]);
#pragma unroll
      for (int i = 0; i < 4; i++) {
        float a = As[ty * 4 + i][kk];
        acc[i][0] = fmaf(a, b4.x, acc[i][0]);
        acc[i][1] = fmaf(a, b4.y, acc[i][1]);
        acc[i][2] = fmaf(a, b4.z, acc[i][2]);
        acc[i][3] = fmaf(a, b4.w, acc[i][3]);
      }
    }
    __syncthreads();
    const float* maa_f = (f == 0) ? maa_w : (f == 1) ? maa_k
                        : (f == 2) ? maa_v : (f == 3) ? maa_r : maa_g;
    ushort* dst = (f == 0) ? xw : (f == 1) ? xk
                 : (f == 2) ? xvb : (f == 3) ? xr : xg;
    float4 mf = *(const float4*)(maa_f + cb);
#pragma unroll
    for (int i = 0; i < 4; i++) {
      size_t off = (size_t)(m0 + ty * 4 + i) * C + cb;
      ushort4 ob;
      ob.x = f2bf(xv4[i].x + dd4[i].x * (mf.x + acc[i][0]));
      ob.y = f2bf(xv4[i].y + dd4[i].y * (mf.y + acc[i][1]));
      ob.z = f2bf(xv4[i].z + dd4[i].z * (mf.z + acc[i][2]));
      ob.w = f2bf(xv4[i].w + dd4[i].w * (mf.w + acc[i][3]));
      *(ushort4*)(dst + off) = ob;
    }
  }
}

// -------------------------------------------- fp32 -> bf16 cvt (5 arrays) --
__global__ __launch_bounds__(256) void k_cvt5(
    const float* __restrict__ s0, const float* __restrict__ s1,
    const float* __restrict__ s2, const float* __restrict__ s3,
    const float* __restrict__ s4,
    ushort* __restrict__ d0, ushort* __restrict__ d1,
    ushort* __restrict__ d2, ushort* __restrict__ d3,
    ushort* __restrict__ d4, int n) {
  const float* s;
  ushort* d;
  switch (blockIdx.y) {
    case 0: s = s0; d = d0; break;
    case 1: s = s1; d = d1; break;
    case 2: s = s2; d = d2; break;
    case 3: s = s3; d = d3; break;
    default: s = s4; d = d4; break;
  }
  int i = (blockIdx.x * 256 + threadIdx.x) * 4;
  if (i >= n) return;
  float4 v = *(const float4*)(s + i);
  ushort4 o;
  o.x = f2bf(v.x); o.y = f2bf(v.y); o.z = f2bf(v.z); o.w = f2bf(v.w);
  *(ushort4*)(d + i) = o;
}

// ----------------------------------------------------- bf16 MFMA GEMM ------
template <int EPI, bool NMASK, bool OBF16>
__global__ __launch_bounds__(256) void k_gemm_bf(
    const ushort* __restrict__ A, const ushort* __restrict__ W,
    const float* __restrict__ bias, void* __restrict__ Cm,
    int M, int N, int K) {
  __shared__ ushort Al[128 * 32];
  __shared__ ushort Bl[128 * 32];
  int tid = threadIdx.x;
  int m0 = blockIdx.y * 128, n0 = blockIdx.x * 128;
  int lane = tid & 63, wave = tid >> 6;
  int wm = (wave >> 1) * 64, wn = (wave & 1) * 64;
  int lm = lane & 15, lk = (lane >> 4) * 8;
  f32x4 acc[4][4];
#pragma unroll
  for (int i = 0; i < 4; i++)
#pragma unroll
    for (int j = 0; j < 4; j++) acc[i][j] = (f32x4){0.f, 0.f, 0.f, 0.f};

  int arow = tid >> 2, achunk = (tid & 3) * 8;
  const ushort* Ag = A + (size_t)(m0 + arow) * K + achunk;
  const ushort* Wg = W + (size_t)(n0 + arow) * K + achunk;
  ushort* Ald = Al + tid * 8;
  ushort* Bld = Bl + tid * 8;

  for (int k0 = 0; k0 < K; k0 += 32) {
    GLDS16(Ag + k0, Ald);
    GLDS16(Ag + (size_t)64 * K + k0, Ald + 2048);
    GLDS16(Wg + k0, Bld);
    GLDS16(Wg + (size_t)64 * K + k0, Bld + 2048);
    __syncthreads();
    bf16x8 af[4], bf[4];
#pragma unroll
    for (int i = 0; i < 4; i++)
      af[i] = *(const bf16x8*)&Al[(wm + i * 16 + lm) * 32 + lk];
#pragma unroll
    for (int j = 0; j < 4; j++)
      bf[j] = *(const bf16x8*)&Bl[(wn + j * 16 + lm) * 32 + lk];
#pragma unroll
    for (int i = 0; i < 4; i++)
#pragma unroll
      for (int j = 0; j < 4; j++)
        acc[i][j] = __builtin_amdgcn_mfma_f32_16x16x32_bf16(
            af[i], bf[j], acc[i][j], 0, 0, 0);
    __syncthreads();
  }
  int rq = (lane >> 4) * 4;
#pragma unroll
  for (int i = 0; i < 4; i++) {
#pragma unroll
    for (int j = 0; j < 4; j++) {
      int gn = n0 + wn + j * 16 + lm;
      if (NMASK && gn >= N) continue;
      float bv = (EPI == EPI_BIAS) ? bias[gn] : 0.f;
#pragma unroll
      for (int q = 0; q < 4; q++) {
        int gm = m0 + wm + i * 16 + rq + q;
        float val = acc[i][j][q];
        if (EPI == EPI_BIAS) val += bv;
        if (EPI == EPI_RELU) val = fmaxf(val, 0.f);
        if (EPI == EPI_TANH) val = tanhf(val);
        if (OBF16) ((ushort*)Cm)[(size_t)gm * N + gn] = f2bf(val);
        else       ((float*)Cm)[(size_t)gm * N + gn] = val;
      }
    }
  }
}

// --------------------------------- batched 4-projection bf16 MFMA GEMM -----
__global__ __launch_bounds__(256) void k_proj4(
    const ushort* __restrict__ A0, const ushort* __restrict__ A1,
    const ushort* __restrict__ A2, const ushort* __restrict__ A3,
    const ushort* __restrict__ W0, const ushort* __restrict__ W1,
    const ushort* __restrict__ W2, const ushort* __restrict__ W3,
    float* __restrict__ C0, float* __restrict__ C1,
    float* __restrict__ C2, float* __restrict__ C3,
    int M, int N, int K) {
  int z = blockIdx.z;
  const ushort* A = (z == 0) ? A0 : (z == 1) ? A1 : (z == 2) ? A2 : A3;
  const ushort* W = (z == 0) ? W0 : (z == 1) ? W1 : (z == 2) ? W2 : W3;
  float* Cm       = (z == 0) ? C0 : (z == 1) ? C1 : (z == 2) ? C2 : C3;
  __shared__ ushort Al[128 * 32];
  __shared__ ushort Bl[128 * 32];
  int tid = threadIdx.x;
  int m0 = blockIdx.y * 128, n0 = blockIdx.x * 128;
  int lane = tid & 63, wave = tid >> 6;
  int wm = (wave >> 1) * 64, wn = (wave & 1) * 64;
  int lm = lane & 15, lk = (lane >> 4) * 8;
  f32x4 acc[4][4];
#pragma unroll
  for (int i = 0; i < 4; i++)
#pragma unroll
    for (int j = 0; j < 4; j++) acc[i][j] = (f32x4){0.f, 0.f, 0.f, 0.f};

  int arow = tid >> 2, achunk = (tid & 3) * 8;
  const ushort* Ag = A + (size_t)(m0 + arow) * K + achunk;
  const ushort* Wg = W + (size_t)(n0 + arow) * K + achunk;
  ushort* Ald = Al + tid * 8;
  ushort* Bld = Bl + tid * 8;

  for (int k0 = 0; k0 < K; k0 += 32) {
    GLDS16(Ag + k0, Ald);
    GLDS16(Ag + (size_t)64 * K + k0, Ald + 2048);
    GLDS16(Wg + k0, Bld);
    GLDS16(Wg + (size_t)64 * K + k0, Bld + 2048);
    __syncthreads();
    bf16x8 af[4], bf[4];
#pragma unroll
    for (int i = 0; i < 4; i++)
      af[i] = *(const bf16x8*)&Al[(wm + i * 16 + lm) * 32 + lk];
#pragma unroll
    for (int j = 0; j < 4; j++)
      bf[j] = *(const bf16x8*)&Bl[(wn + j * 16 + lm) * 32 + lk];
#pragma unroll
    for (int i = 0; i < 4; i++)
#pragma unroll
      for (int j = 0; j < 4; j++)
        acc[i][j] = __builtin_amdgcn_mfma_f32_16x16x32_bf16(
            af[i], bf[j], acc[i][j], 0, 0, 0);
    __syncthreads();
  }
  bool relu = (z == 3);
  int rq = (lane >> 4) * 4;
#pragma unroll
  for (int i = 0; i < 4; i++) {
#pragma unroll
    for (int j = 0; j < 4; j++) {
      int gn = n0 + wn + j * 16 + lm;
#pragma unroll
      for (int q = 0; q < 4; q++) {
        int gm = m0 + wm + i * 16 + rq + q;
        float val = acc[i][j][q];
        if (relu) val = fmaxf(val, 0.f);
        Cm[(size_t)gm * N + gn] = val;
      }
    }
  }
}

// ------------------------------------------------- chunked WKV: phase pre --
__global__ __launch_bounds__(64) void k_wkv_pre(
    const float* __restrict__ r, const float* __restrict__ k,
    const float* __restrict__ w, const float* __restrict__ u,
    float* __restrict__ rt, float* __restrict__ kt,
    float* __restrict__ aL, float* __restrict__ pdiag,
    int B, int T, int C, int H, int L) {
  int nch = T / L;
  int blk = blockIdx.x;
  int bh = blk / nch, c = blk - bh * nch;
  int b = bh / H, h = bh - b * H;
  int j = threadIdx.x;
  float uj = u[h * 64 + j];
  float cum = 0.f;
  long base = ((long)b * T + (long)c * L) * C + h * 64 + j;
  for (int tau = 0; tau < L; tau++) {
    long off = base + (long)tau * C;
    float wv = w[off];
    float rv = r[off];
    float kv = k[off];
    float e = expf(wv);
    rt[off] = rv * expf(-cum);
    cum += e;
    kt[off] = kv * expf(cum);
    float pd = rv * uj * kv;
#pragma unroll
    for (int o = 32; o >= 1; o >>= 1) pd += __shfl_xor(pd, o, 64);
    if (j == 0) pdiag[(long)bh * T + c * L + tau] = pd;
  }
  aL[((long)bh * nch + c) * 64 + j] = expf(-cum);
}

// --------------------------------------- chunked WKV: per-chunk KV outer ---
__global__ __launch_bounds__(256) void k_wkv_kv(
    const float* __restrict__ kt, const float* __restrict__ v,
    float* __restrict__ kvb, int B, int T, int C, int H, int L) {
  int nch = T / L;
  int blk = blockIdx.x;
  int bh = blk / nch, c = blk - bh * nch;
  int b = bh / H, h = bh - b * H;
  __shared__ float Ks[64 * LPAD];
  __shared__ float Vs[64 * LPAD];
  int tid = threadIdx.x;
  int lane = tid & 63, jg = tid >> 6;
  long cbase = ((long)b * T + (long)c * L) * C + h * 64;
#pragma unroll
  for (int q = 0; q < 4; q++) {
    int idx = tid + q * 256;
    int row = idx >> 4, col = (idx & 15) * 4;
    long g = cbase + (long)row * C + col;
    *(float4*)(Ks + row * LPAD + col) = *(const float4*)(kt + g);
    *(float4*)(Vs + row * LPAD + col) = *(const float4*)(v + g);
  }
  __syncthreads();
  float acc[16];
#pragma unroll
  for (int q = 0; q < 16; q++) acc[q] = 0.f;
  for (int s = 0; s < 64; s++) {
    float vi = Vs[s * LPAD + lane];
#pragma unroll
    for (int q4 = 0; q4 < 4; q4++) {
      float4 kk = *(const float4*)(Ks + s * LPAD + jg * 16 + q4 * 4);
      acc[q4 * 4 + 0] = fmaf(kk.x, vi, acc[q4 * 4 + 0]);
      acc[q4 * 4 + 1] = fmaf(kk.y, vi, acc[q4 * 4 + 1]);
      acc[q4 * 4 + 2] = fmaf(kk.z, vi, acc[q4 * 4 + 2]);
      acc[q4 * 4 + 3] = fmaf(kk.w, vi, acc[q4 * 4 + 3]);
    }
  }
  float* out = kvb + ((long)bh * nch + c) * 4096;
#pragma unroll
  for (int q = 0; q < 16; q++) out[(jg * 16 + q) * 64 + lane] = acc[q];
}

// ---------------------------------------- chunked WKV: state prefix scan ---
__global__ __launch_bounds__(256) void k_wkv_scan(
    const float* __restrict__ kvb, const float* __restrict__ aL,
    float* __restrict__ Scb, int nch) {
  int bh = blockIdx.x;
  int tid = threadIdx.x;
  float S[16];
#pragma unroll
  for (int q = 0; q < 16; q++) S[q] = 0.f;
  for (int c = 0; c < nch; c++) {
    const float* kv = kvb + ((long)bh * nch + c) * 4096;
    float* sc = Scb + ((long)bh * nch + c) * 4096;
    const float* aLc = aL + ((long)bh * nch + c) * 64;
#pragma unroll
    for (int q = 0; q < 16; q++) {
      int e = q * 256 + tid;
      sc[e] = S[q];
      S[q] = aLc[e >> 6] * (S[q] + kv[e]);
    }
  }
}

// ------------- chunked WKV: intra + inter + groupnorm*gate (fused) ---------
// y = mask(Rt Kt^T + diag) @ V + Rt @ S_prev; GN over head channels; gate.
// S_prev streamed from global in-loop (coalesced, L1-reused by 4 waves) —
// NO per-thread array (a dynamically-indexed array spills to scratch: R8).
__global__ __launch_bounds__(256, 3) void k_wkv_intra(
    const float* __restrict__ rt, const float* __restrict__ kt,
    const float* __restrict__ v, const float* __restrict__ pdiag,
    const float* __restrict__ Scb, const float* __restrict__ g,
    const float* __restrict__ ln_w, const float* __restrict__ ln_b,
    ushort* __restrict__ z, int B, int T, int C, int H, int L) {
  int nch = T / L;
  int blk = blockIdx.x;
  int bh = blk / nch, c = blk - bh * nch;
  int b = bh / H, h = bh - b * H;
  __shared__ float RPs[64 * LPAD];   // Rt tile -> P^T
  __shared__ float Ks[64 * LPAD];    // Kt tile -> Rt^T
  __shared__ float Vs[64 * LPAD];
  int tid = threadIdx.x;
  long cbase = ((long)b * T + (long)c * L) * C + h * 64;
  const float* scp = Scb + ((long)bh * nch + c) * 4096;
#pragma unroll
  for (int q = 0; q < 4; q++) {
    int idx = tid + q * 256;
    int row = idx >> 4, col = (idx & 15) * 4;
    long g4 = cbase + (long)row * C + col;
    *(float4*)(RPs + row * LPAD + col) = *(const float4*)(rt + g4);
    *(float4*)(Ks + row * LPAD + col) = *(const float4*)(kt + g4);
    *(float4*)(Vs + row * LPAD + col) = *(const float4*)(v + g4);
  }
  __syncthreads();
  int tau = tid & 63, sg = tid >> 6;
  float4 rreg[16];
#pragma unroll
  for (int q = 0; q < 16; q++)
    rreg[q] = *(const float4*)(RPs + tau * LPAD + q * 4);
  float pd = pdiag[(long)bh * T + c * L + tau];
  __syncthreads();   // Rt reads done; RPs becomes P^T storage
#pragma unroll 2
  for (int ss = 0; ss < 16; ss++) {
    int s = sg * 16 + ss;
    float a0 = 0.f, a1 = 0.f, a2 = 0.f, a3 = 0.f;
#pragma unroll
    for (int q = 0; q < 16; q++) {
      float4 kk = *(const float4*)(Ks + s * LPAD + q * 4);
      a0 = fmaf(rreg[q].x, kk.x, a0);
      a1 = fmaf(rreg[q].y, kk.y, a1);
      a2 = fmaf(rreg[q].z, kk.z, a2);
      a3 = fmaf(rreg[q].w, kk.w, a3);
    }
    float a = (a0 + a1) + (a2 + a3);
    float val = (s < tau) ? a : (s == tau ? pd : 0.f);
    RPs[s * LPAD + tau] = val;
  }
  __syncthreads();   // Kt reads done; Ks becomes Rt^T storage
#pragma unroll
  for (int qq = 0; qq < 16; qq++) {
    const float* rr = (const float*)&rreg[sg * 4 + (qq >> 2)];
    Ks[(sg * 16 + qq) * LPAD + tau] = rr[qq & 3];
  }
  __syncthreads();
  int i = tid & 63, tg = tid >> 6;
  float acc[16];
#pragma unroll
  for (int q = 0; q < 16; q++) acc[q] = 0.f;
  // interleaved contraction: P@V (LDS) + Rt@S_prev (S from global, coalesced)
#pragma unroll 4
  for (int s = 0; s < 64; s++) {
    float si = scp[s * 64 + i];        // 256B/wave coalesced, L1-reused x4
    float vi = Vs[s * LPAD + i];
#pragma unroll
    for (int q4 = 0; q4 < 4; q4++) {
      float4 pp = *(const float4*)(RPs + s * LPAD + tg * 16 + q4 * 4);
      float4 rr = *(const float4*)(Ks + s * LPAD + tg * 16 + q4 * 4);
      acc[q4 * 4 + 0] = fmaf(pp.x, vi, fmaf(rr.x, si, acc[q4 * 4 + 0]));
      acc[q4 * 4 + 1] = fmaf(pp.y, vi, fmaf(rr.y, si, acc[q4 * 4 + 1]));
      acc[q4 * 4 + 2] = fmaf(pp.z, vi, fmaf(rr.z, si, acc[q4 * 4 + 2]));
      acc[q4 * 4 + 3] = fmaf(pp.w, vi, fmaf(rr.w, si, acc[q4 * 4 + 3]));
    }
  }
  // fused groupnorm (per row over this head's 64 channels) * gate -> z bf16
  int ch = h * 64 + i;
  float lw = ln_w[ch], lb = ln_b[ch];
#pragma unroll
  for (int q = 0; q < 16; q++) {
    float val = acc[q];
    float s = val;
#pragma unroll
    for (int o = 32; o >= 1; o >>= 1) s += __shfl_xor(s, o, 64);
    float mu = s * (1.f / 64.f);
    float d = val - mu;
    float vs = d * d;
#pragma unroll
    for (int o = 32; o >= 1; o >>= 1) vs += __shfl_xor(vs, o, 64);
    float var = vs * (1.f / 64.f);
    float nrm = d * rsqrtf(var + 1e-5f);
    long off = cbase + (long)(tg * 16 + q) * C + i;
    z[off] = f2bf((nrm * lw + lb) * g[off]);
  }
}

// ---------------------------------------------------------------- launch ---
extern "C" void kernel_launch(void* const* d_in, const int* in_sizes, int n_in,
                              void* d_out, int out_size, void* d_ws, size_t ws_size,
                              hipStream_t stream) {
  const int B = 8, T = 1024, C = 768, H = 12, ph = 32, pw = 32;
  const int M = B * T;
  const int L = 64, NCH = T / L;

  const float* x        = (const float*)d_in[0];
  const float* W_r      = (const float*)d_in[1];
  const float* W_k      = (const float*)d_in[2];
  const float* W_v      = (const float*)d_in[3];
  const float* W_g      = (const float*)d_in[4];
  const float* W_o      = (const float*)d_in[5];
  const float* maa_x    = (const float*)d_in[6];
  const float* maa_w    = (const float*)d_in[7];
  const float* maa_k    = (const float*)d_in[8];
  const float* maa_v    = (const float*)d_in[9];
  const float* maa_r    = (const float*)d_in[10];
  const float* maa_g    = (const float*)d_in[11];
  const float* maa_w1   = (const float*)d_in[12];
  const float* maa_w2   = (const float*)d_in[13];
  const float* time_dec = (const float*)d_in[14];
  const float* dec_w1   = (const float*)d_in[15];
  const float* dec_w2   = (const float*)d_in[16];
  const float* faaaa    = (const float*)d_in[17];
  const float* ln_w     = (const float*)d_in[18];
  const float* ln_b     = (const float*)d_in[19];

  float* ws = (float*)d_ws;
  const size_t S = (size_t)M * C;
  float* F0 = ws + 0 * S;   // xx -> r -> kvb
  float* F1 = ws + 1 * S;   // xxx_bf -> k -> Scb
  float* F2 = ws + 2 * S;   // xw_bf -> w -> Kt (in place)
  float* F3 = ws + 3 * S;   // v
  float* F4 = ws + 4 * S;   // g
  float* F5 = ws + 5 * S;   // xr_bf | xk_bf -> Rt (fp32)
  float* F6 = ws + 6 * S;   // xv_bf | xg_bf -> z_bf
  float* t5    = ws + 7 * S;            // [M,160] fp32 -> bf16 W_r..W_g
  float* t6    = t5 + (size_t)M * 160;  // bf16 W_o + maa1T + decT
  float* aLb   = t6 + (size_t)M * 64;
  float* pdiag = aLb + (size_t)B * H * NCH * 64;
  float* dec_t = pdiag + (size_t)B * H * T;   // [M,64] t_bf scratch

  ushort* xxx_bf = (ushort*)F1;
  ushort* xw_bf = (ushort*)F2;
  ushort* xr_bf = (ushort*)F5;
  ushort* xk_bf = xr_bf + S;
  ushort* xv_bf = (ushort*)F6;
  ushort* xg_bf = xv_bf + S;
  ushort* z_bf  = (ushort*)F6;
  ushort* t_bf  = (ushort*)dec_t;       // [M,64] bf16
  float* kvb = F0;
  float* Scb = F1;
  const int WSZ = C * C;
  ushort* wr_bf = (ushort*)t5;
  ushort* wk_bf = wr_bf + WSZ;
  ushort* wv_bf = wk_bf + WSZ;
  ushort* wg_bf = wv_bf + WSZ;
  ushort* wo_bf = (ushort*)t6;
  ushort* maa1T = wo_bf + WSZ;          // [256,768]
  ushort* w1dT  = maa1T + 256 * 768;    // [128,768]
  ushort* w2dT  = w1dT + 128 * 768;     // [768,64]

  // 1. qshift (xx fp32, xxx bf16)
  {
    long total = (long)M * C;
    k_qshift<<<(int)((total + 255) / 256), 256, 0, stream>>>(
        x, maa_x, F0, xxx_bf, B, T, C, ph, pw);
  }
  // 2. maa_w1/dec transposes -> bf16; t5 = tanh(xxx @ maa_w1) via MFMA
  {
    dim3 gt(3, 256);
    k_w1t<<<gt, 256, 0, stream>>>(maa_w1, maa1T);
    k_decT<<<(128 * 768 + 768 * 64) / 256, 256, 0, stream>>>(
        dec_w1, dec_w2, w1dT, w2dT);
    dim3 grid(2, M / 128);
    k_gemm_bf<EPI_TANH, true, false><<<grid, 256, 0, stream>>>(
        xxx_bf, maa1T, nullptr, t5, M, 160, C);
  }
  // 3. mix5 (all outputs bf16)
  {
    dim3 grid(C / 64, M / 64);
    k_mix5f<<<grid, 256, 0, stream>>>(t5, maa_w2, x, F0, maa_w, maa_k, maa_v,
                                      maa_r, maa_g, xw_bf, xk_bf, xv_bf, xr_bf,
                                      xg_bf, C);
  }
  // 4. weight conversion (t5 data dead now)
  {
    dim3 grid((WSZ / 4 + 255) / 256, 5);
    k_cvt5<<<grid, 256, 0, stream>>>(W_r, W_k, W_v, W_g, W_o,
                                     wr_bf, wk_bf, wv_bf, wg_bf, wo_bf, WSZ);
  }
  // 5. big projections: ONE batched bf16 MFMA dispatch (grid.z = 4)
  {
    dim3 grid(C / 128, M / 128, 4);
    k_proj4<<<grid, 256, 0, stream>>>(xr_bf, xk_bf, xv_bf, xg_bf,
                                      wr_bf, wk_bf, wv_bf, wg_bf,
                                      F0, F1, F3, F4, M, C, C);
  }
  // 6. decay path on MFMA
  {
    dim3 g1(1, M / 128);
    k_gemm_bf<EPI_TANH, true, true><<<g1, 256, 0, stream>>>(
        xw_bf, w1dT, nullptr, t_bf, M, 64, C);
    dim3 g2(C / 128, M / 128);
    k_gemm_bf<EPI_BIAS, false, false><<<g2, 256, 0, stream>>>(
        t_bf, w2dT, time_dec, F2, M, C, 64);
  }
  // 7. chunked wkv6: pre -> kv -> scan -> intra(+GN+gate -> z bf16)
  k_wkv_pre<<<B * H * NCH, 64, 0, stream>>>(F0, F1, F2, faaaa, F5, F2,
                                            aLb, pdiag, B, T, C, H, L);
  k_wkv_kv<<<B * H * NCH, 256, 0, stream>>>(F2, F3, kvb, B, T, C, H, L);
  k_wkv_scan<<<B * H, 256, 0, stream>>>(kvb, aLb, Scb, NCH);
  k_wkv_intra<<<B * H * NCH, 256, 0, stream>>>(F5, F2, F3, pdiag, Scb, F4,
                                               ln_w, ln_b, z_bf, B, T, C, H, L);
  // 8. out = z @ W_o^T (bf16 MFMA)
  {
    dim3 grid(C / 128, M / 128);
    k_gemm_bf<EPI_NONE, false, false><<<grid, 256, 0, stream>>>(
        z_bf, wo_bf, nullptr, (float*)d_out, M, C, C);
  }
}